// Round 6
// baseline (5295.472 us; speedup 1.0000x reference)
//
#include <hip/hip_runtime.h>
#include <math.h>

#define HIDC 128
#define EDGEF 16
#define LAY 3
#define KNN 3
#define UU 4
#define NBLK 20000
#define NATOM (NBLK*UU)      // 80000
#define EBK 30000
#define EALL (EBK*UU*KNN)    // 360000
#define NGRP (EBK*UU)        // 120000 (edge,u) groups

#define W1F_L 36864          // 9 kb * 8 j * 64 lanes * 8
#define W2F_L 16384          // 4 kb * 8 j * 64 lanes * 8

typedef __attribute__((ext_vector_type(8))) short bf16x8;
typedef __attribute__((ext_vector_type(4))) float f32x4;

__device__ __forceinline__ float silu_f(float v) {
    return v / (1.0f + expf(-v));
}

__device__ __forceinline__ unsigned short f2bf(float f) {
    union { float f; unsigned int u; } v; v.f = f;
    unsigned int r = v.u + 0x7FFFu + ((v.u >> 16) & 1u);
    return (unsigned short)(r >> 16);
}

__device__ __forceinline__ float bf2f(unsigned short h) {
    union { unsigned int u; float f; } t; t.u = ((unsigned int)h) << 16;
    return t.f;
}

// split f32 into bf16 hi + bf16 lo (x ~= hi + lo, ~17 mantissa bits)
__device__ __forceinline__ void split2(float v, short& hi, short& lo) {
    unsigned short h = f2bf(v);
    hi = (short)h;
    lo = (short)f2bf(v - bf2f(h));
}

// ---------------- CSR build ----------------

__global__ void k_count(const int* __restrict__ edges, int* __restrict__ degB) {
    int e = blockIdx.x * 256 + threadIdx.x;
    if (e < EBK) atomicAdd(&degB[edges[e]], 1);
}

__global__ void k_scan(const int* __restrict__ degB, int* __restrict__ offB) {
    __shared__ int s[1024];
    __shared__ int carry;
    if (threadIdx.x == 0) carry = 0;
    __syncthreads();
    for (int base = 0; base < NBLK; base += 1024) {
        int i = base + threadIdx.x;
        int v = (i < NBLK) ? degB[i] : 0;
        s[threadIdx.x] = v;
        __syncthreads();
        for (int d = 1; d < 1024; d <<= 1) {
            int t = (threadIdx.x >= d) ? s[threadIdx.x - d] : 0;
            __syncthreads();
            s[threadIdx.x] += t;
            __syncthreads();
        }
        if (i < NBLK) offB[i] = carry + s[threadIdx.x] - v;
        int tot = s[1023];
        __syncthreads();
        if (threadIdx.x == 0) carry += tot;
        __syncthreads();
    }
    if (threadIdx.x == 0) offB[NBLK] = carry;
}

__global__ void k_fill(const int* __restrict__ edges, const int* __restrict__ offB,
                       int* __restrict__ cursor, int* __restrict__ listE) {
    int e = blockIdx.x * 256 + threadIdx.x;
    if (e < EBK) {
        int b = edges[e];
        int p = atomicAdd(&cursor[b], 1);
        listE[offB[b] + p] = e;
    }
}

// top-3 nearest dst atoms per src atom; exact f32, tie -> lower index (matches top_k)
__global__ void k_topk(const int* __restrict__ edges, const float* __restrict__ Z,
                       int* __restrict__ colIdx) {
    int t = blockIdx.x * 256 + threadIdx.x;
    if (t >= EBK * UU) return;
    int e = t >> 2, u = t & 3;
    int b0 = edges[e], b1 = edges[EBK + e];
    int s = b0 * UU + u;
    float zs0 = Z[s*3+0], zs1 = Z[s*3+1], zs2 = Z[s*3+2];
    float d2[UU];
    #pragma unroll
    for (int v = 0; v < UU; v++) {
        int d = b1 * UU + v;
        float a0 = __fsub_rn(zs0, Z[d*3+0]);
        float a1 = __fsub_rn(zs1, Z[d*3+1]);
        float a2 = __fsub_rn(zs2, Z[d*3+2]);
        float p0 = __fmul_rn(a0, a0);
        float p1 = __fmul_rn(a1, a1);
        float p2 = __fmul_rn(a2, a2);
        d2[v] = __fadd_rn(__fadd_rn(p0, p1), p2);
    }
    bool used[UU] = {false, false, false, false};
    #pragma unroll
    for (int k = 0; k < KNN; k++) {
        int best = -1;
        float bd = INFINITY;
        #pragma unroll
        for (int v = 0; v < UU; v++) {
            if (!used[v] && d2[v] < bd) { bd = d2[v]; best = v; }
        }
        used[best] = true;
        colIdx[t * KNN + k] = b1 * UU + best;
    }
}

// ---------------- weight fragment precompute (hi/lo bf16, MFMA B-layout) ----------------
// frag chunk (kb,j): lane l holds W[kb*32 + (l>>4)*8 + t][j*16 + (l&15)], t=0..7

__global__ void k_wfrag(const float* __restrict__ ew1, const float* __restrict__ ew2,
                        const float* __restrict__ cw1,
                        unsigned short* __restrict__ w1f_hi, unsigned short* __restrict__ w1f_lo,
                        unsigned short* __restrict__ w2f_hi, unsigned short* __restrict__ w2f_lo,
                        unsigned short* __restrict__ c1f_hi, unsigned short* __restrict__ c1f_lo) {
    int i = blockIdx.x * 256 + threadIdx.x;
    float v;
    unsigned short* dh;
    unsigned short* dl;
    int di;
    if (i < 3 * W1F_L) {
        int l = i / W1F_L, rem = i % W1F_L;
        int chunk = rem >> 9, lane = (rem >> 3) & 63, t = rem & 7;
        int kb = chunk >> 3, j = chunk & 7;
        int k = kb*32 + (lane >> 4)*8 + t, n = j*16 + (lane & 15);
        v = (k < 273) ? ew1[(size_t)l*273*128 + (size_t)k*128 + n] : 0.f;
        dh = w1f_hi; dl = w1f_lo; di = i;
    } else {
        int i2 = i - 3 * W1F_L;
        if (i2 < 3 * W2F_L) {
            int l = i2 / W2F_L, rem = i2 % W2F_L;
            int chunk = rem >> 9, lane = (rem >> 3) & 63, t = rem & 7;
            int kb = chunk >> 3, j = chunk & 7;
            int k = kb*32 + (lane >> 4)*8 + t, n = j*16 + (lane & 15);
            v = ew2[(size_t)l*128*128 + (size_t)k*128 + n];
            dh = w2f_hi; dl = w2f_lo; di = i2;
        } else {
            int i3 = i2 - 3 * W2F_L;
            if (i3 >= 3 * W2F_L) return;
            int l = i3 / W2F_L, rem = i3 % W2F_L;
            int chunk = rem >> 9, lane = (rem >> 3) & 63, t = rem & 7;
            int kb = chunk >> 3, j = chunk & 7;
            int k = kb*32 + (lane >> 4)*8 + t, n = j*16 + (lane & 15);
            v = cw1[(size_t)l*128*128 + (size_t)k*128 + n];
            dh = c1f_hi; dl = c1f_lo; di = i3;
        }
    }
    short hi, lo;
    split2(v, hi, lo);
    dh[di] = (unsigned short)hi;
    dl[di] = (unsigned short)lo;
}

// ---------------- flat fused edge pipeline (split-bf16 MFMA, 64 rows/wave) ----------------
// Row space: 16 rows per block-edge (4 u-groups x 4 kk-slots, kk=3 duplicates kk=2).
// One wave = 4 block-edges = 4 sub-tiles of 16 rows. Weight chunk reuse x4.
// Outputs per (edge,u) group: msum[128] (kk-summed m, bf16) and xsum[3] — no atomics.

__global__ __launch_bounds__(64) void k_edge_flat(
    const float* __restrict__ hbuf,
    const float* __restrict__ x,
    const float* __restrict__ eattr,
    const int* __restrict__ edges0,
    const int* __restrict__ colIdx,
    const unsigned short* __restrict__ w1f_hi, const unsigned short* __restrict__ w1f_lo,
    const unsigned short* __restrict__ w2f_hi, const unsigned short* __restrict__ w2f_lo,
    const unsigned short* __restrict__ c1f_hi, const unsigned short* __restrict__ c1f_lo,
    const float* __restrict__ eb1,
    const float* __restrict__ eb2,
    const float* __restrict__ cb1,
    const float* __restrict__ cw2v,
    unsigned short* __restrict__ msum,
    float* __restrict__ xsum)
{
    __shared__ unsigned short C1h[64 * 128], C1l[64 * 128];  // reused for M in phase 3
    __shared__ float diffS[64 * 3];

    const int l = threadIdx.x;
    const int g = l >> 4, er = l & 15;
    const int u = er >> 2, kk = er & 3;
    const int kkc = (kk < 3) ? kk : 2;
    const int e0 = blockIdx.x * 4;

    // per-tile atom indices (wave-uniform edge per tile, per-lane u/kk)
    int srcA[4], colA[4];
    float rad[4];
    #pragma unroll
    for (int t = 0; t < 4; t++) {
        const int e = e0 + t;
        const int bs = edges0[e];
        srcA[t] = bs * 4 + u;
        colA[t] = colIdx[(e * 4 + u) * 3 + kkc];
        if (g == 0) {
            float dx = x[srcA[t]*3+0] - x[colA[t]*3+0];
            float dy = x[srcA[t]*3+1] - x[colA[t]*3+1];
            float dz = x[srcA[t]*3+2] - x[colA[t]*3+2];
            rad[t] = dx*dx + dy*dy + dz*dz;
            diffS[(t*16+er)*3+0] = dx; diffS[(t*16+er)*3+1] = dy; diffS[(t*16+er)*3+2] = dz;
        }
    }

    // ---- phase 1: C1 = silu([h_r|h_c|rad|ea] @ W1 + b1), K=288 ----
    {
        f32x4 acc[4][8];
        #pragma unroll
        for (int t = 0; t < 4; t++)
            #pragma unroll
            for (int jj = 0; jj < 8; jj++) acc[t][jj] = (f32x4){0.f, 0.f, 0.f, 0.f};

        #pragma unroll 1
        for (int kb = 0; kb < 9; kb++) {
            bf16x8 ah[4], al[4];
            if (kb < 8) {
                #pragma unroll
                for (int t = 0; t < 4; t++) {
                    const float* p0 = ((kb < 4) ? (hbuf + (size_t)srcA[t] * 128 + kb * 32)
                                                : (hbuf + (size_t)colA[t] * 128 + (kb - 4) * 32)) + g * 8;
                    float4 v0 = *(const float4*)(p0);
                    float4 v1 = *(const float4*)(p0 + 4);
                    float vv[8] = {v0.x, v0.y, v0.z, v0.w, v1.x, v1.y, v1.z, v1.w};
                    bf16x8 h8, l8;
                    #pragma unroll
                    for (int q = 0; q < 8; q++) { short hh, ll; split2(vv[q], hh, ll); h8[q] = hh; l8[q] = ll; }
                    ah[t] = h8; al[t] = l8;
                }
            } else {
                // tail slice k in [256,288): radial, eattr, zero-pad
                #pragma unroll
                for (int t = 0; t < 4; t++) {
                    const int e = e0 + t;
                    float tv[8];
                    #pragma unroll
                    for (int q = 0; q < 8; q++) tv[q] = 0.f;
                    if (g == 0) {
                        tv[0] = rad[t];
                        #pragma unroll
                        for (int q = 1; q < 8; q++) tv[q] = eattr[(size_t)e*16 + (q-1)];
                    } else if (g == 1) {
                        #pragma unroll
                        for (int q = 0; q < 8; q++) tv[q] = eattr[(size_t)e*16 + 7 + q];
                    } else if (g == 2) {
                        tv[0] = eattr[(size_t)e*16 + 15];
                    }
                    bf16x8 h8, l8;
                    #pragma unroll
                    for (int q = 0; q < 8; q++) { short hh, ll; split2(tv[q], hh, ll); h8[q] = hh; l8[q] = ll; }
                    ah[t] = h8; al[t] = l8;
                }
            }
            #pragma unroll
            for (int jj = 0; jj < 8; jj++) {
                const int off = ((kb * 8 + jj) << 9) + (l << 3);
                bf16x8 wh = *(const bf16x8*)(w1f_hi + off);
                bf16x8 wl = *(const bf16x8*)(w1f_lo + off);
                #pragma unroll
                for (int t = 0; t < 4; t++) {
                    acc[t][jj] = __builtin_amdgcn_mfma_f32_16x16x32_bf16(ah[t], wh, acc[t][jj], 0, 0, 0);
                    acc[t][jj] = __builtin_amdgcn_mfma_f32_16x16x32_bf16(al[t], wh, acc[t][jj], 0, 0, 0);
                    acc[t][jj] = __builtin_amdgcn_mfma_f32_16x16x32_bf16(ah[t], wl, acc[t][jj], 0, 0, 0);
                }
            }
        }
        #pragma unroll
        for (int t = 0; t < 4; t++)
            #pragma unroll
            for (int jj = 0; jj < 8; jj++) {
                const int n = jj * 16 + er;
                const float bv = eb1[n];
                #pragma unroll
                for (int reg = 0; reg < 4; reg++) {
                    const int row = t * 16 + g * 4 + reg;
                    float v = silu_f(acc[t][jj][reg] + bv);
                    short hh, ll; split2(v, hh, ll);
                    const int sidx = row * 128 + (n ^ ((row & 7) << 3));
                    C1h[sidx] = (unsigned short)hh;
                    C1l[sidx] = (unsigned short)ll;
                }
            }
    }
    __syncthreads();

    // ---- phase 2: m = silu(C1 @ W2 + b2); emit kk-summed msum; stage M over C1 ----
    {
        f32x4 acc[4][8];
        #pragma unroll
        for (int t = 0; t < 4; t++)
            #pragma unroll
            for (int jj = 0; jj < 8; jj++) acc[t][jj] = (f32x4){0.f, 0.f, 0.f, 0.f};

        #pragma unroll 1
        for (int kb = 0; kb < 4; kb++) {
            bf16x8 ah[4], al[4];
            #pragma unroll
            for (int t = 0; t < 4; t++) {
                const int row = t * 16 + er;
                const int aoff = row * 128 + ((kb * 32 + g * 8) ^ ((row & 7) << 3));
                ah[t] = *(const bf16x8*)&C1h[aoff];
                al[t] = *(const bf16x8*)&C1l[aoff];
            }
            #pragma unroll
            for (int jj = 0; jj < 8; jj++) {
                const int off = ((kb * 8 + jj) << 9) + (l << 3);
                bf16x8 wh = *(const bf16x8*)(w2f_hi + off);
                bf16x8 wl = *(const bf16x8*)(w2f_lo + off);
                #pragma unroll
                for (int t = 0; t < 4; t++) {
                    acc[t][jj] = __builtin_amdgcn_mfma_f32_16x16x32_bf16(ah[t], wh, acc[t][jj], 0, 0, 0);
                    acc[t][jj] = __builtin_amdgcn_mfma_f32_16x16x32_bf16(al[t], wh, acc[t][jj], 0, 0, 0);
                    acc[t][jj] = __builtin_amdgcn_mfma_f32_16x16x32_bf16(ah[t], wl, acc[t][jj], 0, 0, 0);
                }
            }
        }
        __syncthreads();   // all C1 reads done before overwriting with M
        #pragma unroll
        for (int t = 0; t < 4; t++) {
            #pragma unroll
            for (int jj = 0; jj < 8; jj++) {
                const int n = jj * 16 + er;
                const float bv = eb2[n];
                float ms = 0.f;
                #pragma unroll
                for (int reg = 0; reg < 4; reg++) {
                    const int row = t * 16 + g * 4 + reg;   // u = g, kk = reg
                    float v = silu_f(acc[t][jj][reg] + bv);
                    if (reg < 3) ms += v;
                    short hh, ll; split2(v, hh, ll);
                    const int sidx = row * 128 + (n ^ ((row & 7) << 3));
                    C1h[sidx] = (unsigned short)hh;
                    C1l[sidx] = (unsigned short)ll;
                }
                msum[(size_t)((e0 + t) * 4 + g) * 128 + n] = f2bf(ms);
            }
        }
    }
    __syncthreads();

    // ---- phase 3: w = silu(m @ CW1 + cb1) @ cw2; emit xsum per (edge,u) ----
    {
        f32x4 acc[4][8];
        #pragma unroll
        for (int t = 0; t < 4; t++)
            #pragma unroll
            for (int jj = 0; jj < 8; jj++) acc[t][jj] = (f32x4){0.f, 0.f, 0.f, 0.f};

        #pragma unroll 1
        for (int kb = 0; kb < 4; kb++) {
            bf16x8 ah[4], al[4];
            #pragma unroll
            for (int t = 0; t < 4; t++) {
                const int row = t * 16 + er;
                const int aoff = row * 128 + ((kb * 32 + g * 8) ^ ((row & 7) << 3));
                ah[t] = *(const bf16x8*)&C1h[aoff];
                al[t] = *(const bf16x8*)&C1l[aoff];
            }
            #pragma unroll
            for (int jj = 0; jj < 8; jj++) {
                const int off = ((kb * 8 + jj) << 9) + (l << 3);
                bf16x8 wh = *(const bf16x8*)(c1f_hi + off);
                bf16x8 wl = *(const bf16x8*)(c1f_lo + off);
                #pragma unroll
                for (int t = 0; t < 4; t++) {
                    acc[t][jj] = __builtin_amdgcn_mfma_f32_16x16x32_bf16(ah[t], wh, acc[t][jj], 0, 0, 0);
                    acc[t][jj] = __builtin_amdgcn_mfma_f32_16x16x32_bf16(al[t], wh, acc[t][jj], 0, 0, 0);
                    acc[t][jj] = __builtin_amdgcn_mfma_f32_16x16x32_bf16(ah[t], wl, acc[t][jj], 0, 0, 0);
                }
            }
        }
        #pragma unroll
        for (int t = 0; t < 4; t++) {
            float p[4] = {0.f, 0.f, 0.f, 0.f};
            #pragma unroll
            for (int jj = 0; jj < 8; jj++) {
                const int n = jj * 16 + er;
                const float cb = cb1[n], cw = cw2v[n];
                #pragma unroll
                for (int reg = 0; reg < 4; reg++)
                    p[reg] += silu_f(acc[t][jj][reg] + cb) * cw;
            }
            #pragma unroll
            for (int d = 1; d < 16; d <<= 1) {
                #pragma unroll
                for (int reg = 0; reg < 4; reg++)
                    p[reg] += __shfl_xor(p[reg], d);
            }
            if (er < 3) {
                float xs = 0.f;
                #pragma unroll
                for (int reg = 0; reg < 3; reg++)
                    xs += diffS[(t * 16 + g * 4 + reg) * 3 + er] * p[reg];
                xsum[(size_t)((e0 + t) * 4 + g) * 3 + er] = xs;
            }
        }
    }
}

// ---------------- per-atom aggregation (CSR gather, no atomics) ----------------

__global__ __launch_bounds__(128) void k_agg(
    const unsigned short* __restrict__ msum, const float* __restrict__ xsum,
    const int* __restrict__ offB, const int* __restrict__ listE,
    const float* __restrict__ x,
    float* __restrict__ agg, float* __restrict__ xnext)
{
    const int a = blockIdx.x;
    const int b = a >> 2, u = a & 3;
    const int o0 = offB[b], o1 = offB[b + 1];
    const int tid = threadIdx.x;

    float s = 0.f;
    for (int pos = o0; pos < o1; pos++) {
        const int e = listE[pos];
        s += bf2f(msum[(size_t)(e * 4 + u) * 128 + tid]);
    }
    agg[(size_t)a * 128 + tid] = s;
    if (tid < 3) {
        float xs = 0.f;
        for (int pos = o0; pos < o1; pos++) {
            const int e = listE[pos];
            xs += xsum[(size_t)(e * 4 + u) * 3 + tid];
        }
        const int deg = o1 - o0;
        xnext[a * 3 + tid] = x[a * 3 + tid] + ((deg > 0) ? xs / (3.0f * (float)deg) : 0.f);
    }
}

// ---------------- generic tiled f32 GEMM (node / emb MLPs) ----------------

template<int KT, bool DOSILU, bool DORES, bool SPLIT>
__global__ __launch_bounds__(128) void k_gemm(
    const float* __restrict__ A0, const float* __restrict__ A1,
    const float* __restrict__ W, const float* __restrict__ bias,
    const float* __restrict__ R, float* __restrict__ C, int M)
{
    __shared__ float At[KT][32];
    __shared__ float Bs[32][128];
    const int tid = threadIdx.x;
    const int tile0 = blockIdx.x * 32;
    const int r = tid >> 2, part = tid & 3;
    const int gr = tile0 + r;

    if (gr < M) {
        const float* a0r = A0 + (size_t)gr * 128;
        #pragma unroll
        for (int j = 0; j < 8; j++) {
            int c = part * 32 + j * 4;
            float4 v = *(const float4*)(a0r + c);
            At[c][r] = v.x; At[c+1][r] = v.y; At[c+2][r] = v.z; At[c+3][r] = v.w;
        }
        if (SPLIT) {
            const float* a1r = A1 + (size_t)gr * 128;
            #pragma unroll
            for (int j = 0; j < 8; j++) {
                int c = part * 32 + j * 4;
                float4 v = *(const float4*)(a1r + c);
                At[128+c][r] = v.x; At[129+c][r] = v.y; At[130+c][r] = v.z; At[131+c][r] = v.w;
            }
        }
    } else {
        #pragma unroll
        for (int j = 0; j < 8; j++) {
            int c = part * 32 + j * 4;
            At[c][r] = 0.f; At[c+1][r] = 0.f; At[c+2][r] = 0.f; At[c+3][r] = 0.f;
            if (SPLIT) { At[128+c][r] = 0.f; At[129+c][r] = 0.f; At[130+c][r] = 0.f; At[131+c][r] = 0.f; }
        }
    }

    float acc[4][8];
    #pragma unroll
    for (int i = 0; i < 4; i++)
        #pragma unroll
        for (int j = 0; j < 8; j++) acc[i][j] = 0.f;

    const int tx = tid & 15, ty = tid >> 4;

    for (int kb = 0; kb < KT / 32; kb++) {
        __syncthreads();
        #pragma unroll
        for (int j = 0; j < 8; j++) {
            int li = j * 512 + tid * 4;
            int kk = li >> 7, c = li & 127;
            float4 v = *(const float4*)(W + (size_t)(kb * 32 + kk) * 128 + c);
            *(float4*)&Bs[kk][c] = v;
        }
        __syncthreads();
        #pragma unroll 8
        for (int kk = 0; kk < 32; kk++) {
            float4 a  = *(const float4*)&At[kb * 32 + kk][ty * 4];
            float4 b0 = *(const float4*)&Bs[kk][tx * 8];
            float4 b1 = *(const float4*)&Bs[kk][tx * 8 + 4];
            float av[4] = {a.x, a.y, a.z, a.w};
            float bv[8] = {b0.x, b0.y, b0.z, b0.w, b1.x, b1.y, b1.z, b1.w};
            #pragma unroll
            for (int i = 0; i < 4; i++)
                #pragma unroll
                for (int j = 0; j < 8; j++)
                    acc[i][j] = fmaf(av[i], bv[j], acc[i][j]);
        }
    }

    #pragma unroll
    for (int i = 0; i < 4; i++) {
        int grr = tile0 + ty * 4 + i;
        if (grr >= M) continue;
        #pragma unroll
        for (int j = 0; j < 8; j++) {
            int c = tx * 8 + j;
            float v = acc[i][j] + bias[c];
            if (DOSILU) v = v / (1.0f + expf(-v));
            if (DORES)  v += R[(size_t)grr * 128 + c];
            C[(size_t)grr * 128 + c] = v;
        }
    }
}

// ---------------- launch ----------------

extern "C" void kernel_launch(void* const* d_in, const int* in_sizes, int n_in,
                              void* d_out, int out_size, void* d_ws, size_t ws_size,
                              hipStream_t stream) {
    const float* H        = (const float*)d_in[0];
    const float* Z        = (const float*)d_in[1];
    const int*   edges    = (const int*)  d_in[4];
    const float* eattr    = (const float*)d_in[5];
    const float* emb_in_w = (const float*)d_in[6];
    const float* emb_in_b = (const float*)d_in[7];
    const float* emb_out_w= (const float*)d_in[8];
    const float* emb_out_b= (const float*)d_in[9];
    const float* edge_w1  = (const float*)d_in[10];
    const float* edge_b1  = (const float*)d_in[11];
    const float* edge_w2  = (const float*)d_in[12];
    const float* edge_b2  = (const float*)d_in[13];
    const float* node_w1  = (const float*)d_in[14];
    const float* node_b1  = (const float*)d_in[15];
    const float* node_w2  = (const float*)d_in[16];
    const float* node_b2  = (const float*)d_in[17];
    const float* coord_w1 = (const float*)d_in[18];
    const float* coord_b1 = (const float*)d_in[19];
    const float* coord_w2 = (const float*)d_in[20];

    float* out  = (float*)d_out;
    float* hbuf = out;                              // [N][128]
    float* xout = out + (size_t)NATOM * 128;        // [N][3]

    // workspace (~78 MB), 16B-aligned sections
    char* w = (char*)d_ws;
    float* agg = (float*)w;            w += (size_t)NATOM * 128 * 4;       // 40.96 MB
    float* xA  = (float*)w;            w += (size_t)NATOM * 3 * 4;
    float* xB  = (float*)w;            w += (size_t)NATOM * 3 * 4;
    unsigned short* msum = (unsigned short*)w;  w += (size_t)NGRP * 128 * 2;  // 30.72 MB
    float* xsum = (float*)w;           w += (size_t)NGRP * 3 * 4;            // 1.44 MB
    unsigned short* w1f_hi = (unsigned short*)w;  w += (size_t)3 * W1F_L * 2;
    unsigned short* w1f_lo = (unsigned short*)w;  w += (size_t)3 * W1F_L * 2;
    unsigned short* w2f_hi = (unsigned short*)w;  w += (size_t)3 * W2F_L * 2;
    unsigned short* w2f_lo = (unsigned short*)w;  w += (size_t)3 * W2F_L * 2;
    unsigned short* c1f_hi = (unsigned short*)w;  w += (size_t)3 * W2F_L * 2;
    unsigned short* c1f_lo = (unsigned short*)w;  w += (size_t)3 * W2F_L * 2;
    int* colIdx = (int*)w;             w += (size_t)EALL * 4;
    int* degB   = (int*)w;             w += (size_t)NBLK * 4;
    int* cursor = (int*)w;             w += (size_t)NBLK * 4;
    int* listE  = (int*)w;             w += (size_t)EBK * 4;
    int* offB   = (int*)w;             w += (size_t)(NBLK + 1) * 4;

    hipMemsetAsync(degB,   0, NBLK * sizeof(int), stream);
    hipMemsetAsync(cursor, 0, NBLK * sizeof(int), stream);

    k_count<<<(EBK + 255) / 256, 256, 0, stream>>>(edges, degB);
    k_scan <<<1, 1024, 0, stream>>>(degB, offB);
    k_fill <<<(EBK + 255) / 256, 256, 0, stream>>>(edges, offB, cursor, listE);
    k_topk <<<(EBK * UU + 255) / 256, 256, 0, stream>>>(edges, Z, colIdx);

    {
        int total = 3 * W1F_L + 3 * W2F_L + 3 * W2F_L;
        k_wfrag<<<(total + 255) / 256, 256, 0, stream>>>(
            edge_w1, edge_w2, coord_w1,
            w1f_hi, w1f_lo, w2f_hi, w2f_lo, c1f_hi, c1f_lo);
    }

    // h = H @ emb_in_w + b
    k_gemm<128, false, false, false><<<NATOM / 32, 128, 0, stream>>>(
        H, nullptr, emb_in_w, emb_in_b, nullptr, hbuf, NATOM);

    const float* xcur = Z;
    for (int l = 0; l < LAY; l++) {
        float* xnext = (l == 0) ? xA : (l == 1) ? xB : xout;

        k_edge_flat<<<EBK / 4, 64, 0, stream>>>(
            hbuf, xcur, eattr, edges, colIdx,
            w1f_hi + (size_t)l * W1F_L, w1f_lo + (size_t)l * W1F_L,
            w2f_hi + (size_t)l * W2F_L, w2f_lo + (size_t)l * W2F_L,
            c1f_hi + (size_t)l * W2F_L, c1f_lo + (size_t)l * W2F_L,
            edge_b1 + l * 128, edge_b2 + l * 128, coord_b1 + l * 128, coord_w2 + l * 128,
            msum, xsum);

        k_agg<<<NATOM, 128, 0, stream>>>(msum, xsum, offB, listE, xcur, agg, xnext);

        // node MLP: hidden = silu([h|agg] @ w1 + b1)  (in-place into agg)
        k_gemm<256, true, false, true><<<NATOM / 32, 128, 0, stream>>>(
            hbuf, agg, node_w1 + (size_t)l * 256 * 128, node_b1 + l * 128,
            nullptr, agg, NATOM);
        // h += hidden @ w2 + b2
        k_gemm<128, false, true, false><<<NATOM / 32, 128, 0, stream>>>(
            agg, nullptr, node_w2 + (size_t)l * 128 * 128, node_b2 + l * 128,
            hbuf, hbuf, NATOM);

        xcur = xnext;
    }

    k_gemm<128, false, false, false><<<NATOM / 32, 128, 0, stream>>>(
        hbuf, nullptr, emb_out_w, emb_out_b, nullptr, hbuf, NATOM);
}

// Round 7
// 1662.104 us; speedup vs baseline: 3.1860x; 3.1860x over previous
//
#include <hip/hip_runtime.h>
#include <math.h>

#define HIDC 128
#define EDGEF 16
#define LAY 3
#define KNN 3
#define UU 4
#define NBLK 20000
#define NATOM (NBLK*UU)      // 80000
#define EBK 30000
#define EALL (EBK*UU*KNN)    // 360000
#define NGRP (EBK*UU)        // 120000 (edge,u) groups

#define W1F_L 36864          // 9 kb * 8 j * 64 lanes * 8
#define W2F_L 16384          // 4 kb * 8 j * 64 lanes * 8

typedef __attribute__((ext_vector_type(8))) short bf16x8;
typedef __attribute__((ext_vector_type(4))) float f32x4;

__device__ __forceinline__ float silu_f(float v) {
    return v / (1.0f + expf(-v));
}

__device__ __forceinline__ unsigned short f2bf(float f) {
    union { float f; unsigned int u; } v; v.f = f;
    unsigned int r = v.u + 0x7FFFu + ((v.u >> 16) & 1u);
    return (unsigned short)(r >> 16);
}

__device__ __forceinline__ float bf2f(unsigned short h) {
    union { unsigned int u; float f; } t; t.u = ((unsigned int)h) << 16;
    return t.f;
}

// split f32 into bf16 hi + bf16 lo (x ~= hi + lo, ~17 mantissa bits)
__device__ __forceinline__ void split2(float v, short& hi, short& lo) {
    unsigned short h = f2bf(v);
    hi = (short)h;
    lo = (short)f2bf(v - bf2f(h));
}

// ---------------- CSR build ----------------

__global__ void k_count(const int* __restrict__ edges, int* __restrict__ degB) {
    int e = blockIdx.x * 256 + threadIdx.x;
    if (e < EBK) atomicAdd(&degB[edges[e]], 1);
}

__global__ void k_scan(const int* __restrict__ degB, int* __restrict__ offB) {
    __shared__ int s[1024];
    __shared__ int carry;
    if (threadIdx.x == 0) carry = 0;
    __syncthreads();
    for (int base = 0; base < NBLK; base += 1024) {
        int i = base + threadIdx.x;
        int v = (i < NBLK) ? degB[i] : 0;
        s[threadIdx.x] = v;
        __syncthreads();
        for (int d = 1; d < 1024; d <<= 1) {
            int t = (threadIdx.x >= d) ? s[threadIdx.x - d] : 0;
            __syncthreads();
            s[threadIdx.x] += t;
            __syncthreads();
        }
        if (i < NBLK) offB[i] = carry + s[threadIdx.x] - v;
        int tot = s[1023];
        __syncthreads();
        if (threadIdx.x == 0) carry += tot;
        __syncthreads();
    }
    if (threadIdx.x == 0) offB[NBLK] = carry;
}

__global__ void k_fill(const int* __restrict__ edges, const int* __restrict__ offB,
                       int* __restrict__ cursor, int* __restrict__ listE) {
    int e = blockIdx.x * 256 + threadIdx.x;
    if (e < EBK) {
        int b = edges[e];
        int p = atomicAdd(&cursor[b], 1);
        listE[offB[b] + p] = e;
    }
}

// top-3 nearest dst atoms per src atom; exact f32, tie -> lower index (matches top_k)
__global__ void k_topk(const int* __restrict__ edges, const float* __restrict__ Z,
                       int* __restrict__ colIdx) {
    int t = blockIdx.x * 256 + threadIdx.x;
    if (t >= EBK * UU) return;
    int e = t >> 2, u = t & 3;
    int b0 = edges[e], b1 = edges[EBK + e];
    int s = b0 * UU + u;
    float zs0 = Z[s*3+0], zs1 = Z[s*3+1], zs2 = Z[s*3+2];
    float d2[UU];
    #pragma unroll
    for (int v = 0; v < UU; v++) {
        int d = b1 * UU + v;
        float a0 = __fsub_rn(zs0, Z[d*3+0]);
        float a1 = __fsub_rn(zs1, Z[d*3+1]);
        float a2 = __fsub_rn(zs2, Z[d*3+2]);
        float p0 = __fmul_rn(a0, a0);
        float p1 = __fmul_rn(a1, a1);
        float p2 = __fmul_rn(a2, a2);
        d2[v] = __fadd_rn(__fadd_rn(p0, p1), p2);
    }
    bool used[UU] = {false, false, false, false};
    #pragma unroll
    for (int k = 0; k < KNN; k++) {
        int best = -1;
        float bd = INFINITY;
        #pragma unroll
        for (int v = 0; v < UU; v++) {
            if (!used[v] && d2[v] < bd) { bd = d2[v]; best = v; }
        }
        used[best] = true;
        colIdx[t * KNN + k] = b1 * UU + best;
    }
}

// ---------------- weight fragment precompute (hi/lo bf16, MFMA B-layout) ----------------
// frag chunk (kb,j): lane l holds W[kb*32 + (l>>4)*8 + t][j*16 + (l&15)], t=0..7

__global__ void k_wfrag(const float* __restrict__ ew1, const float* __restrict__ ew2,
                        const float* __restrict__ cw1,
                        unsigned short* __restrict__ w1f_hi, unsigned short* __restrict__ w1f_lo,
                        unsigned short* __restrict__ w2f_hi, unsigned short* __restrict__ w2f_lo,
                        unsigned short* __restrict__ c1f_hi, unsigned short* __restrict__ c1f_lo) {
    int i = blockIdx.x * 256 + threadIdx.x;
    float v;
    unsigned short* dh;
    unsigned short* dl;
    int di;
    if (i < 3 * W1F_L) {
        int l = i / W1F_L, rem = i % W1F_L;
        int chunk = rem >> 9, lane = (rem >> 3) & 63, t = rem & 7;
        int kb = chunk >> 3, j = chunk & 7;
        int k = kb*32 + (lane >> 4)*8 + t, n = j*16 + (lane & 15);
        v = (k < 273) ? ew1[(size_t)l*273*128 + (size_t)k*128 + n] : 0.f;
        dh = w1f_hi; dl = w1f_lo; di = i;
    } else {
        int i2 = i - 3 * W1F_L;
        if (i2 < 3 * W2F_L) {
            int l = i2 / W2F_L, rem = i2 % W2F_L;
            int chunk = rem >> 9, lane = (rem >> 3) & 63, t = rem & 7;
            int kb = chunk >> 3, j = chunk & 7;
            int k = kb*32 + (lane >> 4)*8 + t, n = j*16 + (lane & 15);
            v = ew2[(size_t)l*128*128 + (size_t)k*128 + n];
            dh = w2f_hi; dl = w2f_lo; di = i2;
        } else {
            int i3 = i2 - 3 * W2F_L;
            if (i3 >= 3 * W2F_L) return;
            int l = i3 / W2F_L, rem = i3 % W2F_L;
            int chunk = rem >> 9, lane = (rem >> 3) & 63, t = rem & 7;
            int kb = chunk >> 3, j = chunk & 7;
            int k = kb*32 + (lane >> 4)*8 + t, n = j*16 + (lane & 15);
            v = cw1[(size_t)l*128*128 + (size_t)k*128 + n];
            dh = c1f_hi; dl = c1f_lo; di = i3;
        }
    }
    short hi, lo;
    split2(v, hi, lo);
    dh[di] = (unsigned short)hi;
    dl[di] = (unsigned short)lo;
}

// ---------------- shared-weight fused edge pipeline (split-bf16 MFMA) ----------------
// Workgroup = 256 threads = 4 waves. Each wave owns one 16-row tile (one block-edge:
// 4 u-groups x 4 kk-slots, kk=3 duplicates kk=2). Weight chunks (16KB/kb hi+lo) are
// staged global->LDS once per workgroup and consumed by all 4 waves (4x L2-traffic cut).
// Per-wave acc[8] keeps VGPR low. Outputs per (edge,u): msum[128] bf16, xsum[3] f32.

__global__ __launch_bounds__(256, 3) void k_edge_shared(
    const float* __restrict__ hbuf,
    const float* __restrict__ x,
    const float* __restrict__ eattr,
    const int* __restrict__ edges0,
    const int* __restrict__ colIdx,
    const unsigned short* __restrict__ w1f_hi, const unsigned short* __restrict__ w1f_lo,
    const unsigned short* __restrict__ w2f_hi, const unsigned short* __restrict__ w2f_lo,
    const unsigned short* __restrict__ c1f_hi, const unsigned short* __restrict__ c1f_lo,
    const float* __restrict__ eb1,
    const float* __restrict__ eb2,
    const float* __restrict__ cb1,
    const float* __restrict__ cw2v,
    unsigned short* __restrict__ msum,
    float* __restrict__ xsum)
{
    __shared__ unsigned short wbufH[4096], wbufL[4096];      // 8KB + 8KB (one kb chunk)
    __shared__ unsigned short C1h[4][16 * 128], C1l[4][16 * 128];  // per-wave, reused for M
    __shared__ float diffS[4][48];

    const int tid = threadIdx.x;
    const int wid = tid >> 6, l = tid & 63;
    const int g = l >> 4, er = l & 15;
    const int u = er >> 2, kk = er & 3;
    const int kkc = (kk < 3) ? kk : 2;
    const int e = blockIdx.x * 4 + wid;

    const int bs = edges0[e];
    const int srcA = bs * 4 + u;
    const int colA = colIdx[(e * 4 + u) * 3 + kkc];
    float rad = 0.f;
    if (g == 0) {
        float dx = x[srcA*3+0] - x[colA*3+0];
        float dy = x[srcA*3+1] - x[colA*3+1];
        float dz = x[srcA*3+2] - x[colA*3+2];
        rad = dx*dx + dy*dy + dz*dz;
        diffS[wid][er*3+0] = dx; diffS[wid][er*3+1] = dy; diffS[wid][er*3+2] = dz;
    }

    // ---- phase 1: C1 = silu([h_r|h_c|rad|ea] @ W1 + b1), K=288 ----
    {
        f32x4 acc[8];
        #pragma unroll
        for (int jj = 0; jj < 8; jj++) acc[jj] = (f32x4){0.f, 0.f, 0.f, 0.f};

        #pragma unroll 1
        for (int kb = 0; kb < 9; kb++) {
            __syncthreads();   // previous kb's LDS reads done
            #pragma unroll
            for (int r = 0; r < 2; r++) {
                const int so = tid * 8 + r * 2048;
                *(bf16x8*)&wbufH[so] = *(const bf16x8*)(w1f_hi + (kb << 12) + so);
                *(bf16x8*)&wbufL[so] = *(const bf16x8*)(w1f_lo + (kb << 12) + so);
            }
            // build this kb's A fragment while staging is in flight
            bf16x8 ah, al;
            if (kb < 8) {
                const float* p0 = ((kb < 4) ? (hbuf + (size_t)srcA * 128 + kb * 32)
                                            : (hbuf + (size_t)colA * 128 + (kb - 4) * 32)) + g * 8;
                float4 v0 = *(const float4*)(p0);
                float4 v1 = *(const float4*)(p0 + 4);
                float vv[8] = {v0.x, v0.y, v0.z, v0.w, v1.x, v1.y, v1.z, v1.w};
                #pragma unroll
                for (int q = 0; q < 8; q++) { short hh, ll; split2(vv[q], hh, ll); ah[q] = hh; al[q] = ll; }
            } else {
                float tv[8];
                #pragma unroll
                for (int q = 0; q < 8; q++) tv[q] = 0.f;
                if (g == 0) {
                    tv[0] = rad;
                    #pragma unroll
                    for (int q = 1; q < 8; q++) tv[q] = eattr[(size_t)e*16 + (q-1)];
                } else if (g == 1) {
                    #pragma unroll
                    for (int q = 0; q < 8; q++) tv[q] = eattr[(size_t)e*16 + 7 + q];
                } else if (g == 2) {
                    tv[0] = eattr[(size_t)e*16 + 15];
                }
                #pragma unroll
                for (int q = 0; q < 8; q++) { short hh, ll; split2(tv[q], hh, ll); ah[q] = hh; al[q] = ll; }
            }
            __syncthreads();   // staging visible
            #pragma unroll
            for (int jj = 0; jj < 8; jj++) {
                const int off = (jj << 9) + (l << 3);
                bf16x8 wh = *(const bf16x8*)&wbufH[off];
                bf16x8 wl = *(const bf16x8*)&wbufL[off];
                acc[jj] = __builtin_amdgcn_mfma_f32_16x16x32_bf16(ah, wh, acc[jj], 0, 0, 0);
                acc[jj] = __builtin_amdgcn_mfma_f32_16x16x32_bf16(al, wh, acc[jj], 0, 0, 0);
                acc[jj] = __builtin_amdgcn_mfma_f32_16x16x32_bf16(ah, wl, acc[jj], 0, 0, 0);
            }
        }
        #pragma unroll
        for (int jj = 0; jj < 8; jj++) {
            const int n = jj * 16 + er;
            const float bv = eb1[n];
            #pragma unroll
            for (int reg = 0; reg < 4; reg++) {
                const int row = g * 4 + reg;
                float v = silu_f(acc[jj][reg] + bv);
                short hh, ll; split2(v, hh, ll);
                const int sidx = row * 128 + (n ^ ((row & 7) << 3));
                C1h[wid][sidx] = (unsigned short)hh;
                C1l[wid][sidx] = (unsigned short)ll;
            }
        }
    }

    // ---- phase 2: m = silu(C1 @ W2 + b2); emit kk-summed msum; stage M over C1 ----
    {
        f32x4 acc[8];
        #pragma unroll
        for (int jj = 0; jj < 8; jj++) acc[jj] = (f32x4){0.f, 0.f, 0.f, 0.f};

        #pragma unroll 1
        for (int kb = 0; kb < 4; kb++) {
            __syncthreads();
            #pragma unroll
            for (int r = 0; r < 2; r++) {
                const int so = tid * 8 + r * 2048;
                *(bf16x8*)&wbufH[so] = *(const bf16x8*)(w2f_hi + (kb << 12) + so);
                *(bf16x8*)&wbufL[so] = *(const bf16x8*)(w2f_lo + (kb << 12) + so);
            }
            const int aoff = er * 128 + ((kb * 32 + g * 8) ^ ((er & 7) << 3));
            bf16x8 ah = *(const bf16x8*)&C1h[wid][aoff];
            bf16x8 al = *(const bf16x8*)&C1l[wid][aoff];
            __syncthreads();
            #pragma unroll
            for (int jj = 0; jj < 8; jj++) {
                const int off = (jj << 9) + (l << 3);
                bf16x8 wh = *(const bf16x8*)&wbufH[off];
                bf16x8 wl = *(const bf16x8*)&wbufL[off];
                acc[jj] = __builtin_amdgcn_mfma_f32_16x16x32_bf16(ah, wh, acc[jj], 0, 0, 0);
                acc[jj] = __builtin_amdgcn_mfma_f32_16x16x32_bf16(al, wh, acc[jj], 0, 0, 0);
                acc[jj] = __builtin_amdgcn_mfma_f32_16x16x32_bf16(ah, wl, acc[jj], 0, 0, 0);
            }
        }
        #pragma unroll
        for (int jj = 0; jj < 8; jj++) {
            const int n = jj * 16 + er;
            const float bv = eb2[n];
            float ms = 0.f;
            #pragma unroll
            for (int reg = 0; reg < 4; reg++) {
                const int row = g * 4 + reg;       // u = g, kk = reg
                float v = silu_f(acc[jj][reg] + bv);
                if (reg < 3) ms += v;
                short hh, ll; split2(v, hh, ll);
                const int sidx = row * 128 + (n ^ ((row & 7) << 3));
                C1h[wid][sidx] = (unsigned short)hh;
                C1l[wid][sidx] = (unsigned short)ll;
            }
            msum[(size_t)(e * 4 + g) * 128 + n] = f2bf(ms);
        }
    }

    // ---- phase 3: w = silu(m @ CW1 + cb1) @ cw2; emit xsum per (edge,u) ----
    {
        f32x4 acc[8];
        #pragma unroll
        for (int jj = 0; jj < 8; jj++) acc[jj] = (f32x4){0.f, 0.f, 0.f, 0.f};

        #pragma unroll 1
        for (int kb = 0; kb < 4; kb++) {
            __syncthreads();
            #pragma unroll
            for (int r = 0; r < 2; r++) {
                const int so = tid * 8 + r * 2048;
                *(bf16x8*)&wbufH[so] = *(const bf16x8*)(c1f_hi + (kb << 12) + so);
                *(bf16x8*)&wbufL[so] = *(const bf16x8*)(c1f_lo + (kb << 12) + so);
            }
            const int aoff = er * 128 + ((kb * 32 + g * 8) ^ ((er & 7) << 3));
            bf16x8 ah = *(const bf16x8*)&C1h[wid][aoff];
            bf16x8 al = *(const bf16x8*)&C1l[wid][aoff];
            __syncthreads();
            #pragma unroll
            for (int jj = 0; jj < 8; jj++) {
                const int off = (jj << 9) + (l << 3);
                bf16x8 wh = *(const bf16x8*)&wbufH[off];
                bf16x8 wl = *(const bf16x8*)&wbufL[off];
                acc[jj] = __builtin_amdgcn_mfma_f32_16x16x32_bf16(ah, wh, acc[jj], 0, 0, 0);
                acc[jj] = __builtin_amdgcn_mfma_f32_16x16x32_bf16(al, wh, acc[jj], 0, 0, 0);
                acc[jj] = __builtin_amdgcn_mfma_f32_16x16x32_bf16(ah, wl, acc[jj], 0, 0, 0);
            }
        }
        float p[4] = {0.f, 0.f, 0.f, 0.f};
        #pragma unroll
        for (int jj = 0; jj < 8; jj++) {
            const int n = jj * 16 + er;
            const float cb = cb1[n], cw = cw2v[n];
            #pragma unroll
            for (int reg = 0; reg < 4; reg++)
                p[reg] += silu_f(acc[jj][reg] + cb) * cw;
        }
        #pragma unroll
        for (int d = 1; d < 16; d <<= 1) {
            #pragma unroll
            for (int reg = 0; reg < 4; reg++)
                p[reg] += __shfl_xor(p[reg], d);
        }
        if (er < 3) {
            float xs = 0.f;
            #pragma unroll
            for (int reg = 0; reg < 3; reg++)
                xs += diffS[wid][(g * 4 + reg) * 3 + er] * p[reg];
            xsum[(size_t)(e * 4 + g) * 3 + er] = xs;
        }
    }
}

// ---------------- per-atom aggregation (CSR gather, no atomics) ----------------

__global__ __launch_bounds__(128) void k_agg(
    const unsigned short* __restrict__ msum, const float* __restrict__ xsum,
    const int* __restrict__ offB, const int* __restrict__ listE,
    const float* __restrict__ x,
    float* __restrict__ agg, float* __restrict__ xnext)
{
    const int a = blockIdx.x;
    const int b = a >> 2, u = a & 3;
    const int o0 = offB[b], o1 = offB[b + 1];
    const int tid = threadIdx.x;

    float s = 0.f;
    for (int pos = o0; pos < o1; pos++) {
        const int e = listE[pos];
        s += bf2f(msum[(size_t)(e * 4 + u) * 128 + tid]);
    }
    agg[(size_t)a * 128 + tid] = s;
    if (tid < 3) {
        float xs = 0.f;
        for (int pos = o0; pos < o1; pos++) {
            const int e = listE[pos];
            xs += xsum[(size_t)(e * 4 + u) * 3 + tid];
        }
        const int deg = o1 - o0;
        xnext[a * 3 + tid] = x[a * 3 + tid] + ((deg > 0) ? xs / (3.0f * (float)deg) : 0.f);
    }
}

// ---------------- generic tiled f32 GEMM (node / emb MLPs) ----------------

template<int KT, bool DOSILU, bool DORES, bool SPLIT>
__global__ __launch_bounds__(128) void k_gemm(
    const float* __restrict__ A0, const float* __restrict__ A1,
    const float* __restrict__ W, const float* __restrict__ bias,
    const float* __restrict__ R, float* __restrict__ C, int M)
{
    __shared__ float At[KT][32];
    __shared__ float Bs[32][128];
    const int tid = threadIdx.x;
    const int tile0 = blockIdx.x * 32;
    const int r = tid >> 2, part = tid & 3;
    const int gr = tile0 + r;

    if (gr < M) {
        const float* a0r = A0 + (size_t)gr * 128;
        #pragma unroll
        for (int j = 0; j < 8; j++) {
            int c = part * 32 + j * 4;
            float4 v = *(const float4*)(a0r + c);
            At[c][r] = v.x; At[c+1][r] = v.y; At[c+2][r] = v.z; At[c+3][r] = v.w;
        }
        if (SPLIT) {
            const float* a1r = A1 + (size_t)gr * 128;
            #pragma unroll
            for (int j = 0; j < 8; j++) {
                int c = part * 32 + j * 4;
                float4 v = *(const float4*)(a1r + c);
                At[128+c][r] = v.x; At[129+c][r] = v.y; At[130+c][r] = v.z; At[131+c][r] = v.w;
            }
        }
    } else {
        #pragma unroll
        for (int j = 0; j < 8; j++) {
            int c = part * 32 + j * 4;
            At[c][r] = 0.f; At[c+1][r] = 0.f; At[c+2][r] = 0.f; At[c+3][r] = 0.f;
            if (SPLIT) { At[128+c][r] = 0.f; At[129+c][r] = 0.f; At[130+c][r] = 0.f; At[131+c][r] = 0.f; }
        }
    }

    float acc[4][8];
    #pragma unroll
    for (int i = 0; i < 4; i++)
        #pragma unroll
        for (int j = 0; j < 8; j++) acc[i][j] = 0.f;

    const int tx = tid & 15, ty = tid >> 4;

    for (int kb = 0; kb < KT / 32; kb++) {
        __syncthreads();
        #pragma unroll
        for (int j = 0; j < 8; j++) {
            int li = j * 512 + tid * 4;
            int kk = li >> 7, c = li & 127;
            float4 v = *(const float4*)(W + (size_t)(kb * 32 + kk) * 128 + c);
            *(float4*)&Bs[kk][c] = v;
        }
        __syncthreads();
        #pragma unroll 8
        for (int kk = 0; kk < 32; kk++) {
            float4 a  = *(const float4*)&At[kb * 32 + kk][ty * 4];
            float4 b0 = *(const float4*)&Bs[kk][tx * 8];
            float4 b1 = *(const float4*)&Bs[kk][tx * 8 + 4];
            float av[4] = {a.x, a.y, a.z, a.w};
            float bv[8] = {b0.x, b0.y, b0.z, b0.w, b1.x, b1.y, b1.z, b1.w};
            #pragma unroll
            for (int i = 0; i < 4; i++)
                #pragma unroll
                for (int j = 0; j < 8; j++)
                    acc[i][j] = fmaf(av[i], bv[j], acc[i][j]);
        }
    }

    #pragma unroll
    for (int i = 0; i < 4; i++) {
        int grr = tile0 + ty * 4 + i;
        if (grr >= M) continue;
        #pragma unroll
        for (int j = 0; j < 8; j++) {
            int c = tx * 8 + j;
            float v = acc[i][j] + bias[c];
            if (DOSILU) v = v / (1.0f + expf(-v));
            if (DORES)  v += R[(size_t)grr * 128 + c];
            C[(size_t)grr * 128 + c] = v;
        }
    }
}

// ---------------- launch ----------------

extern "C" void kernel_launch(void* const* d_in, const int* in_sizes, int n_in,
                              void* d_out, int out_size, void* d_ws, size_t ws_size,
                              hipStream_t stream) {
    const float* H        = (const float*)d_in[0];
    const float* Z        = (const float*)d_in[1];
    const int*   edges    = (const int*)  d_in[4];
    const float* eattr    = (const float*)d_in[5];
    const float* emb_in_w = (const float*)d_in[6];
    const float* emb_in_b = (const float*)d_in[7];
    const float* emb_out_w= (const float*)d_in[8];
    const float* emb_out_b= (const float*)d_in[9];
    const float* edge_w1  = (const float*)d_in[10];
    const float* edge_b1  = (const float*)d_in[11];
    const float* edge_w2  = (const float*)d_in[12];
    const float* edge_b2  = (const float*)d_in[13];
    const float* node_w1  = (const float*)d_in[14];
    const float* node_b1  = (const float*)d_in[15];
    const float* node_w2  = (const float*)d_in[16];
    const float* node_b2  = (const float*)d_in[17];
    const float* coord_w1 = (const float*)d_in[18];
    const float* coord_b1 = (const float*)d_in[19];
    const float* coord_w2 = (const float*)d_in[20];

    float* out  = (float*)d_out;
    float* hbuf = out;                              // [N][128]
    float* xout = out + (size_t)NATOM * 128;        // [N][3]

    // workspace (~78 MB), 16B-aligned sections
    char* w = (char*)d_ws;
    float* agg = (float*)w;            w += (size_t)NATOM * 128 * 4;       // 40.96 MB
    float* xA  = (float*)w;            w += (size_t)NATOM * 3 * 4;
    float* xB  = (float*)w;            w += (size_t)NATOM * 3 * 4;
    unsigned short* msum = (unsigned short*)w;  w += (size_t)NGRP * 128 * 2;  // 30.72 MB
    float* xsum = (float*)w;           w += (size_t)NGRP * 3 * 4;            // 1.44 MB
    unsigned short* w1f_hi = (unsigned short*)w;  w += (size_t)3 * W1F_L * 2;
    unsigned short* w1f_lo = (unsigned short*)w;  w += (size_t)3 * W1F_L * 2;
    unsigned short* w2f_hi = (unsigned short*)w;  w += (size_t)3 * W2F_L * 2;
    unsigned short* w2f_lo = (unsigned short*)w;  w += (size_t)3 * W2F_L * 2;
    unsigned short* c1f_hi = (unsigned short*)w;  w += (size_t)3 * W2F_L * 2;
    unsigned short* c1f_lo = (unsigned short*)w;  w += (size_t)3 * W2F_L * 2;
    int* colIdx = (int*)w;             w += (size_t)EALL * 4;
    int* degB   = (int*)w;             w += (size_t)NBLK * 4;
    int* cursor = (int*)w;             w += (size_t)NBLK * 4;
    int* listE  = (int*)w;             w += (size_t)EBK * 4;
    int* offB   = (int*)w;             w += (size_t)(NBLK + 1) * 4;

    hipMemsetAsync(degB,   0, NBLK * sizeof(int), stream);
    hipMemsetAsync(cursor, 0, NBLK * sizeof(int), stream);

    k_count<<<(EBK + 255) / 256, 256, 0, stream>>>(edges, degB);
    k_scan <<<1, 1024, 0, stream>>>(degB, offB);
    k_fill <<<(EBK + 255) / 256, 256, 0, stream>>>(edges, offB, cursor, listE);
    k_topk <<<(EBK * UU + 255) / 256, 256, 0, stream>>>(edges, Z, colIdx);

    {
        int total = 3 * W1F_L + 3 * W2F_L + 3 * W2F_L;
        k_wfrag<<<(total + 255) / 256, 256, 0, stream>>>(
            edge_w1, edge_w2, coord_w1,
            w1f_hi, w1f_lo, w2f_hi, w2f_lo, c1f_hi, c1f_lo);
    }

    // h = H @ emb_in_w + b
    k_gemm<128, false, false, false><<<NATOM / 32, 128, 0, stream>>>(
        H, nullptr, emb_in_w, emb_in_b, nullptr, hbuf, NATOM);

    const float* xcur = Z;
    for (int l = 0; l < LAY; l++) {
        float* xnext = (l == 0) ? xA : (l == 1) ? xB : xout;

        k_edge_shared<<<EBK / 4, 256, 0, stream>>>(
            hbuf, xcur, eattr, edges, colIdx,
            w1f_hi + (size_t)l * W1F_L, w1f_lo + (size_t)l * W1F_L,
            w2f_hi + (size_t)l * W2F_L, w2f_lo + (size_t)l * W2F_L,
            c1f_hi + (size_t)l * W2F_L, c1f_lo + (size_t)l * W2F_L,
            edge_b1 + l * 128, edge_b2 + l * 128, coord_b1 + l * 128, coord_w2 + l * 128,
            msum, xsum);

        k_agg<<<NATOM, 128, 0, stream>>>(msum, xsum, offB, listE, xcur, agg, xnext);

        // node MLP: hidden = silu([h|agg] @ w1 + b1)  (in-place into agg)
        k_gemm<256, true, false, true><<<NATOM / 32, 128, 0, stream>>>(
            hbuf, agg, node_w1 + (size_t)l * 256 * 128, node_b1 + l * 128,
            nullptr, agg, NATOM);
        // h += hidden @ w2 + b2
        k_gemm<128, false, true, false><<<NATOM / 32, 128, 0, stream>>>(
            agg, nullptr, node_w2 + (size_t)l * 128 * 128, node_b2 + l * 128,
            hbuf, hbuf, NATOM);

        xcur = xnext;
    }

    k_gemm<128, false, false, false><<<NATOM / 32, 128, 0, stream>>>(
        hbuf, nullptr, emb_out_w, emb_out_b, nullptr, hbuf, NATOM);
}

// Round 8
// 1251.227 us; speedup vs baseline: 4.2322x; 1.3284x over previous
//
#include <hip/hip_runtime.h>
#include <math.h>

#define HIDC 128
#define EDGEF 16
#define LAY 3
#define KNN 3
#define UU 4
#define NBLK 20000
#define NATOM (NBLK*UU)      // 80000
#define EBK 30000
#define EALL (EBK*UU*KNN)    // 360000
#define NGRP (EBK*UU)        // 120000 (edge,u) groups

#define W1F_L 36864          // 9 kb * 8 j * 64 lanes * 8
#define W2F_L 16384          // 4 kb * 8 j * 64 lanes * 8
#define NW1F_L 32768         // 8 kb * 8 j * 64 lanes * 8

typedef __attribute__((ext_vector_type(8))) short bf16x8;
typedef __attribute__((ext_vector_type(4))) float f32x4;

__device__ __forceinline__ float silu_f(float v) {
    return __fdividef(v, 1.0f + __expf(-v));
}

__device__ __forceinline__ unsigned short f2bf(float f) {
    union { float f; unsigned int u; } v; v.f = f;
    unsigned int r = v.u + 0x7FFFu + ((v.u >> 16) & 1u);
    return (unsigned short)(r >> 16);
}

__device__ __forceinline__ float bf2f(unsigned short h) {
    union { unsigned int u; float f; } t; t.u = ((unsigned int)h) << 16;
    return t.f;
}

// split f32 into bf16 hi + bf16 lo (x ~= hi + lo, ~17 mantissa bits)
__device__ __forceinline__ void split2(float v, short& hi, short& lo) {
    unsigned short h = f2bf(v);
    hi = (short)h;
    lo = (short)f2bf(v - bf2f(h));
}

__device__ __forceinline__ unsigned int packhl(float v) {
    short hi, lo; split2(v, hi, lo);
    return ((unsigned int)(unsigned short)hi << 16) | (unsigned short)lo;
}

__device__ __forceinline__ float unpackf(unsigned int u) {
    return bf2f((unsigned short)(u >> 16)) + bf2f((unsigned short)(u & 0xffffu));
}

__device__ __forceinline__ void unpack8(uint4 v0, uint4 v1, bf16x8& ah, bf16x8& al) {
    unsigned int uu[8] = {v0.x, v0.y, v0.z, v0.w, v1.x, v1.y, v1.z, v1.w};
    #pragma unroll
    for (int q = 0; q < 8; q++) {
        ah[q] = (short)(unsigned short)(uu[q] >> 16);
        al[q] = (short)(unsigned short)(uu[q] & 0xffffu);
    }
}

// ---------------- CSR build ----------------

__global__ void k_count(const int* __restrict__ edges, int* __restrict__ degB) {
    int e = blockIdx.x * 256 + threadIdx.x;
    if (e < EBK) atomicAdd(&degB[edges[e]], 1);
}

__global__ void k_scan(const int* __restrict__ degB, int* __restrict__ offB) {
    __shared__ int s[1024];
    __shared__ int carry;
    if (threadIdx.x == 0) carry = 0;
    __syncthreads();
    for (int base = 0; base < NBLK; base += 1024) {
        int i = base + threadIdx.x;
        int v = (i < NBLK) ? degB[i] : 0;
        s[threadIdx.x] = v;
        __syncthreads();
        for (int d = 1; d < 1024; d <<= 1) {
            int t = (threadIdx.x >= d) ? s[threadIdx.x - d] : 0;
            __syncthreads();
            s[threadIdx.x] += t;
            __syncthreads();
        }
        if (i < NBLK) offB[i] = carry + s[threadIdx.x] - v;
        int tot = s[1023];
        __syncthreads();
        if (threadIdx.x == 0) carry += tot;
        __syncthreads();
    }
    if (threadIdx.x == 0) offB[NBLK] = carry;
}

__global__ void k_fill(const int* __restrict__ edges, const int* __restrict__ offB,
                       int* __restrict__ cursor, int* __restrict__ listE) {
    int e = blockIdx.x * 256 + threadIdx.x;
    if (e < EBK) {
        int b = edges[e];
        int p = atomicAdd(&cursor[b], 1);
        listE[offB[b] + p] = e;
    }
}

// top-3 nearest dst atoms per src atom; exact f32, tie -> lower index (matches top_k)
__global__ void k_topk(const int* __restrict__ edges, const float* __restrict__ Z,
                       int* __restrict__ colIdx) {
    int t = blockIdx.x * 256 + threadIdx.x;
    if (t >= EBK * UU) return;
    int e = t >> 2, u = t & 3;
    int b0 = edges[e], b1 = edges[EBK + e];
    int s = b0 * UU + u;
    float zs0 = Z[s*3+0], zs1 = Z[s*3+1], zs2 = Z[s*3+2];
    float d2[UU];
    #pragma unroll
    for (int v = 0; v < UU; v++) {
        int d = b1 * UU + v;
        float a0 = __fsub_rn(zs0, Z[d*3+0]);
        float a1 = __fsub_rn(zs1, Z[d*3+1]);
        float a2 = __fsub_rn(zs2, Z[d*3+2]);
        float p0 = __fmul_rn(a0, a0);
        float p1 = __fmul_rn(a1, a1);
        float p2 = __fmul_rn(a2, a2);
        d2[v] = __fadd_rn(__fadd_rn(p0, p1), p2);
    }
    bool used[UU] = {false, false, false, false};
    #pragma unroll
    for (int k = 0; k < KNN; k++) {
        int best = -1;
        float bd = INFINITY;
        #pragma unroll
        for (int v = 0; v < UU; v++) {
            if (!used[v] && d2[v] < bd) { bd = d2[v]; best = v; }
        }
        used[best] = true;
        colIdx[t * KNN + k] = b1 * UU + best;
    }
}

// ---------------- weight fragment precompute (hi/lo bf16, MFMA B-layout) ----------------
// frag chunk (kb,j): lane l holds W[kb*32 + (l>>4)*8 + t][j*16 + (l&15)], t=0..7

__global__ void k_wfrag(const float* __restrict__ ew1, const float* __restrict__ ew2,
                        const float* __restrict__ cw1,
                        const float* __restrict__ nw1, const float* __restrict__ nw2,
                        unsigned short* __restrict__ w1f_hi, unsigned short* __restrict__ w1f_lo,
                        unsigned short* __restrict__ w2f_hi, unsigned short* __restrict__ w2f_lo,
                        unsigned short* __restrict__ c1f_hi, unsigned short* __restrict__ c1f_lo,
                        unsigned short* __restrict__ n1f_hi, unsigned short* __restrict__ n1f_lo,
                        unsigned short* __restrict__ n2f_hi, unsigned short* __restrict__ n2f_lo) {
    int i = blockIdx.x * 256 + threadIdx.x;
    float v = 0.f;
    unsigned short* dh = nullptr;
    unsigned short* dl = nullptr;
    int di = 0;
    if (i < 3 * W1F_L) {
        int l = i / W1F_L, rem = i % W1F_L;
        int chunk = rem >> 9, lane = (rem >> 3) & 63, t = rem & 7;
        int kb = chunk >> 3, j = chunk & 7;
        int k = kb*32 + (lane >> 4)*8 + t, n = j*16 + (lane & 15);
        v = (k < 273) ? ew1[(size_t)l*273*128 + (size_t)k*128 + n] : 0.f;
        dh = w1f_hi; dl = w1f_lo; di = i;
    } else {
        int i2 = i - 3 * W1F_L;
        if (i2 < 3 * W2F_L) {
            int l = i2 / W2F_L, rem = i2 % W2F_L;
            int chunk = rem >> 9, lane = (rem >> 3) & 63, t = rem & 7;
            int kb = chunk >> 3, j = chunk & 7;
            int k = kb*32 + (lane >> 4)*8 + t, n = j*16 + (lane & 15);
            v = ew2[(size_t)l*128*128 + (size_t)k*128 + n];
            dh = w2f_hi; dl = w2f_lo; di = i2;
        } else {
            int i3 = i2 - 3 * W2F_L;
            if (i3 < 3 * W2F_L) {
                int l = i3 / W2F_L, rem = i3 % W2F_L;
                int chunk = rem >> 9, lane = (rem >> 3) & 63, t = rem & 7;
                int kb = chunk >> 3, j = chunk & 7;
                int k = kb*32 + (lane >> 4)*8 + t, n = j*16 + (lane & 15);
                v = cw1[(size_t)l*128*128 + (size_t)k*128 + n];
                dh = c1f_hi; dl = c1f_lo; di = i3;
            } else {
                int i4 = i3 - 3 * W2F_L;
                if (i4 < 3 * NW1F_L) {
                    int l = i4 / NW1F_L, rem = i4 % NW1F_L;
                    int chunk = rem >> 9, lane = (rem >> 3) & 63, t = rem & 7;
                    int kb = chunk >> 3, j = chunk & 7;
                    int k = kb*32 + (lane >> 4)*8 + t, n = j*16 + (lane & 15);
                    v = nw1[(size_t)l*256*128 + (size_t)k*128 + n];
                    dh = n1f_hi; dl = n1f_lo; di = i4;
                } else {
                    int i5 = i4 - 3 * NW1F_L;
                    if (i5 >= 3 * W2F_L) return;
                    int l = i5 / W2F_L, rem = i5 % W2F_L;
                    int chunk = rem >> 9, lane = (rem >> 3) & 63, t = rem & 7;
                    int kb = chunk >> 3, j = chunk & 7;
                    int k = kb*32 + (lane >> 4)*8 + t, n = j*16 + (lane & 15);
                    v = nw2[(size_t)l*128*128 + (size_t)k*128 + n];
                    dh = n2f_hi; dl = n2f_lo; di = i5;
                }
            }
        }
    }
    short hi, lo;
    split2(v, hi, lo);
    dh[di] = (unsigned short)hi;
    dl[di] = (unsigned short)lo;
}

// ---------------- shared-weight fused edge pipeline (split-bf16 MFMA) ----------------
// Workgroup = 256 threads = 4 waves; each wave owns one block-edge (16 rows).
// h is packed hi/lo u32. Weight chunks staged global->LDS shared by 4 waves.

__global__ __launch_bounds__(256, 3) void k_edge_shared(
    const unsigned int* __restrict__ hp,
    const float* __restrict__ x,
    const float* __restrict__ eattr,
    const int* __restrict__ edges0,
    const int* __restrict__ colIdx,
    const unsigned short* __restrict__ w1f_hi, const unsigned short* __restrict__ w1f_lo,
    const unsigned short* __restrict__ w2f_hi, const unsigned short* __restrict__ w2f_lo,
    const unsigned short* __restrict__ c1f_hi, const unsigned short* __restrict__ c1f_lo,
    const float* __restrict__ eb1,
    const float* __restrict__ eb2,
    const float* __restrict__ cb1,
    const float* __restrict__ cw2v,
    unsigned short* __restrict__ msum,
    float* __restrict__ xsum)
{
    __shared__ unsigned short wbufH[4096], wbufL[4096];
    __shared__ unsigned short C1h[4][16 * 128], C1l[4][16 * 128];
    __shared__ float diffS[4][48];

    const int tid = threadIdx.x;
    const int wid = tid >> 6, l = tid & 63;
    const int g = l >> 4, er = l & 15;
    const int u = er >> 2, kk = er & 3;
    const int kkc = (kk < 3) ? kk : 2;
    const int e = blockIdx.x * 4 + wid;

    const int bs = edges0[e];
    const int srcA = bs * 4 + u;
    const int colA = colIdx[(e * 4 + u) * 3 + kkc];
    float rad = 0.f;
    if (g == 0) {
        float dx = x[srcA*3+0] - x[colA*3+0];
        float dy = x[srcA*3+1] - x[colA*3+1];
        float dz = x[srcA*3+2] - x[colA*3+2];
        rad = dx*dx + dy*dy + dz*dz;
        diffS[wid][er*3+0] = dx; diffS[wid][er*3+1] = dy; diffS[wid][er*3+2] = dz;
    }

    // ---- phase 1: C1 = silu([h_r|h_c|rad|ea] @ W1 + b1), K=288 ----
    {
        f32x4 acc[8];
        #pragma unroll
        for (int jj = 0; jj < 8; jj++) acc[jj] = (f32x4){0.f, 0.f, 0.f, 0.f};

        #pragma unroll 1
        for (int kb = 0; kb < 9; kb++) {
            __syncthreads();
            #pragma unroll
            for (int r = 0; r < 2; r++) {
                const int so = tid * 8 + r * 2048;
                *(bf16x8*)&wbufH[so] = *(const bf16x8*)(w1f_hi + (kb << 12) + so);
                *(bf16x8*)&wbufL[so] = *(const bf16x8*)(w1f_lo + (kb << 12) + so);
            }
            bf16x8 ah, al;
            if (kb < 8) {
                const unsigned int* src = (kb < 4) ? (hp + (size_t)srcA * 128 + kb * 32 + g * 8)
                                                   : (hp + (size_t)colA * 128 + (kb - 4) * 32 + g * 8);
                uint4 v0 = *(const uint4*)src;
                uint4 v1 = *((const uint4*)src + 1);
                unpack8(v0, v1, ah, al);
            } else {
                float tv[8];
                #pragma unroll
                for (int q = 0; q < 8; q++) tv[q] = 0.f;
                if (g == 0) {
                    tv[0] = rad;
                    #pragma unroll
                    for (int q = 1; q < 8; q++) tv[q] = eattr[(size_t)e*16 + (q-1)];
                } else if (g == 1) {
                    #pragma unroll
                    for (int q = 0; q < 8; q++) tv[q] = eattr[(size_t)e*16 + 7 + q];
                } else if (g == 2) {
                    tv[0] = eattr[(size_t)e*16 + 15];
                }
                #pragma unroll
                for (int q = 0; q < 8; q++) { short hh, ll; split2(tv[q], hh, ll); ah[q] = hh; al[q] = ll; }
            }
            __syncthreads();
            #pragma unroll
            for (int jj = 0; jj < 8; jj++) {
                const int off = (jj << 9) + (l << 3);
                bf16x8 wh = *(const bf16x8*)&wbufH[off];
                bf16x8 wl = *(const bf16x8*)&wbufL[off];
                acc[jj] = __builtin_amdgcn_mfma_f32_16x16x32_bf16(ah, wh, acc[jj], 0, 0, 0);
                acc[jj] = __builtin_amdgcn_mfma_f32_16x16x32_bf16(al, wh, acc[jj], 0, 0, 0);
                acc[jj] = __builtin_amdgcn_mfma_f32_16x16x32_bf16(ah, wl, acc[jj], 0, 0, 0);
            }
        }
        #pragma unroll
        for (int jj = 0; jj < 8; jj++) {
            const int n = jj * 16 + er;
            const float bv = eb1[n];
            #pragma unroll
            for (int reg = 0; reg < 4; reg++) {
                const int row = g * 4 + reg;
                float v = silu_f(acc[jj][reg] + bv);
                short hh, ll; split2(v, hh, ll);
                const int sidx = row * 128 + (n ^ ((row & 7) << 3));
                C1h[wid][sidx] = (unsigned short)hh;
                C1l[wid][sidx] = (unsigned short)ll;
            }
        }
    }

    // ---- phase 2: m = silu(C1 @ W2 + b2); emit kk-summed msum; stage M over C1 ----
    {
        f32x4 acc[8];
        #pragma unroll
        for (int jj = 0; jj < 8; jj++) acc[jj] = (f32x4){0.f, 0.f, 0.f, 0.f};

        #pragma unroll 1
        for (int kb = 0; kb < 4; kb++) {
            __syncthreads();
            #pragma unroll
            for (int r = 0; r < 2; r++) {
                const int so = tid * 8 + r * 2048;
                *(bf16x8*)&wbufH[so] = *(const bf16x8*)(w2f_hi + (kb << 12) + so);
                *(bf16x8*)&wbufL[so] = *(const bf16x8*)(w2f_lo + (kb << 12) + so);
            }
            const int aoff = er * 128 + ((kb * 32 + g * 8) ^ ((er & 7) << 3));
            bf16x8 ah = *(const bf16x8*)&C1h[wid][aoff];
            bf16x8 al = *(const bf16x8*)&C1l[wid][aoff];
            __syncthreads();
            #pragma unroll
            for (int jj = 0; jj < 8; jj++) {
                const int off = (jj << 9) + (l << 3);
                bf16x8 wh = *(const bf16x8*)&wbufH[off];
                bf16x8 wl = *(const bf16x8*)&wbufL[off];
                acc[jj] = __builtin_amdgcn_mfma_f32_16x16x32_bf16(ah, wh, acc[jj], 0, 0, 0);
                acc[jj] = __builtin_amdgcn_mfma_f32_16x16x32_bf16(al, wh, acc[jj], 0, 0, 0);
                acc[jj] = __builtin_amdgcn_mfma_f32_16x16x32_bf16(ah, wl, acc[jj], 0, 0, 0);
            }
        }
        #pragma unroll
        for (int jj = 0; jj < 8; jj++) {
            const int n = jj * 16 + er;
            const float bv = eb2[n];
            float ms = 0.f;
            #pragma unroll
            for (int reg = 0; reg < 4; reg++) {
                const int row = g * 4 + reg;       // u = g, kk = reg
                float v = silu_f(acc[jj][reg] + bv);
                if (reg < 3) ms += v;
                short hh, ll; split2(v, hh, ll);
                const int sidx = row * 128 + (n ^ ((row & 7) << 3));
                C1h[wid][sidx] = (unsigned short)hh;
                C1l[wid][sidx] = (unsigned short)ll;
            }
            msum[(size_t)(e * 4 + g) * 128 + n] = f2bf(ms);
        }
    }

    // ---- phase 3: w = silu(m @ CW1 + cb1) @ cw2; emit xsum per (edge,u) ----
    {
        f32x4 acc[8];
        #pragma unroll
        for (int jj = 0; jj < 8; jj++) acc[jj] = (f32x4){0.f, 0.f, 0.f, 0.f};

        #pragma unroll 1
        for (int kb = 0; kb < 4; kb++) {
            __syncthreads();
            #pragma unroll
            for (int r = 0; r < 2; r++) {
                const int so = tid * 8 + r * 2048;
                *(bf16x8*)&wbufH[so] = *(const bf16x8*)(c1f_hi + (kb << 12) + so);
                *(bf16x8*)&wbufL[so] = *(const bf16x8*)(c1f_lo + (kb << 12) + so);
            }
            const int aoff = er * 128 + ((kb * 32 + g * 8) ^ ((er & 7) << 3));
            bf16x8 ah = *(const bf16x8*)&C1h[wid][aoff];
            bf16x8 al = *(const bf16x8*)&C1l[wid][aoff];
            __syncthreads();
            #pragma unroll
            for (int jj = 0; jj < 8; jj++) {
                const int off = (jj << 9) + (l << 3);
                bf16x8 wh = *(const bf16x8*)&wbufH[off];
                bf16x8 wl = *(const bf16x8*)&wbufL[off];
                acc[jj] = __builtin_amdgcn_mfma_f32_16x16x32_bf16(ah, wh, acc[jj], 0, 0, 0);
                acc[jj] = __builtin_amdgcn_mfma_f32_16x16x32_bf16(al, wh, acc[jj], 0, 0, 0);
                acc[jj] = __builtin_amdgcn_mfma_f32_16x16x32_bf16(ah, wl, acc[jj], 0, 0, 0);
            }
        }
        float p[4] = {0.f, 0.f, 0.f, 0.f};
        #pragma unroll
        for (int jj = 0; jj < 8; jj++) {
            const int n = jj * 16 + er;
            const float cb = cb1[n], cw = cw2v[n];
            #pragma unroll
            for (int reg = 0; reg < 4; reg++)
                p[reg] += silu_f(acc[jj][reg] + cb) * cw;
        }
        #pragma unroll
        for (int d = 1; d < 16; d <<= 1) {
            #pragma unroll
            for (int reg = 0; reg < 4; reg++)
                p[reg] += __shfl_xor(p[reg], d);
        }
        if (er < 3) {
            float xs = 0.f;
            #pragma unroll
            for (int reg = 0; reg < 3; reg++)
                xs += diffS[wid][(g * 4 + reg) * 3 + er] * p[reg];
            xsum[(size_t)(e * 4 + g) * 3 + er] = xs;
        }
    }
}

// ---------------- per-atom aggregation (CSR gather, no atomics) ----------------

__global__ __launch_bounds__(128) void k_agg(
    const unsigned short* __restrict__ msum, const float* __restrict__ xsum,
    const int* __restrict__ offB, const int* __restrict__ listE,
    const float* __restrict__ x,
    unsigned int* __restrict__ aggp, float* __restrict__ xnext)
{
    const int a = blockIdx.x;
    const int b = a >> 2, u = a & 3;
    const int o0 = offB[b], o1 = offB[b + 1];
    const int tid = threadIdx.x;

    float s = 0.f;
    for (int pos = o0; pos < o1; pos++) {
        const int e = listE[pos];
        s += bf2f(msum[(size_t)(e * 4 + u) * 128 + tid]);
    }
    aggp[(size_t)a * 128 + tid] = packhl(s);
    if (tid < 3) {
        float xs = 0.f;
        for (int pos = o0; pos < o1; pos++) {
            const int e = listE[pos];
            xs += xsum[(size_t)(e * 4 + u) * 3 + tid];
        }
        const int deg = o1 - o0;
        xnext[a * 3 + tid] = x[a * 3 + tid] + ((deg > 0) ? xs / (3.0f * (float)deg) : 0.f);
    }
}

// ---------------- fused node MLP (split-bf16 MFMA, shared weights) ----------------
// WG = 256 = 4 waves; each wave owns 16 atoms. h_new = h + silu([h|agg]@w1+b1)@w2+b2.
// h and agg packed hi/lo u32. In-place on hp (each WG touches only own rows).

__global__ __launch_bounds__(256, 3) void k_node(
    unsigned int* __restrict__ hp,
    const unsigned int* __restrict__ aggp,
    const unsigned short* __restrict__ n1f_hi, const unsigned short* __restrict__ n1f_lo,
    const unsigned short* __restrict__ n2f_hi, const unsigned short* __restrict__ n2f_lo,
    const float* __restrict__ nb1,
    const float* __restrict__ nb2)
{
    __shared__ unsigned short wbufH[4096], wbufL[4096];
    __shared__ unsigned short hidH[4][16 * 128], hidL[4][16 * 128];

    const int tid = threadIdx.x;
    const int wid = tid >> 6, l = tid & 63;
    const int g = l >> 4, er = l & 15;
    const int a0 = blockIdx.x * 64 + wid * 16;

    // ---- phase A: hid = silu([h|agg] @ W1 + b1), K=256 ----
    {
        f32x4 acc[8];
        #pragma unroll
        for (int jj = 0; jj < 8; jj++) acc[jj] = (f32x4){0.f, 0.f, 0.f, 0.f};

        #pragma unroll 1
        for (int kb = 0; kb < 8; kb++) {
            __syncthreads();
            #pragma unroll
            for (int r = 0; r < 2; r++) {
                const int so = tid * 8 + r * 2048;
                *(bf16x8*)&wbufH[so] = *(const bf16x8*)(n1f_hi + (kb << 12) + so);
                *(bf16x8*)&wbufL[so] = *(const bf16x8*)(n1f_lo + (kb << 12) + so);
            }
            const unsigned int* src = (kb < 4)
                ? (hp   + (size_t)(a0 + er) * 128 + kb * 32 + g * 8)
                : (aggp + (size_t)(a0 + er) * 128 + (kb - 4) * 32 + g * 8);
            uint4 v0 = *(const uint4*)src;
            uint4 v1 = *((const uint4*)src + 1);
            bf16x8 ah, al;
            unpack8(v0, v1, ah, al);
            __syncthreads();
            #pragma unroll
            for (int jj = 0; jj < 8; jj++) {
                const int off = (jj << 9) + (l << 3);
                bf16x8 wh = *(const bf16x8*)&wbufH[off];
                bf16x8 wl = *(const bf16x8*)&wbufL[off];
                acc[jj] = __builtin_amdgcn_mfma_f32_16x16x32_bf16(ah, wh, acc[jj], 0, 0, 0);
                acc[jj] = __builtin_amdgcn_mfma_f32_16x16x32_bf16(al, wh, acc[jj], 0, 0, 0);
                acc[jj] = __builtin_amdgcn_mfma_f32_16x16x32_bf16(ah, wl, acc[jj], 0, 0, 0);
            }
        }
        #pragma unroll
        for (int jj = 0; jj < 8; jj++) {
            const int n = jj * 16 + er;
            const float bv = nb1[n];
            #pragma unroll
            for (int reg = 0; reg < 4; reg++) {
                const int row = g * 4 + reg;
                float v = silu_f(acc[jj][reg] + bv);
                short hh, ll; split2(v, hh, ll);
                const int sidx = row * 128 + (n ^ ((row & 7) << 3));
                hidH[wid][sidx] = (unsigned short)hh;
                hidL[wid][sidx] = (unsigned short)ll;
            }
        }
    }

    // ---- phase B: h += hid @ W2 + b2, K=128 ----
    {
        f32x4 acc[8];
        #pragma unroll
        for (int jj = 0; jj < 8; jj++) acc[jj] = (f32x4){0.f, 0.f, 0.f, 0.f};

        #pragma unroll 1
        for (int kb = 0; kb < 4; kb++) {
            __syncthreads();
            #pragma unroll
            for (int r = 0; r < 2; r++) {
                const int so = tid * 8 + r * 2048;
                *(bf16x8*)&wbufH[so] = *(const bf16x8*)(n2f_hi + (kb << 12) + so);
                *(bf16x8*)&wbufL[so] = *(const bf16x8*)(n2f_lo + (kb << 12) + so);
            }
            const int aoff = er * 128 + ((kb * 32 + g * 8) ^ ((er & 7) << 3));
            bf16x8 ah = *(const bf16x8*)&hidH[wid][aoff];
            bf16x8 al = *(const bf16x8*)&hidL[wid][aoff];
            __syncthreads();
            #pragma unroll
            for (int jj = 0; jj < 8; jj++) {
                const int off = (jj << 9) + (l << 3);
                bf16x8 wh = *(const bf16x8*)&wbufH[off];
                bf16x8 wl = *(const bf16x8*)&wbufL[off];
                acc[jj] = __builtin_amdgcn_mfma_f32_16x16x32_bf16(ah, wh, acc[jj], 0, 0, 0);
                acc[jj] = __builtin_amdgcn_mfma_f32_16x16x32_bf16(al, wh, acc[jj], 0, 0, 0);
                acc[jj] = __builtin_amdgcn_mfma_f32_16x16x32_bf16(ah, wl, acc[jj], 0, 0, 0);
            }
        }
        #pragma unroll
        for (int jj = 0; jj < 8; jj++) {
            const int n = jj * 16 + er;
            const float bv = nb2[n];
            #pragma unroll
            for (int reg = 0; reg < 4; reg++) {
                const int row = g * 4 + reg;
                const size_t idx = (size_t)(a0 + row) * 128 + n;
                float v = acc[jj][reg] + bv + unpackf(hp[idx]);
                hp[idx] = packhl(v);
            }
        }
    }
}

// ---------------- generic tiled f32 GEMM (emb MLPs; pack/unpack variants) ----------------

template<int KT, bool PACKIN, bool PACKOUT>
__global__ __launch_bounds__(128) void k_gemm(
    const float* __restrict__ A0,
    const float* __restrict__ W, const float* __restrict__ bias,
    float* __restrict__ C, int M)
{
    __shared__ float At[KT][32];
    __shared__ float Bs[32][128];
    const int tid = threadIdx.x;
    const int tile0 = blockIdx.x * 32;
    const int r = tid >> 2, part = tid & 3;
    const int gr = tile0 + r;

    if (gr < M) {
        #pragma unroll
        for (int j = 0; j < 8; j++) {
            int c = part * 32 + j * 4;
            float f0, f1, f2, f3;
            if (PACKIN) {
                const unsigned int* ap = (const unsigned int*)A0 + (size_t)gr * 128 + c;
                uint4 v = *(const uint4*)ap;
                f0 = unpackf(v.x); f1 = unpackf(v.y); f2 = unpackf(v.z); f3 = unpackf(v.w);
            } else {
                float4 v = *(const float4*)(A0 + (size_t)gr * 128 + c);
                f0 = v.x; f1 = v.y; f2 = v.z; f3 = v.w;
            }
            At[c][r] = f0; At[c+1][r] = f1; At[c+2][r] = f2; At[c+3][r] = f3;
        }
    } else {
        #pragma unroll
        for (int j = 0; j < 8; j++) {
            int c = part * 32 + j * 4;
            At[c][r] = 0.f; At[c+1][r] = 0.f; At[c+2][r] = 0.f; At[c+3][r] = 0.f;
        }
    }

    float acc[4][8];
    #pragma unroll
    for (int i = 0; i < 4; i++)
        #pragma unroll
        for (int j = 0; j < 8; j++) acc[i][j] = 0.f;

    const int tx = tid & 15, ty = tid >> 4;

    for (int kb = 0; kb < KT / 32; kb++) {
        __syncthreads();
        #pragma unroll
        for (int j = 0; j < 8; j++) {
            int li = j * 512 + tid * 4;
            int kk = li >> 7, c = li & 127;
            float4 v = *(const float4*)(W + (size_t)(kb * 32 + kk) * 128 + c);
            *(float4*)&Bs[kk][c] = v;
        }
        __syncthreads();
        #pragma unroll 8
        for (int kk = 0; kk < 32; kk++) {
            float4 a  = *(const float4*)&At[kb * 32 + kk][ty * 4];
            float4 b0 = *(const float4*)&Bs[kk][tx * 8];
            float4 b1 = *(const float4*)&Bs[kk][tx * 8 + 4];
            float av[4] = {a.x, a.y, a.z, a.w};
            float bv[8] = {b0.x, b0.y, b0.z, b0.w, b1.x, b1.y, b1.z, b1.w};
            #pragma unroll
            for (int i = 0; i < 4; i++)
                #pragma unroll
                for (int j = 0; j < 8; j++)
                    acc[i][j] = fmaf(av[i], bv[j], acc[i][j]);
        }
    }

    #pragma unroll
    for (int i = 0; i < 4; i++) {
        int grr = tile0 + ty * 4 + i;
        if (grr >= M) continue;
        #pragma unroll
        for (int j = 0; j < 8; j++) {
            int c = tx * 8 + j;
            float v = acc[i][j] + bias[c];
            if (PACKOUT) ((unsigned int*)C)[(size_t)grr * 128 + c] = packhl(v);
            else         C[(size_t)grr * 128 + c] = v;
        }
    }
}

// ---------------- launch ----------------

extern "C" void kernel_launch(void* const* d_in, const int* in_sizes, int n_in,
                              void* d_out, int out_size, void* d_ws, size_t ws_size,
                              hipStream_t stream) {
    const float* H        = (const float*)d_in[0];
    const float* Z        = (const float*)d_in[1];
    const int*   edges    = (const int*)  d_in[4];
    const float* eattr    = (const float*)d_in[5];
    const float* emb_in_w = (const float*)d_in[6];
    const float* emb_in_b = (const float*)d_in[7];
    const float* emb_out_w= (const float*)d_in[8];
    const float* emb_out_b= (const float*)d_in[9];
    const float* edge_w1  = (const float*)d_in[10];
    const float* edge_b1  = (const float*)d_in[11];
    const float* edge_w2  = (const float*)d_in[12];
    const float* edge_b2  = (const float*)d_in[13];
    const float* node_w1  = (const float*)d_in[14];
    const float* node_b1  = (const float*)d_in[15];
    const float* node_w2  = (const float*)d_in[16];
    const float* node_b2  = (const float*)d_in[17];
    const float* coord_w1 = (const float*)d_in[18];
    const float* coord_b1 = (const float*)d_in[19];
    const float* coord_w2 = (const float*)d_in[20];

    float* out  = (float*)d_out;
    float* hbuf = out;                              // [N][128]  (packed u32 during layers)
    unsigned int* hp = (unsigned int*)hbuf;
    float* xout = out + (size_t)NATOM * 128;        // [N][3]

    // workspace (~78 MB), 16B-aligned sections
    char* w = (char*)d_ws;
    unsigned int* aggp = (unsigned int*)w;  w += (size_t)NATOM * 128 * 4;   // 40.96 MB
    float* xA  = (float*)w;            w += (size_t)NATOM * 3 * 4;
    float* xB  = (float*)w;            w += (size_t)NATOM * 3 * 4;
    unsigned short* msum = (unsigned short*)w;  w += (size_t)NGRP * 128 * 2;  // 30.72 MB
    float* xsum = (float*)w;           w += (size_t)NGRP * 3 * 4;            // 1.44 MB
    unsigned short* w1f_hi = (unsigned short*)w;  w += (size_t)3 * W1F_L * 2;
    unsigned short* w1f_lo = (unsigned short*)w;  w += (size_t)3 * W1F_L * 2;
    unsigned short* w2f_hi = (unsigned short*)w;  w += (size_t)3 * W2F_L * 2;
    unsigned short* w2f_lo = (unsigned short*)w;  w += (size_t)3 * W2F_L * 2;
    unsigned short* c1f_hi = (unsigned short*)w;  w += (size_t)3 * W2F_L * 2;
    unsigned short* c1f_lo = (unsigned short*)w;  w += (size_t)3 * W2F_L * 2;
    unsigned short* n1f_hi = (unsigned short*)w;  w += (size_t)3 * NW1F_L * 2;
    unsigned short* n1f_lo = (unsigned short*)w;  w += (size_t)3 * NW1F_L * 2;
    unsigned short* n2f_hi = (unsigned short*)w;  w += (size_t)3 * W2F_L * 2;
    unsigned short* n2f_lo = (unsigned short*)w;  w += (size_t)3 * W2F_L * 2;
    int* colIdx = (int*)w;             w += (size_t)EALL * 4;
    int* degB   = (int*)w;             w += (size_t)NBLK * 4;
    int* cursor = (int*)w;             w += (size_t)NBLK * 4;
    int* listE  = (int*)w;             w += (size_t)EBK * 4;
    int* offB   = (int*)w;             w += (size_t)(NBLK + 1) * 4;

    hipMemsetAsync(degB,   0, NBLK * sizeof(int), stream);
    hipMemsetAsync(cursor, 0, NBLK * sizeof(int), stream);

    k_count<<<(EBK + 255) / 256, 256, 0, stream>>>(edges, degB);
    k_scan <<<1, 1024, 0, stream>>>(degB, offB);
    k_fill <<<(EBK + 255) / 256, 256, 0, stream>>>(edges, offB, cursor, listE);
    k_topk <<<(EBK * UU + 255) / 256, 256, 0, stream>>>(edges, Z, colIdx);

    {
        int total = 3 * W1F_L + 3 * W2F_L + 3 * W2F_L + 3 * NW1F_L + 3 * W2F_L;
        k_wfrag<<<(total + 255) / 256, 256, 0, stream>>>(
            edge_w1, edge_w2, coord_w1, node_w1, node_w2,
            w1f_hi, w1f_lo, w2f_hi, w2f_lo, c1f_hi, c1f_lo,
            n1f_hi, n1f_lo, n2f_hi, n2f_lo);
    }

    // h = H @ emb_in_w + b  (write packed hi/lo)
    k_gemm<128, false, true><<<NATOM / 32, 128, 0, stream>>>(
        H, emb_in_w, emb_in_b, (float*)hp, NATOM);

    const float* xcur = Z;
    for (int l = 0; l < LAY; l++) {
        float* xnext = (l == 0) ? xA : (l == 1) ? xB : xout;

        k_edge_shared<<<EBK / 4, 256, 0, stream>>>(
            hp, xcur, eattr, edges, colIdx,
            w1f_hi + (size_t)l * W1F_L, w1f_lo + (size_t)l * W1F_L,
            w2f_hi + (size_t)l * W2F_L, w2f_lo + (size_t)l * W2F_L,
            c1f_hi + (size_t)l * W2F_L, c1f_lo + (size_t)l * W2F_L,
            edge_b1 + l * 128, edge_b2 + l * 128, coord_b1 + l * 128, coord_w2 + l * 128,
            msum, xsum);

        k_agg<<<NATOM, 128, 0, stream>>>(msum, xsum, offB, listE, xcur, aggp, xnext);

        k_node<<<NATOM / 64, 256, 0, stream>>>(
            hp, aggp,
            n1f_hi + (size_t)l * NW1F_L, n1f_lo + (size_t)l * NW1F_L,
            n2f_hi + (size_t)l * W2F_L, n2f_lo + (size_t)l * W2F_L,
            node_b1 + l * 128, node_b2 + l * 128);

        xcur = xnext;
    }

    // h_out = h @ emb_out_w + b  (read packed, write f32 in-place)
    k_gemm<128, true, false><<<NATOM / 32, 128, 0, stream>>>(
        hbuf, emb_out_w, emb_out_b, hbuf, NATOM);
}

// Round 9
// 1099.538 us; speedup vs baseline: 4.8161x; 1.1380x over previous
//
#include <hip/hip_runtime.h>
#include <math.h>

#define HIDC 128
#define EDGEF 16
#define LAY 3
#define KNN 3
#define UU 4
#define NBLK 20000
#define NATOM (NBLK*UU)      // 80000
#define EBK 30000
#define EALL (EBK*UU*KNN)    // 360000
#define NGRP (EBK*UU)        // 120000 (edge,u) groups

#define W1F_L 36864          // 9 kb * 8 j * 64 lanes * 8
#define W2F_L 16384          // 4 kb * 8 j * 64 lanes * 8
#define NW1F_L 32768         // 8 kb * 8 j * 64 lanes * 8

typedef __attribute__((ext_vector_type(8))) short bf16x8;
typedef __attribute__((ext_vector_type(4))) float f32x4;

__device__ __forceinline__ float silu_f(float v) {
    return __fdividef(v, 1.0f + __expf(-v));
}

__device__ __forceinline__ unsigned short f2bf(float f) {
    union { float f; unsigned int u; } v; v.f = f;
    unsigned int r = v.u + 0x7FFFu + ((v.u >> 16) & 1u);
    return (unsigned short)(r >> 16);
}

__device__ __forceinline__ float bf2f(unsigned short h) {
    union { unsigned int u; float f; } t; t.u = ((unsigned int)h) << 16;
    return t.f;
}

// full-precision split (RNE hi) — used in one-time weight prep only
__device__ __forceinline__ void split2(float v, short& hi, short& lo) {
    unsigned short h = f2bf(v);
    hi = (short)h;
    lo = (short)f2bf(v - bf2f(h));
}

// cheap split: truncated hi + RNE lo (lo captures truncation exactly; ~2^-17 rel)
__device__ __forceinline__ void csplit(float v, unsigned short& hi, unsigned short& lo) {
    unsigned int hu = __float_as_uint(v) & 0xffff0000u;
    hi = (unsigned short)(hu >> 16);
    lo = f2bf(v - __uint_as_float(hu));
}

__device__ __forceinline__ unsigned int packhl(float v) {
    unsigned int hu = __float_as_uint(v) & 0xffff0000u;
    return hu | (unsigned int)f2bf(v - __uint_as_float(hu));
}

__device__ __forceinline__ float unpackf(unsigned int u) {
    return bf2f((unsigned short)(u >> 16)) + bf2f((unsigned short)(u & 0xffffu));
}

__device__ __forceinline__ void unpack8(uint4 v0, uint4 v1, bf16x8& ah, bf16x8& al) {
    unsigned int uu[8] = {v0.x, v0.y, v0.z, v0.w, v1.x, v1.y, v1.z, v1.w};
    #pragma unroll
    for (int q = 0; q < 8; q++) {
        ah[q] = (short)(unsigned short)(uu[q] >> 16);
        al[q] = (short)(unsigned short)(uu[q] & 0xffffu);
    }
}

// async global->LDS DMA: 16B per lane, LDS dest = wave-uniform base + lane*16
__device__ __forceinline__ void stage16(const unsigned short* gsrc, unsigned short* ldst) {
    __builtin_amdgcn_global_load_lds(
        (const __attribute__((address_space(1))) unsigned int*)(const void*)gsrc,
        (__attribute__((address_space(3))) unsigned int*)(void*)ldst,
        16, 0, 0);
}

// ---------------- CSR build ----------------

__global__ void k_count(const int* __restrict__ edges, int* __restrict__ degB) {
    int e = blockIdx.x * 256 + threadIdx.x;
    if (e < EBK) atomicAdd(&degB[edges[e]], 1);
}

__global__ void k_scan(const int* __restrict__ degB, int* __restrict__ offB) {
    __shared__ int s[1024];
    __shared__ int carry;
    if (threadIdx.x == 0) carry = 0;
    __syncthreads();
    for (int base = 0; base < NBLK; base += 1024) {
        int i = base + threadIdx.x;
        int v = (i < NBLK) ? degB[i] : 0;
        s[threadIdx.x] = v;
        __syncthreads();
        for (int d = 1; d < 1024; d <<= 1) {
            int t = (threadIdx.x >= d) ? s[threadIdx.x - d] : 0;
            __syncthreads();
            s[threadIdx.x] += t;
            __syncthreads();
        }
        if (i < NBLK) offB[i] = carry + s[threadIdx.x] - v;
        int tot = s[1023];
        __syncthreads();
        if (threadIdx.x == 0) carry += tot;
        __syncthreads();
    }
    if (threadIdx.x == 0) offB[NBLK] = carry;
}

__global__ void k_fill(const int* __restrict__ edges, const int* __restrict__ offB,
                       int* __restrict__ cursor, int* __restrict__ listE) {
    int e = blockIdx.x * 256 + threadIdx.x;
    if (e < EBK) {
        int b = edges[e];
        int p = atomicAdd(&cursor[b], 1);
        listE[offB[b] + p] = e;
    }
}

// top-3 nearest dst atoms per src atom; exact f32, tie -> lower index (matches top_k)
__global__ void k_topk(const int* __restrict__ edges, const float* __restrict__ Z,
                       int* __restrict__ colIdx) {
    int t = blockIdx.x * 256 + threadIdx.x;
    if (t >= EBK * UU) return;
    int e = t >> 2, u = t & 3;
    int b0 = edges[e], b1 = edges[EBK + e];
    int s = b0 * UU + u;
    float zs0 = Z[s*3+0], zs1 = Z[s*3+1], zs2 = Z[s*3+2];
    float d2[UU];
    #pragma unroll
    for (int v = 0; v < UU; v++) {
        int d = b1 * UU + v;
        float a0 = __fsub_rn(zs0, Z[d*3+0]);
        float a1 = __fsub_rn(zs1, Z[d*3+1]);
        float a2 = __fsub_rn(zs2, Z[d*3+2]);
        float p0 = __fmul_rn(a0, a0);
        float p1 = __fmul_rn(a1, a1);
        float p2 = __fmul_rn(a2, a2);
        d2[v] = __fadd_rn(__fadd_rn(p0, p1), p2);
    }
    bool used[UU] = {false, false, false, false};
    #pragma unroll
    for (int k = 0; k < KNN; k++) {
        int best = -1;
        float bd = INFINITY;
        #pragma unroll
        for (int v = 0; v < UU; v++) {
            if (!used[v] && d2[v] < bd) { bd = d2[v]; best = v; }
        }
        used[best] = true;
        colIdx[t * KNN + k] = b1 * UU + best;
    }
}

// ---------------- weight fragment precompute (hi/lo bf16, MFMA B-layout) ----------------

__global__ void k_wfrag(const float* __restrict__ ew1, const float* __restrict__ ew2,
                        const float* __restrict__ cw1,
                        const float* __restrict__ nw1, const float* __restrict__ nw2,
                        unsigned short* __restrict__ w1f_hi, unsigned short* __restrict__ w1f_lo,
                        unsigned short* __restrict__ w2f_hi, unsigned short* __restrict__ w2f_lo,
                        unsigned short* __restrict__ c1f_hi, unsigned short* __restrict__ c1f_lo,
                        unsigned short* __restrict__ n1f_hi, unsigned short* __restrict__ n1f_lo,
                        unsigned short* __restrict__ n2f_hi, unsigned short* __restrict__ n2f_lo) {
    int i = blockIdx.x * 256 + threadIdx.x;
    float v = 0.f;
    unsigned short* dh = nullptr;
    unsigned short* dl = nullptr;
    int di = 0;
    if (i < 3 * W1F_L) {
        int l = i / W1F_L, rem = i % W1F_L;
        int chunk = rem >> 9, lane = (rem >> 3) & 63, t = rem & 7;
        int kb = chunk >> 3, j = chunk & 7;
        int k = kb*32 + (lane >> 4)*8 + t, n = j*16 + (lane & 15);
        v = (k < 273) ? ew1[(size_t)l*273*128 + (size_t)k*128 + n] : 0.f;
        dh = w1f_hi; dl = w1f_lo; di = i;
    } else {
        int i2 = i - 3 * W1F_L;
        if (i2 < 3 * W2F_L) {
            int l = i2 / W2F_L, rem = i2 % W2F_L;
            int chunk = rem >> 9, lane = (rem >> 3) & 63, t = rem & 7;
            int kb = chunk >> 3, j = chunk & 7;
            int k = kb*32 + (lane >> 4)*8 + t, n = j*16 + (lane & 15);
            v = ew2[(size_t)l*128*128 + (size_t)k*128 + n];
            dh = w2f_hi; dl = w2f_lo; di = i2;
        } else {
            int i3 = i2 - 3 * W2F_L;
            if (i3 < 3 * W2F_L) {
                int l = i3 / W2F_L, rem = i3 % W2F_L;
                int chunk = rem >> 9, lane = (rem >> 3) & 63, t = rem & 7;
                int kb = chunk >> 3, j = chunk & 7;
                int k = kb*32 + (lane >> 4)*8 + t, n = j*16 + (lane & 15);
                v = cw1[(size_t)l*128*128 + (size_t)k*128 + n];
                dh = c1f_hi; dl = c1f_lo; di = i3;
            } else {
                int i4 = i3 - 3 * W2F_L;
                if (i4 < 3 * NW1F_L) {
                    int l = i4 / NW1F_L, rem = i4 % NW1F_L;
                    int chunk = rem >> 9, lane = (rem >> 3) & 63, t = rem & 7;
                    int kb = chunk >> 3, j = chunk & 7;
                    int k = kb*32 + (lane >> 4)*8 + t, n = j*16 + (lane & 15);
                    v = nw1[(size_t)l*256*128 + (size_t)k*128 + n];
                    dh = n1f_hi; dl = n1f_lo; di = i4;
                } else {
                    int i5 = i4 - 3 * NW1F_L;
                    if (i5 >= 3 * W2F_L) return;
                    int l = i5 / W2F_L, rem = i5 % W2F_L;
                    int chunk = rem >> 9, lane = (rem >> 3) & 63, t = rem & 7;
                    int kb = chunk >> 3, j = chunk & 7;
                    int k = kb*32 + (lane >> 4)*8 + t, n = j*16 + (lane & 15);
                    v = nw2[(size_t)l*128*128 + (size_t)k*128 + n];
                    dh = n2f_hi; dl = n2f_lo; di = i5;
                }
            }
        }
    }
    short hi, lo;
    split2(v, hi, lo);
    dh[di] = (unsigned short)hi;
    dl[di] = (unsigned short)lo;
}

// ---------------- shared-weight fused edge pipeline (split-bf16 MFMA) ----------------
// WG = 256 = 4 waves; each wave owns one block-edge (16 rows = 4u x 4kk, kk3 dup).
// Weights DMA-staged global->LDS (global_load_lds), shared by 4 waves.

__global__ __launch_bounds__(256, 3) void k_edge_shared(
    const unsigned int* __restrict__ hp,
    const float* __restrict__ x,
    const float* __restrict__ eattr,
    const int* __restrict__ edges0,
    const int* __restrict__ colIdx,
    const unsigned short* __restrict__ w1f_hi, const unsigned short* __restrict__ w1f_lo,
    const unsigned short* __restrict__ w2f_hi, const unsigned short* __restrict__ w2f_lo,
    const unsigned short* __restrict__ c1f_hi, const unsigned short* __restrict__ c1f_lo,
    const float* __restrict__ eb1,
    const float* __restrict__ eb2,
    const float* __restrict__ cb1,
    const float* __restrict__ cw2v,
    unsigned short* __restrict__ msum,
    float* __restrict__ xsum)
{
    __shared__ unsigned short wbufH[4096], wbufL[4096];
    __shared__ unsigned short C1h[4][16 * 128], C1l[4][16 * 128];
    __shared__ float diffS[4][48];

    const int tid = threadIdx.x;
    const int wid = tid >> 6, l = tid & 63;
    const int g = l >> 4, er = l & 15;
    const int u = er >> 2, kk = er & 3;
    const int kkc = (kk < 3) ? kk : 2;
    const int e = blockIdx.x * 4 + wid;

    const int bs = edges0[e];
    const int srcA = bs * 4 + u;
    const int colA = colIdx[(e * 4 + u) * 3 + kkc];
    float rad = 0.f;
    if (g == 0) {
        float dx = x[srcA*3+0] - x[colA*3+0];
        float dy = x[srcA*3+1] - x[colA*3+1];
        float dz = x[srcA*3+2] - x[colA*3+2];
        rad = dx*dx + dy*dy + dz*dz;
        diffS[wid][er*3+0] = dx; diffS[wid][er*3+1] = dy; diffS[wid][er*3+2] = dz;
    }

    const int goff = wid * 512 + l * 8;     // per-lane global offset (shorts)
    unsigned short* lb0H = wbufH + wid * 512;         // wave-uniform LDS bases
    unsigned short* lb1H = wbufH + 2048 + wid * 512;
    unsigned short* lb0L = wbufL + wid * 512;
    unsigned short* lb1L = wbufL + 2048 + wid * 512;

    // ---- phase 1: C1 = silu([h_r|h_c|rad|ea] @ W1 + b1), K=288 ----
    {
        f32x4 acc[8];
        #pragma unroll
        for (int jj = 0; jj < 8; jj++) acc[jj] = (f32x4){0.f, 0.f, 0.f, 0.f};

        #pragma unroll 1
        for (int kb = 0; kb < 9; kb++) {
            __syncthreads();
            stage16(w1f_hi + (kb << 12) + goff,        lb0H);
            stage16(w1f_hi + (kb << 12) + 2048 + goff, lb1H);
            stage16(w1f_lo + (kb << 12) + goff,        lb0L);
            stage16(w1f_lo + (kb << 12) + 2048 + goff, lb1L);
            bf16x8 ah, al;
            if (kb < 8) {
                const unsigned int* src = (kb < 4) ? (hp + (size_t)srcA * 128 + kb * 32 + g * 8)
                                                   : (hp + (size_t)colA * 128 + (kb - 4) * 32 + g * 8);
                uint4 v0 = *(const uint4*)src;
                uint4 v1 = *((const uint4*)src + 1);
                unpack8(v0, v1, ah, al);
            } else {
                float tv[8];
                #pragma unroll
                for (int q = 0; q < 8; q++) tv[q] = 0.f;
                if (g == 0) {
                    tv[0] = rad;
                    #pragma unroll
                    for (int q = 1; q < 8; q++) tv[q] = eattr[(size_t)e*16 + (q-1)];
                } else if (g == 1) {
                    #pragma unroll
                    for (int q = 0; q < 8; q++) tv[q] = eattr[(size_t)e*16 + 7 + q];
                } else if (g == 2) {
                    tv[0] = eattr[(size_t)e*16 + 15];
                }
                #pragma unroll
                for (int q = 0; q < 8; q++) { unsigned short hh, ll; csplit(tv[q], hh, ll); ah[q] = (short)hh; al[q] = (short)ll; }
            }
            __syncthreads();
            __builtin_amdgcn_s_setprio(1);
            #pragma unroll
            for (int jj = 0; jj < 8; jj++) {
                const int off = (jj << 9) + (l << 3);
                bf16x8 wh = *(const bf16x8*)&wbufH[off];
                bf16x8 wl = *(const bf16x8*)&wbufL[off];
                acc[jj] = __builtin_amdgcn_mfma_f32_16x16x32_bf16(ah, wh, acc[jj], 0, 0, 0);
                acc[jj] = __builtin_amdgcn_mfma_f32_16x16x32_bf16(al, wh, acc[jj], 0, 0, 0);
                acc[jj] = __builtin_amdgcn_mfma_f32_16x16x32_bf16(ah, wl, acc[jj], 0, 0, 0);
            }
            __builtin_amdgcn_s_setprio(0);
        }
        #pragma unroll
        for (int jj = 0; jj < 8; jj++) {
            const int n = jj * 16 + er;
            const float bv = eb1[n];
            #pragma unroll
            for (int reg = 0; reg < 4; reg++) {
                const int row = g * 4 + reg;
                float v = silu_f(acc[jj][reg] + bv);
                unsigned short hh, ll; csplit(v, hh, ll);
                const int sidx = row * 128 + (n ^ ((row & 7) << 3));
                C1h[wid][sidx] = hh;
                C1l[wid][sidx] = ll;
            }
        }
    }

    // ---- phase 2: m = silu(C1 @ W2 + b2); emit kk-summed msum; stage M over C1 ----
    {
        f32x4 acc[8];
        #pragma unroll
        for (int jj = 0; jj < 8; jj++) acc[jj] = (f32x4){0.f, 0.f, 0.f, 0.f};

        #pragma unroll 1
        for (int kb = 0; kb < 4; kb++) {
            __syncthreads();
            stage16(w2f_hi + (kb << 12) + goff,        lb0H);
            stage16(w2f_hi + (kb << 12) + 2048 + goff, lb1H);
            stage16(w2f_lo + (kb << 12) + goff,        lb0L);
            stage16(w2f_lo + (kb << 12) + 2048 + goff, lb1L);
            const int aoff = er * 128 + ((kb * 32 + g * 8) ^ ((er & 7) << 3));
            bf16x8 ah = *(const bf16x8*)&C1h[wid][aoff];
            bf16x8 al = *(const bf16x8*)&C1l[wid][aoff];
            __syncthreads();
            __builtin_amdgcn_s_setprio(1);
            #pragma unroll
            for (int jj = 0; jj < 8; jj++) {
                const int off = (jj << 9) + (l << 3);
                bf16x8 wh = *(const bf16x8*)&wbufH[off];
                bf16x8 wl = *(const bf16x8*)&wbufL[off];
                acc[jj] = __builtin_amdgcn_mfma_f32_16x16x32_bf16(ah, wh, acc[jj], 0, 0, 0);
                acc[jj] = __builtin_amdgcn_mfma_f32_16x16x32_bf16(al, wh, acc[jj], 0, 0, 0);
                acc[jj] = __builtin_amdgcn_mfma_f32_16x16x32_bf16(ah, wl, acc[jj], 0, 0, 0);
            }
            __builtin_amdgcn_s_setprio(0);
        }
        #pragma unroll
        for (int jj = 0; jj < 8; jj++) {
            const int n = jj * 16 + er;
            const float bv = eb2[n];
            float ms = 0.f;
            #pragma unroll
            for (int reg = 0; reg < 4; reg++) {
                const int row = g * 4 + reg;       // u = g, kk = reg
                float v = silu_f(acc[jj][reg] + bv);
                if (reg < 3) ms += v;
                unsigned short hh, ll; csplit(v, hh, ll);
                const int sidx = row * 128 + (n ^ ((row & 7) << 3));
                C1h[wid][sidx] = hh;
                C1l[wid][sidx] = ll;
            }
            msum[(size_t)(e * 4 + g) * 128 + n] = f2bf(ms);
        }
    }

    // ---- phase 3: w = silu(m @ CW1 + cb1) @ cw2; emit xsum per (edge,u) ----
    {
        f32x4 acc[8];
        #pragma unroll
        for (int jj = 0; jj < 8; jj++) acc[jj] = (f32x4){0.f, 0.f, 0.f, 0.f};

        #pragma unroll 1
        for (int kb = 0; kb < 4; kb++) {
            __syncthreads();
            stage16(c1f_hi + (kb << 12) + goff,        lb0H);
            stage16(c1f_hi + (kb << 12) + 2048 + goff, lb1H);
            stage16(c1f_lo + (kb << 12) + goff,        lb0L);
            stage16(c1f_lo + (kb << 12) + 2048 + goff, lb1L);
            const int aoff = er * 128 + ((kb * 32 + g * 8) ^ ((er & 7) << 3));
            bf16x8 ah = *(const bf16x8*)&C1h[wid][aoff];
            bf16x8 al = *(const bf16x8*)&C1l[wid][aoff];
            __syncthreads();
            __builtin_amdgcn_s_setprio(1);
            #pragma unroll
            for (int jj = 0; jj < 8; jj++) {
                const int off = (jj << 9) + (l << 3);
                bf16x8 wh = *(const bf16x8*)&wbufH[off];
                bf16x8 wl = *(const bf16x8*)&wbufL[off];
                acc[jj] = __builtin_amdgcn_mfma_f32_16x16x32_bf16(ah, wh, acc[jj], 0, 0, 0);
                acc[jj] = __builtin_amdgcn_mfma_f32_16x16x32_bf16(al, wh, acc[jj], 0, 0, 0);
                acc[jj] = __builtin_amdgcn_mfma_f32_16x16x32_bf16(ah, wl, acc[jj], 0, 0, 0);
            }
            __builtin_amdgcn_s_setprio(0);
        }
        float p[4] = {0.f, 0.f, 0.f, 0.f};
        #pragma unroll
        for (int jj = 0; jj < 8; jj++) {
            const int n = jj * 16 + er;
            const float cb = cb1[n], cw = cw2v[n];
            #pragma unroll
            for (int reg = 0; reg < 4; reg++)
                p[reg] += silu_f(acc[jj][reg] + cb) * cw;
        }
        #pragma unroll
        for (int d = 1; d < 16; d <<= 1) {
            #pragma unroll
            for (int reg = 0; reg < 4; reg++)
                p[reg] += __shfl_xor(p[reg], d);
        }
        if (er < 3) {
            float xs = 0.f;
            #pragma unroll
            for (int reg = 0; reg < 3; reg++)
                xs += diffS[wid][(g * 4 + reg) * 3 + er] * p[reg];
            xsum[(size_t)(e * 4 + g) * 3 + er] = xs;
        }
    }
}

// ---------------- coordinate update (CSR gather of xsum) ----------------

__global__ void k_xupd(const float* __restrict__ xcur, const float* __restrict__ xsum,
                       const int* __restrict__ offB, const int* __restrict__ listE,
                       float* __restrict__ xnext)
{
    int i = blockIdx.x * 256 + threadIdx.x;
    if (i >= NATOM * 3) return;
    int a = i / 3, d = i - a * 3;
    int b = a >> 2, u = a & 3;
    int o0 = offB[b], o1 = offB[b + 1];
    float xs = 0.f;
    for (int pos = o0; pos < o1; pos++) {
        int e = listE[pos];
        xs += xsum[(size_t)(e * 4 + u) * 3 + d];
    }
    int deg = o1 - o0;
    xnext[i] = xcur[i] + ((deg > 0) ? xs / (3.0f * (float)deg) : 0.f);
}

// ---------------- fused node MLP (gathers msum directly; split-bf16 MFMA) ----------------
// WG = 256 = 4 waves; each wave owns 16 atoms. h_new = h + silu([h|agg]@w1+b1)@w2+b2,
// where agg[atom] = sum over CSR edges of msum — gathered on the fly (no agg tensor).

__global__ __launch_bounds__(256, 3) void k_node(
    unsigned int* __restrict__ hp,
    const unsigned short* __restrict__ msum,
    const int* __restrict__ offB,
    const int* __restrict__ listE,
    const unsigned short* __restrict__ n1f_hi, const unsigned short* __restrict__ n1f_lo,
    const unsigned short* __restrict__ n2f_hi, const unsigned short* __restrict__ n2f_lo,
    const float* __restrict__ nb1,
    const float* __restrict__ nb2)
{
    __shared__ unsigned short wbufH[4096], wbufL[4096];
    __shared__ unsigned short hidH[4][16 * 128], hidL[4][16 * 128];

    const int tid = threadIdx.x;
    const int wid = tid >> 6, l = tid & 63;
    const int g = l >> 4, er = l & 15;
    const int a0 = blockIdx.x * 64 + wid * 16;
    const int a = a0 + er;
    const int b = a >> 2, u = a & 3;
    const int o0 = offB[b], o1 = offB[b + 1];

    const int goff = wid * 512 + l * 8;
    unsigned short* lb0H = wbufH + wid * 512;
    unsigned short* lb1H = wbufH + 2048 + wid * 512;
    unsigned short* lb0L = wbufL + wid * 512;
    unsigned short* lb1L = wbufL + 2048 + wid * 512;

    // ---- phase A: hid = silu([h|agg] @ W1 + b1), K=256 ----
    {
        f32x4 acc[8];
        #pragma unroll
        for (int jj = 0; jj < 8; jj++) acc[jj] = (f32x4){0.f, 0.f, 0.f, 0.f};

        #pragma unroll 1
        for (int kb = 0; kb < 8; kb++) {
            __syncthreads();
            stage16(n1f_hi + (kb << 12) + goff,        lb0H);
            stage16(n1f_hi + (kb << 12) + 2048 + goff, lb1H);
            stage16(n1f_lo + (kb << 12) + goff,        lb0L);
            stage16(n1f_lo + (kb << 12) + 2048 + goff, lb1L);
            bf16x8 ah, al;
            if (kb < 4) {
                const unsigned int* src = hp + (size_t)a * 128 + kb * 32 + g * 8;
                uint4 v0 = *(const uint4*)src;
                uint4 v1 = *((const uint4*)src + 1);
                unpack8(v0, v1, ah, al);
            } else {
                float s[8];
                #pragma unroll
                for (int q = 0; q < 8; q++) s[q] = 0.f;
                for (int pos = o0; pos < o1; pos++) {
                    const int e = listE[pos];
                    bf16x8 mv = *(const bf16x8*)(msum + (size_t)(e * 4 + u) * 128 + (kb - 4) * 32 + g * 8);
                    #pragma unroll
                    for (int q = 0; q < 8; q++) s[q] += bf2f((unsigned short)mv[q]);
                }
                #pragma unroll
                for (int q = 0; q < 8; q++) { unsigned short hh, ll; csplit(s[q], hh, ll); ah[q] = (short)hh; al[q] = (short)ll; }
            }
            __syncthreads();
            __builtin_amdgcn_s_setprio(1);
            #pragma unroll
            for (int jj = 0; jj < 8; jj++) {
                const int off = (jj << 9) + (l << 3);
                bf16x8 wh = *(const bf16x8*)&wbufH[off];
                bf16x8 wl = *(const bf16x8*)&wbufL[off];
                acc[jj] = __builtin_amdgcn_mfma_f32_16x16x32_bf16(ah, wh, acc[jj], 0, 0, 0);
                acc[jj] = __builtin_amdgcn_mfma_f32_16x16x32_bf16(al, wh, acc[jj], 0, 0, 0);
                acc[jj] = __builtin_amdgcn_mfma_f32_16x16x32_bf16(ah, wl, acc[jj], 0, 0, 0);
            }
            __builtin_amdgcn_s_setprio(0);
        }
        #pragma unroll
        for (int jj = 0; jj < 8; jj++) {
            const int n = jj * 16 + er;
            const float bv = nb1[n];
            #pragma unroll
            for (int reg = 0; reg < 4; reg++) {
                const int row = g * 4 + reg;
                float v = silu_f(acc[jj][reg] + bv);
                unsigned short hh, ll; csplit(v, hh, ll);
                const int sidx = row * 128 + (n ^ ((row & 7) << 3));
                hidH[wid][sidx] = hh;
                hidL[wid][sidx] = ll;
            }
        }
    }

    // ---- phase B: h += hid @ W2 + b2, K=128 ----
    {
        f32x4 acc[8];
        #pragma unroll
        for (int jj = 0; jj < 8; jj++) acc[jj] = (f32x4){0.f, 0.f, 0.f, 0.f};

        #pragma unroll 1
        for (int kb = 0; kb < 4; kb++) {
            __syncthreads();
            stage16(n2f_hi + (kb << 12) + goff,        lb0H);
            stage16(n2f_hi + (kb << 12) + 2048 + goff, lb1H);
            stage16(n2f_lo + (kb << 12) + goff,        lb0L);
            stage16(n2f_lo + (kb << 12) + 2048 + goff, lb1L);
            const int aoff = er * 128 + ((kb * 32 + g * 8) ^ ((er & 7) << 3));
            bf16x8 ah = *(const bf16x8*)&hidH[wid][aoff];
            bf16x8 al = *(const bf16x8*)&hidL[wid][aoff];
            __syncthreads();
            __builtin_amdgcn_s_setprio(1);
            #pragma unroll
            for (int jj = 0; jj < 8; jj++) {
                const int off = (jj << 9) + (l << 3);
                bf16x8 wh = *(const bf16x8*)&wbufH[off];
                bf16x8 wl = *(const bf16x8*)&wbufL[off];
                acc[jj] = __builtin_amdgcn_mfma_f32_16x16x32_bf16(ah, wh, acc[jj], 0, 0, 0);
                acc[jj] = __builtin_amdgcn_mfma_f32_16x16x32_bf16(al, wh, acc[jj], 0, 0, 0);
                acc[jj] = __builtin_amdgcn_mfma_f32_16x16x32_bf16(ah, wl, acc[jj], 0, 0, 0);
            }
            __builtin_amdgcn_s_setprio(0);
        }
        #pragma unroll
        for (int jj = 0; jj < 8; jj++) {
            const int n = jj * 16 + er;
            const float bv = nb2[n];
            #pragma unroll
            for (int reg = 0; reg < 4; reg++) {
                const int row = g * 4 + reg;
                const size_t idx = (size_t)(a0 + row) * 128 + n;
                float v = acc[jj][reg] + bv + unpackf(hp[idx]);
                hp[idx] = packhl(v);
            }
        }
    }
}

// ---------------- generic tiled f32 GEMM (emb MLPs; pack/unpack variants) ----------------

template<int KT, bool PACKIN, bool PACKOUT>
__global__ __launch_bounds__(128) void k_gemm(
    const float* __restrict__ A0,
    const float* __restrict__ W, const float* __restrict__ bias,
    float* __restrict__ C, int M)
{
    __shared__ float At[KT][32];
    __shared__ float Bs[32][128];
    const int tid = threadIdx.x;
    const int tile0 = blockIdx.x * 32;
    const int r = tid >> 2, part = tid & 3;
    const int gr = tile0 + r;

    if (gr < M) {
        #pragma unroll
        for (int j = 0; j < 8; j++) {
            int c = part * 32 + j * 4;
            float f0, f1, f2, f3;
            if (PACKIN) {
                const unsigned int* ap = (const unsigned int*)A0 + (size_t)gr * 128 + c;
                uint4 v = *(const uint4*)ap;
                f0 = unpackf(v.x); f1 = unpackf(v.y); f2 = unpackf(v.z); f3 = unpackf(v.w);
            } else {
                float4 v = *(const float4*)(A0 + (size_t)gr * 128 + c);
                f0 = v.x; f1 = v.y; f2 = v.z; f3 = v.w;
            }
            At[c][r] = f0; At[c+1][r] = f1; At[c+2][r] = f2; At[c+3][r] = f3;
        }
    } else {
        #pragma unroll
        for (int j = 0; j < 8; j++) {
            int c = part * 32 + j * 4;
            At[c][r] = 0.f; At[c+1][r] = 0.f; At[c+2][r] = 0.f; At[c+3][r] = 0.f;
        }
    }

    float acc[4][8];
    #pragma unroll
    for (int i = 0; i < 4; i++)
        #pragma unroll
        for (int j = 0; j < 8; j++) acc[i][j] = 0.f;

    const int tx = tid & 15, ty = tid >> 4;

    for (int kb = 0; kb < KT / 32; kb++) {
        __syncthreads();
        #pragma unroll
        for (int j = 0; j < 8; j++) {
            int li = j * 512 + tid * 4;
            int kk = li >> 7, c = li & 127;
            float4 v = *(const float4*)(W + (size_t)(kb * 32 + kk) * 128 + c);
            *(float4*)&Bs[kk][c] = v;
        }
        __syncthreads();
        #pragma unroll 8
        for (int kk = 0; kk < 32; kk++) {
            float4 a  = *(const float4*)&At[kb * 32 + kk][ty * 4];
            float4 b0 = *(const float4*)&Bs[kk][tx * 8];
            float4 b1 = *(const float4*)&Bs[kk][tx * 8 + 4];
            float av[4] = {a.x, a.y, a.z, a.w};
            float bv[8] = {b0.x, b0.y, b0.z, b0.w, b1.x, b1.y, b1.z, b1.w};
            #pragma unroll
            for (int i = 0; i < 4; i++)
                #pragma unroll
                for (int j = 0; j < 8; j++)
                    acc[i][j] = fmaf(av[i], bv[j], acc[i][j]);
        }
    }

    #pragma unroll
    for (int i = 0; i < 4; i++) {
        int grr = tile0 + ty * 4 + i;
        if (grr >= M) continue;
        #pragma unroll
        for (int j = 0; j < 8; j++) {
            int c = tx * 8 + j;
            float v = acc[i][j] + bias[c];
            if (PACKOUT) ((unsigned int*)C)[(size_t)grr * 128 + c] = packhl(v);
            else         C[(size_t)grr * 128 + c] = v;
        }
    }
}

// ---------------- launch ----------------

extern "C" void kernel_launch(void* const* d_in, const int* in_sizes, int n_in,
                              void* d_out, int out_size, void* d_ws, size_t ws_size,
                              hipStream_t stream) {
    const float* H        = (const float*)d_in[0];
    const float* Z        = (const float*)d_in[1];
    const int*   edges    = (const int*)  d_in[4];
    const float* eattr    = (const float*)d_in[5];
    const float* emb_in_w = (const float*)d_in[6];
    const float* emb_in_b = (const float*)d_in[7];
    const float* emb_out_w= (const float*)d_in[8];
    const float* emb_out_b= (const float*)d_in[9];
    const float* edge_w1  = (const float*)d_in[10];
    const float* edge_b1  = (const float*)d_in[11];
    const float* edge_w2  = (const float*)d_in[12];
    const float* edge_b2  = (const float*)d_in[13];
    const float* node_w1  = (const float*)d_in[14];
    const float* node_b1  = (const float*)d_in[15];
    const float* node_w2  = (const float*)d_in[16];
    const float* node_b2  = (const float*)d_in[17];
    const float* coord_w1 = (const float*)d_in[18];
    const float* coord_b1 = (const float*)d_in[19];
    const float* coord_w2 = (const float*)d_in[20];

    float* out  = (float*)d_out;
    float* hbuf = out;                              // [N][128]  (packed u32 during layers)
    unsigned int* hp = (unsigned int*)hbuf;
    float* xout = out + (size_t)NATOM * 128;        // [N][3]

    // workspace (~37 MB), 16B-aligned sections
    char* w = (char*)d_ws;
    unsigned short* msum = (unsigned short*)w;  w += (size_t)NGRP * 128 * 2;  // 30.72 MB
    float* xsum = (float*)w;           w += (size_t)NGRP * 3 * 4;            // 1.44 MB
    float* xA  = (float*)w;            w += (size_t)NATOM * 3 * 4;
    float* xB  = (float*)w;            w += (size_t)NATOM * 3 * 4;
    unsigned short* w1f_hi = (unsigned short*)w;  w += (size_t)3 * W1F_L * 2;
    unsigned short* w1f_lo = (unsigned short*)w;  w += (size_t)3 * W1F_L * 2;
    unsigned short* w2f_hi = (unsigned short*)w;  w += (size_t)3 * W2F_L * 2;
    unsigned short* w2f_lo = (unsigned short*)w;  w += (size_t)3 * W2F_L * 2;
    unsigned short* c1f_hi = (unsigned short*)w;  w += (size_t)3 * W2F_L * 2;
    unsigned short* c1f_lo = (unsigned short*)w;  w += (size_t)3 * W2F_L * 2;
    unsigned short* n1f_hi = (unsigned short*)w;  w += (size_t)3 * NW1F_L * 2;
    unsigned short* n1f_lo = (unsigned short*)w;  w += (size_t)3 * NW1F_L * 2;
    unsigned short* n2f_hi = (unsigned short*)w;  w += (size_t)3 * W2F_L * 2;
    unsigned short* n2f_lo = (unsigned short*)w;  w += (size_t)3 * W2F_L * 2;
    int* colIdx = (int*)w;             w += (size_t)EALL * 4;
    int* degB   = (int*)w;             w += (size_t)NBLK * 4;
    int* cursor = (int*)w;             w += (size_t)NBLK * 4;
    int* listE  = (int*)w;             w += (size_t)EBK * 4;
    int* offB   = (int*)w;             w += (size_t)(NBLK + 1) * 4;

    hipMemsetAsync(degB,   0, NBLK * sizeof(int), stream);
    hipMemsetAsync(cursor, 0, NBLK * sizeof(int), stream);

    k_count<<<(EBK + 255) / 256, 256, 0, stream>>>(edges, degB);
    k_scan <<<1, 1024, 0, stream>>>(degB, offB);
    k_fill <<<(EBK + 255) / 256, 256, 0, stream>>>(edges, offB, cursor, listE);
    k_topk <<<(EBK * UU + 255) / 256, 256, 0, stream>>>(edges, Z, colIdx);

    {
        int total = 3 * W1F_L + 3 * W2F_L + 3 * W2F_L + 3 * NW1F_L + 3 * W2F_L;
        k_wfrag<<<(total + 255) / 256, 256, 0, stream>>>(
            edge_w1, edge_w2, coord_w1, node_w1, node_w2,
            w1f_hi, w1f_lo, w2f_hi, w2f_lo, c1f_hi, c1f_lo,
            n1f_hi, n1f_lo, n2f_hi, n2f_lo);
    }

    // h = H @ emb_in_w + b  (write packed hi/lo)
    k_gemm<128, false, true><<<NATOM / 32, 128, 0, stream>>>(
        H, emb_in_w, emb_in_b, (float*)hp, NATOM);

    const float* xcur = Z;
    for (int l = 0; l < LAY; l++) {
        float* xnext = (l == 0) ? xA : (l == 1) ? xB : xout;

        k_edge_shared<<<EBK / 4, 256, 0, stream>>>(
            hp, xcur, eattr, edges, colIdx,
            w1f_hi + (size_t)l * W1F_L, w1f_lo + (size_t)l * W1F_L,
            w2f_hi + (size_t)l * W2F_L, w2f_lo + (size_t)l * W2F_L,
            c1f_hi + (size_t)l * W2F_L, c1f_lo + (size_t)l * W2F_L,
            edge_b1 + l * 128, edge_b2 + l * 128, coord_b1 + l * 128, coord_w2 + l * 128,
            msum, xsum);

        k_xupd<<<(NATOM * 3 + 255) / 256, 256, 0, stream>>>(xcur, xsum, offB, listE, xnext);

        k_node<<<NATOM / 64, 256, 0, stream>>>(
            hp, msum, offB, listE,
            n1f_hi + (size_t)l * NW1F_L, n1f_lo + (size_t)l * NW1F_L,
            n2f_hi + (size_t)l * W2F_L, n2f_lo + (size_t)l * W2F_L,
            node_b1 + l * 128, node_b2 + l * 128);

        xcur = xnext;
    }

    // h_out = h @ emb_out_w + b  (read packed, write f32 in-place)
    k_gemm<128, true, false><<<NATOM / 32, 128, 0, stream>>>(
        hbuf, emb_out_w, emb_out_b, hbuf, NATOM);
}

// Round 10
// 1000.003 us; speedup vs baseline: 5.2955x; 1.0995x over previous
//
#include <hip/hip_runtime.h>
#include <math.h>

#define HIDC 128
#define EDGEF 16
#define LAY 3
#define KNN 3
#define UU 4
#define NBLK 20000
#define NATOM (NBLK*UU)      // 80000
#define EBK 30000
#define EALL (EBK*UU*KNN)    // 360000
#define NGRP (EBK*UU)        // 120000 (edge,u) groups

#define W1F_L 36864          // 9 kb * 8 j * 64 lanes * 8
#define W2F_L 16384          // 4 kb * 8 j * 64 lanes * 8
#define NW1F_L 32768         // 8 kb * 8 j * 64 lanes * 8

typedef __attribute__((ext_vector_type(8))) short bf16x8;
typedef __attribute__((ext_vector_type(4))) float f32x4;

__device__ __forceinline__ float silu_f(float v) {
    return __fdividef(v, 1.0f + __expf(-v));
}

__device__ __forceinline__ unsigned short f2bf(float f) {
    union { float f; unsigned int u; } v; v.f = f;
    unsigned int r = v.u + 0x7FFFu + ((v.u >> 16) & 1u);
    return (unsigned short)(r >> 16);
}

__device__ __forceinline__ float bf2f(unsigned short h) {
    union { unsigned int u; float f; } t; t.u = ((unsigned int)h) << 16;
    return t.f;
}

// full-precision split (RNE hi) — used in one-time weight prep only
__device__ __forceinline__ void split2(float v, short& hi, short& lo) {
    unsigned short h = f2bf(v);
    hi = (short)h;
    lo = (short)f2bf(v - bf2f(h));
}

// cheap split: truncated hi + RNE lo (lo captures truncation exactly; ~2^-17 rel)
__device__ __forceinline__ void csplit(float v, unsigned short& hi, unsigned short& lo) {
    unsigned int hu = __float_as_uint(v) & 0xffff0000u;
    hi = (unsigned short)(hu >> 16);
    lo = f2bf(v - __uint_as_float(hu));
}

__device__ __forceinline__ unsigned int packhl(float v) {
    unsigned int hu = __float_as_uint(v) & 0xffff0000u;
    return hu | (unsigned int)f2bf(v - __uint_as_float(hu));
}

__device__ __forceinline__ float unpackf(unsigned int u) {
    return bf2f((unsigned short)(u >> 16)) + bf2f((unsigned short)(u & 0xffffu));
}

__device__ __forceinline__ void unpack8(uint4 v0, uint4 v1, bf16x8& ah, bf16x8& al) {
    unsigned int uu[8] = {v0.x, v0.y, v0.z, v0.w, v1.x, v1.y, v1.z, v1.w};
    #pragma unroll
    for (int q = 0; q < 8; q++) {
        ah[q] = (short)(unsigned short)(uu[q] >> 16);
        al[q] = (short)(unsigned short)(uu[q] & 0xffffu);
    }
}

// async global->LDS DMA: 16B per lane, LDS dest = wave-uniform base + lane*16
__device__ __forceinline__ void stage16(const unsigned short* gsrc, unsigned short* ldst) {
    __builtin_amdgcn_global_load_lds(
        (const __attribute__((address_space(1))) unsigned int*)(const void*)gsrc,
        (__attribute__((address_space(3))) unsigned int*)(void*)ldst,
        16, 0, 0);
}

// ---------------- CSR build ----------------

__global__ void k_count(const int* __restrict__ edges, int* __restrict__ degB) {
    int e = blockIdx.x * 256 + threadIdx.x;
    if (e < EBK) atomicAdd(&degB[edges[e]], 1);
}

__global__ void k_scan(const int* __restrict__ degB, int* __restrict__ offB) {
    __shared__ int s[1024];
    __shared__ int carry;
    if (threadIdx.x == 0) carry = 0;
    __syncthreads();
    for (int base = 0; base < NBLK; base += 1024) {
        int i = base + threadIdx.x;
        int v = (i < NBLK) ? degB[i] : 0;
        s[threadIdx.x] = v;
        __syncthreads();
        for (int d = 1; d < 1024; d <<= 1) {
            int t = (threadIdx.x >= d) ? s[threadIdx.x - d] : 0;
            __syncthreads();
            s[threadIdx.x] += t;
            __syncthreads();
        }
        if (i < NBLK) offB[i] = carry + s[threadIdx.x] - v;
        int tot = s[1023];
        __syncthreads();
        if (threadIdx.x == 0) carry += tot;
        __syncthreads();
    }
    if (threadIdx.x == 0) offB[NBLK] = carry;
}

__global__ void k_fill(const int* __restrict__ edges, const int* __restrict__ offB,
                       int* __restrict__ cursor, int* __restrict__ listE) {
    int e = blockIdx.x * 256 + threadIdx.x;
    if (e < EBK) {
        int b = edges[e];
        int p = atomicAdd(&cursor[b], 1);
        listE[offB[b] + p] = e;
    }
}

// top-3 nearest dst atoms per src atom; exact f32, tie -> lower index (matches top_k)
__global__ void k_topk(const int* __restrict__ edges, const float* __restrict__ Z,
                       int* __restrict__ colIdx) {
    int t = blockIdx.x * 256 + threadIdx.x;
    if (t >= EBK * UU) return;
    int e = t >> 2, u = t & 3;
    int b0 = edges[e], b1 = edges[EBK + e];
    int s = b0 * UU + u;
    float zs0 = Z[s*3+0], zs1 = Z[s*3+1], zs2 = Z[s*3+2];
    float d2[UU];
    #pragma unroll
    for (int v = 0; v < UU; v++) {
        int d = b1 * UU + v;
        float a0 = __fsub_rn(zs0, Z[d*3+0]);
        float a1 = __fsub_rn(zs1, Z[d*3+1]);
        float a2 = __fsub_rn(zs2, Z[d*3+2]);
        float p0 = __fmul_rn(a0, a0);
        float p1 = __fmul_rn(a1, a1);
        float p2 = __fmul_rn(a2, a2);
        d2[v] = __fadd_rn(__fadd_rn(p0, p1), p2);
    }
    bool used[UU] = {false, false, false, false};
    #pragma unroll
    for (int k = 0; k < KNN; k++) {
        int best = -1;
        float bd = INFINITY;
        #pragma unroll
        for (int v = 0; v < UU; v++) {
            if (!used[v] && d2[v] < bd) { bd = d2[v]; best = v; }
        }
        used[best] = true;
        colIdx[t * KNN + k] = b1 * UU + best;
    }
}

// ---------------- weight fragment precompute (hi/lo bf16, MFMA B-layout) ----------------

__global__ void k_wfrag(const float* __restrict__ ew1, const float* __restrict__ ew2,
                        const float* __restrict__ cw1,
                        const float* __restrict__ nw1, const float* __restrict__ nw2,
                        unsigned short* __restrict__ w1f_hi, unsigned short* __restrict__ w1f_lo,
                        unsigned short* __restrict__ w2f_hi, unsigned short* __restrict__ w2f_lo,
                        unsigned short* __restrict__ c1f_hi, unsigned short* __restrict__ c1f_lo,
                        unsigned short* __restrict__ n1f_hi, unsigned short* __restrict__ n1f_lo,
                        unsigned short* __restrict__ n2f_hi, unsigned short* __restrict__ n2f_lo) {
    int i = blockIdx.x * 256 + threadIdx.x;
    float v = 0.f;
    unsigned short* dh = nullptr;
    unsigned short* dl = nullptr;
    int di = 0;
    if (i < 3 * W1F_L) {
        int l = i / W1F_L, rem = i % W1F_L;
        int chunk = rem >> 9, lane = (rem >> 3) & 63, t = rem & 7;
        int kb = chunk >> 3, j = chunk & 7;
        int k = kb*32 + (lane >> 4)*8 + t, n = j*16 + (lane & 15);
        v = (k < 273) ? ew1[(size_t)l*273*128 + (size_t)k*128 + n] : 0.f;
        dh = w1f_hi; dl = w1f_lo; di = i;
    } else {
        int i2 = i - 3 * W1F_L;
        if (i2 < 3 * W2F_L) {
            int l = i2 / W2F_L, rem = i2 % W2F_L;
            int chunk = rem >> 9, lane = (rem >> 3) & 63, t = rem & 7;
            int kb = chunk >> 3, j = chunk & 7;
            int k = kb*32 + (lane >> 4)*8 + t, n = j*16 + (lane & 15);
            v = ew2[(size_t)l*128*128 + (size_t)k*128 + n];
            dh = w2f_hi; dl = w2f_lo; di = i2;
        } else {
            int i3 = i2 - 3 * W2F_L;
            if (i3 < 3 * W2F_L) {
                int l = i3 / W2F_L, rem = i3 % W2F_L;
                int chunk = rem >> 9, lane = (rem >> 3) & 63, t = rem & 7;
                int kb = chunk >> 3, j = chunk & 7;
                int k = kb*32 + (lane >> 4)*8 + t, n = j*16 + (lane & 15);
                v = cw1[(size_t)l*128*128 + (size_t)k*128 + n];
                dh = c1f_hi; dl = c1f_lo; di = i3;
            } else {
                int i4 = i3 - 3 * W2F_L;
                if (i4 < 3 * NW1F_L) {
                    int l = i4 / NW1F_L, rem = i4 % NW1F_L;
                    int chunk = rem >> 9, lane = (rem >> 3) & 63, t = rem & 7;
                    int kb = chunk >> 3, j = chunk & 7;
                    int k = kb*32 + (lane >> 4)*8 + t, n = j*16 + (lane & 15);
                    v = nw1[(size_t)l*256*128 + (size_t)k*128 + n];
                    dh = n1f_hi; dl = n1f_lo; di = i4;
                } else {
                    int i5 = i4 - 3 * NW1F_L;
                    if (i5 >= 3 * W2F_L) return;
                    int l = i5 / W2F_L, rem = i5 % W2F_L;
                    int chunk = rem >> 9, lane = (rem >> 3) & 63, t = rem & 7;
                    int kb = chunk >> 3, j = chunk & 7;
                    int k = kb*32 + (lane >> 4)*8 + t, n = j*16 + (lane & 15);
                    v = nw2[(size_t)l*128*128 + (size_t)k*128 + n];
                    dh = n2f_hi; dl = n2f_lo; di = i5;
                }
            }
        }
    }
    short hi, lo;
    split2(v, hi, lo);
    dh[di] = (unsigned short)hi;
    dl[di] = (unsigned short)lo;
}

// ---------------- shared-weight fused edge pipeline (hybrid-precision MFMA) ----------------
// WG = 256 = 4 waves; each wave owns one block-edge (16 rows = 4u x 4kk, kk3 dup).
// Weights DMA-staged global->LDS, shared by 4 waves. Phase 1: A hi/lo (3 MFMA).
// Intermediates C1/M stored single RNE-bf16 -> phases 2/3 use 2 MFMA (a*Whi + a*Wlo).

__global__ __launch_bounds__(256, 4) void k_edge_shared(
    const unsigned int* __restrict__ hp,
    const float* __restrict__ x,
    const float* __restrict__ eattr,
    const int* __restrict__ edges0,
    const int* __restrict__ colIdx,
    const unsigned short* __restrict__ w1f_hi, const unsigned short* __restrict__ w1f_lo,
    const unsigned short* __restrict__ w2f_hi, const unsigned short* __restrict__ w2f_lo,
    const unsigned short* __restrict__ c1f_hi, const unsigned short* __restrict__ c1f_lo,
    const float* __restrict__ eb1,
    const float* __restrict__ eb2,
    const float* __restrict__ cb1,
    const float* __restrict__ cw2v,
    unsigned short* __restrict__ msum,
    float* __restrict__ xsum)
{
    __shared__ unsigned short wbufH[4096], wbufL[4096];   // 16 KB
    __shared__ unsigned short C1[4][16 * 128];            // 16 KB (bf16 RNE; reused for M)
    __shared__ float diffS[4][48];

    const int tid = threadIdx.x;
    const int wid = tid >> 6, l = tid & 63;
    const int g = l >> 4, er = l & 15;
    const int u = er >> 2, kk = er & 3;
    const int kkc = (kk < 3) ? kk : 2;
    const int e = blockIdx.x * 4 + wid;

    const int bs = edges0[e];
    const int srcA = bs * 4 + u;
    const int colA = colIdx[(e * 4 + u) * 3 + kkc];
    float rad = 0.f;
    if (g == 0) {
        float dx = x[srcA*3+0] - x[colA*3+0];
        float dy = x[srcA*3+1] - x[colA*3+1];
        float dz = x[srcA*3+2] - x[colA*3+2];
        rad = dx*dx + dy*dy + dz*dz;
        diffS[wid][er*3+0] = dx; diffS[wid][er*3+1] = dy; diffS[wid][er*3+2] = dz;
    }

    const int goff = wid * 512 + l * 8;     // per-lane global offset (shorts)
    unsigned short* lb0H = wbufH + wid * 512;         // wave-uniform LDS bases
    unsigned short* lb1H = wbufH + 2048 + wid * 512;
    unsigned short* lb0L = wbufL + wid * 512;
    unsigned short* lb1L = wbufL + 2048 + wid * 512;

    // ---- phase 1: C1 = silu([h_r|h_c|rad|ea] @ W1 + b1), K=288, 3-MFMA split ----
    {
        f32x4 acc[8];
        #pragma unroll
        for (int jj = 0; jj < 8; jj++) acc[jj] = (f32x4){0.f, 0.f, 0.f, 0.f};

        #pragma unroll 1
        for (int kb = 0; kb < 9; kb++) {
            __syncthreads();
            stage16(w1f_hi + (kb << 12) + goff,        lb0H);
            stage16(w1f_hi + (kb << 12) + 2048 + goff, lb1H);
            stage16(w1f_lo + (kb << 12) + goff,        lb0L);
            stage16(w1f_lo + (kb << 12) + 2048 + goff, lb1L);
            bf16x8 ah, al;
            if (kb < 8) {
                const unsigned int* src = (kb < 4) ? (hp + (size_t)srcA * 128 + kb * 32 + g * 8)
                                                   : (hp + (size_t)colA * 128 + (kb - 4) * 32 + g * 8);
                uint4 v0 = *(const uint4*)src;
                uint4 v1 = *((const uint4*)src + 1);
                unpack8(v0, v1, ah, al);
            } else {
                float tv[8];
                #pragma unroll
                for (int q = 0; q < 8; q++) tv[q] = 0.f;
                if (g == 0) {
                    tv[0] = rad;
                    #pragma unroll
                    for (int q = 1; q < 8; q++) tv[q] = eattr[(size_t)e*16 + (q-1)];
                } else if (g == 1) {
                    #pragma unroll
                    for (int q = 0; q < 8; q++) tv[q] = eattr[(size_t)e*16 + 7 + q];
                } else if (g == 2) {
                    tv[0] = eattr[(size_t)e*16 + 15];
                }
                #pragma unroll
                for (int q = 0; q < 8; q++) { unsigned short hh, ll; csplit(tv[q], hh, ll); ah[q] = (short)hh; al[q] = (short)ll; }
            }
            __syncthreads();
            __builtin_amdgcn_s_setprio(1);
            #pragma unroll
            for (int jj = 0; jj < 8; jj++) {
                const int off = (jj << 9) + (l << 3);
                bf16x8 wh = *(const bf16x8*)&wbufH[off];
                bf16x8 wl = *(const bf16x8*)&wbufL[off];
                acc[jj] = __builtin_amdgcn_mfma_f32_16x16x32_bf16(ah, wh, acc[jj], 0, 0, 0);
                acc[jj] = __builtin_amdgcn_mfma_f32_16x16x32_bf16(al, wh, acc[jj], 0, 0, 0);
                acc[jj] = __builtin_amdgcn_mfma_f32_16x16x32_bf16(ah, wl, acc[jj], 0, 0, 0);
            }
            __builtin_amdgcn_s_setprio(0);
        }
        #pragma unroll
        for (int jj = 0; jj < 8; jj++) {
            const int n = jj * 16 + er;
            const float bv = eb1[n];
            #pragma unroll
            for (int reg = 0; reg < 4; reg++) {
                const int row = g * 4 + reg;
                float v = silu_f(acc[jj][reg] + bv);
                C1[wid][row * 128 + (n ^ ((row & 7) << 3))] = f2bf(v);
            }
        }
    }

    // ---- phase 2: m = silu(C1 @ W2 + b2); emit kk-summed msum; stage M over C1 ----
    {
        f32x4 acc[8];
        #pragma unroll
        for (int jj = 0; jj < 8; jj++) acc[jj] = (f32x4){0.f, 0.f, 0.f, 0.f};

        #pragma unroll 1
        for (int kb = 0; kb < 4; kb++) {
            __syncthreads();
            stage16(w2f_hi + (kb << 12) + goff,        lb0H);
            stage16(w2f_hi + (kb << 12) + 2048 + goff, lb1H);
            stage16(w2f_lo + (kb << 12) + goff,        lb0L);
            stage16(w2f_lo + (kb << 12) + 2048 + goff, lb1L);
            const int aoff = er * 128 + ((kb * 32 + g * 8) ^ ((er & 7) << 3));
            bf16x8 a2 = *(const bf16x8*)&C1[wid][aoff];
            __syncthreads();
            __builtin_amdgcn_s_setprio(1);
            #pragma unroll
            for (int jj = 0; jj < 8; jj++) {
                const int off = (jj << 9) + (l << 3);
                bf16x8 wh = *(const bf16x8*)&wbufH[off];
                bf16x8 wl = *(const bf16x8*)&wbufL[off];
                acc[jj] = __builtin_amdgcn_mfma_f32_16x16x32_bf16(a2, wh, acc[jj], 0, 0, 0);
                acc[jj] = __builtin_amdgcn_mfma_f32_16x16x32_bf16(a2, wl, acc[jj], 0, 0, 0);
            }
            __builtin_amdgcn_s_setprio(0);
        }
        #pragma unroll
        for (int jj = 0; jj < 8; jj++) {
            const int n = jj * 16 + er;
            const float bv = eb2[n];
            float ms = 0.f;
            #pragma unroll
            for (int reg = 0; reg < 4; reg++) {
                const int row = g * 4 + reg;       // u = g, kk = reg
                float v = silu_f(acc[jj][reg] + bv);
                if (reg < 3) ms += v;
                C1[wid][row * 128 + (n ^ ((row & 7) << 3))] = f2bf(v);
            }
            msum[(size_t)(e * 4 + g) * 128 + n] = f2bf(ms);
        }
    }

    // ---- phase 3: w = silu(m @ CW1 + cb1) @ cw2; emit xsum per (edge,u) ----
    {
        f32x4 acc[8];
        #pragma unroll
        for (int jj = 0; jj < 8; jj++) acc[jj] = (f32x4){0.f, 0.f, 0.f, 0.f};

        #pragma unroll 1
        for (int kb = 0; kb < 4; kb++) {
            __syncthreads();
            stage16(c1f_hi + (kb << 12) + goff,        lb0H);
            stage16(c1f_hi + (kb << 12) + 2048 + goff, lb1H);
            stage16(c1f_lo + (kb << 12) + goff,        lb0L);
            stage16(c1f_lo + (kb << 12) + 2048 + goff, lb1L);
            const int aoff = er * 128 + ((kb * 32 + g * 8) ^ ((er & 7) << 3));
            bf16x8 a3 = *(const bf16x8*)&C1[wid][aoff];
            __syncthreads();
            __builtin_amdgcn_s_setprio(1);
            #pragma unroll
            for (int jj = 0; jj < 8; jj++) {
                const int off = (jj << 9) + (l << 3);
                bf16x8 wh = *(const bf16x8*)&wbufH[off];
                bf16x8 wl = *(const bf16x8*)&wbufL[off];
                acc[jj] = __builtin_amdgcn_mfma_f32_16x16x32_bf16(a3, wh, acc[jj], 0, 0, 0);
                acc[jj] = __builtin_amdgcn_mfma_f32_16x16x32_bf16(a3, wl, acc[jj], 0, 0, 0);
            }
            __builtin_amdgcn_s_setprio(0);
        }
        float p[4] = {0.f, 0.f, 0.f, 0.f};
        #pragma unroll
        for (int jj = 0; jj < 8; jj++) {
            const int n = jj * 16 + er;
            const float cb = cb1[n], cw = cw2v[n];
            #pragma unroll
            for (int reg = 0; reg < 4; reg++)
                p[reg] += silu_f(acc[jj][reg] + cb) * cw;
        }
        #pragma unroll
        for (int d = 1; d < 16; d <<= 1) {
            #pragma unroll
            for (int reg = 0; reg < 4; reg++)
                p[reg] += __shfl_xor(p[reg], d);
        }
        if (er < 3) {
            float xs = 0.f;
            #pragma unroll
            for (int reg = 0; reg < 3; reg++)
                xs += diffS[wid][(g * 4 + reg) * 3 + er] * p[reg];
            xsum[(size_t)(e * 4 + g) * 3 + er] = xs;
        }
    }
}

// ---------------- coordinate update (CSR gather of xsum) ----------------

__global__ void k_xupd(const float* __restrict__ xcur, const float* __restrict__ xsum,
                       const int* __restrict__ offB, const int* __restrict__ listE,
                       float* __restrict__ xnext)
{
    int i = blockIdx.x * 256 + threadIdx.x;
    if (i >= NATOM * 3) return;
    int a = i / 3, d = i - a * 3;
    int b = a >> 2, u = a & 3;
    int o0 = offB[b], o1 = offB[b + 1];
    float xs = 0.f;
    for (int pos = o0; pos < o1; pos++) {
        int e = listE[pos];
        xs += xsum[(size_t)(e * 4 + u) * 3 + d];
    }
    int deg = o1 - o0;
    xnext[i] = xcur[i] + ((deg > 0) ? xs / (3.0f * (float)deg) : 0.f);
}

// ---------------- fused node MLP (gathers msum directly; hybrid-precision MFMA) ----------------
// WG = 256 = 4 waves; each wave owns 16 atoms. h_new = h + silu([h|agg]@w1+b1)@w2+b2,
// where agg[atom] = sum over CSR edges of msum — gathered on the fly (no agg tensor).
// hid stored single RNE-bf16 -> phase B uses 2 MFMA.

__global__ __launch_bounds__(256, 4) void k_node(
    unsigned int* __restrict__ hp,
    const unsigned short* __restrict__ msum,
    const int* __restrict__ offB,
    const int* __restrict__ listE,
    const unsigned short* __restrict__ n1f_hi, const unsigned short* __restrict__ n1f_lo,
    const unsigned short* __restrict__ n2f_hi, const unsigned short* __restrict__ n2f_lo,
    const float* __restrict__ nb1,
    const float* __restrict__ nb2)
{
    __shared__ unsigned short wbufH[4096], wbufL[4096];
    __shared__ unsigned short hid[4][16 * 128];

    const int tid = threadIdx.x;
    const int wid = tid >> 6, l = tid & 63;
    const int g = l >> 4, er = l & 15;
    const int a0 = blockIdx.x * 64 + wid * 16;
    const int a = a0 + er;
    const int b = a >> 2, u = a & 3;
    const int o0 = offB[b], o1 = offB[b + 1];

    const int goff = wid * 512 + l * 8;
    unsigned short* lb0H = wbufH + wid * 512;
    unsigned short* lb1H = wbufH + 2048 + wid * 512;
    unsigned short* lb0L = wbufL + wid * 512;
    unsigned short* lb1L = wbufL + 2048 + wid * 512;

    // ---- phase A: hid = silu([h|agg] @ W1 + b1), K=256, 3-MFMA split ----
    {
        f32x4 acc[8];
        #pragma unroll
        for (int jj = 0; jj < 8; jj++) acc[jj] = (f32x4){0.f, 0.f, 0.f, 0.f};

        #pragma unroll 1
        for (int kb = 0; kb < 8; kb++) {
            __syncthreads();
            stage16(n1f_hi + (kb << 12) + goff,        lb0H);
            stage16(n1f_hi + (kb << 12) + 2048 + goff, lb1H);
            stage16(n1f_lo + (kb << 12) + goff,        lb0L);
            stage16(n1f_lo + (kb << 12) + 2048 + goff, lb1L);
            bf16x8 ah, al;
            if (kb < 4) {
                const unsigned int* src = hp + (size_t)a * 128 + kb * 32 + g * 8;
                uint4 v0 = *(const uint4*)src;
                uint4 v1 = *((const uint4*)src + 1);
                unpack8(v0, v1, ah, al);
            } else {
                float s[8];
                #pragma unroll
                for (int q = 0; q < 8; q++) s[q] = 0.f;
                for (int pos = o0; pos < o1; pos++) {
                    const int e = listE[pos];
                    bf16x8 mv = *(const bf16x8*)(msum + (size_t)(e * 4 + u) * 128 + (kb - 4) * 32 + g * 8);
                    #pragma unroll
                    for (int q = 0; q < 8; q++) s[q] += bf2f((unsigned short)mv[q]);
                }
                #pragma unroll
                for (int q = 0; q < 8; q++) { unsigned short hh, ll; csplit(s[q], hh, ll); ah[q] = (short)hh; al[q] = (short)ll; }
            }
            __syncthreads();
            __builtin_amdgcn_s_setprio(1);
            #pragma unroll
            for (int jj = 0; jj < 8; jj++) {
                const int off = (jj << 9) + (l << 3);
                bf16x8 wh = *(const bf16x8*)&wbufH[off];
                bf16x8 wl = *(const bf16x8*)&wbufL[off];
                acc[jj] = __builtin_amdgcn_mfma_f32_16x16x32_bf16(ah, wh, acc[jj], 0, 0, 0);
                acc[jj] = __builtin_amdgcn_mfma_f32_16x16x32_bf16(al, wh, acc[jj], 0, 0, 0);
                acc[jj] = __builtin_amdgcn_mfma_f32_16x16x32_bf16(ah, wl, acc[jj], 0, 0, 0);
            }
            __builtin_amdgcn_s_setprio(0);
        }
        #pragma unroll
        for (int jj = 0; jj < 8; jj++) {
            const int n = jj * 16 + er;
            const float bv = nb1[n];
            #pragma unroll
            for (int reg = 0; reg < 4; reg++) {
                const int row = g * 4 + reg;
                float v = silu_f(acc[jj][reg] + bv);
                hid[wid][row * 128 + (n ^ ((row & 7) << 3))] = f2bf(v);
            }
        }
    }

    // ---- phase B: h += hid @ W2 + b2, K=128, 2-MFMA ----
    {
        f32x4 acc[8];
        #pragma unroll
        for (int jj = 0; jj < 8; jj++) acc[jj] = (f32x4){0.f, 0.f, 0.f, 0.f};

        #pragma unroll 1
        for (int kb = 0; kb < 4; kb++) {
            __syncthreads();
            stage16(n2f_hi + (kb << 12) + goff,        lb0H);
            stage16(n2f_hi + (kb << 12) + 2048 + goff, lb1H);
            stage16(n2f_lo + (kb << 12) + goff,        lb0L);
            stage16(n2f_lo + (kb << 12) + 2048 + goff, lb1L);
            const int aoff = er * 128 + ((kb * 32 + g * 8) ^ ((er & 7) << 3));
            bf16x8 ab = *(const bf16x8*)&hid[wid][aoff];
            __syncthreads();
            __builtin_amdgcn_s_setprio(1);
            #pragma unroll
            for (int jj = 0; jj < 8; jj++) {
                const int off = (jj << 9) + (l << 3);
                bf16x8 wh = *(const bf16x8*)&wbufH[off];
                bf16x8 wl = *(const bf16x8*)&wbufL[off];
                acc[jj] = __builtin_amdgcn_mfma_f32_16x16x32_bf16(ab, wh, acc[jj], 0, 0, 0);
                acc[jj] = __builtin_amdgcn_mfma_f32_16x16x32_bf16(ab, wl, acc[jj], 0, 0, 0);
            }
            __builtin_amdgcn_s_setprio(0);
        }
        #pragma unroll
        for (int jj = 0; jj < 8; jj++) {
            const int n = jj * 16 + er;
            const float bv = nb2[n];
            #pragma unroll
            for (int reg = 0; reg < 4; reg++) {
                const int row = g * 4 + reg;
                const size_t idx = (size_t)(a0 + row) * 128 + n;
                float v = acc[jj][reg] + bv + unpackf(hp[idx]);
                hp[idx] = packhl(v);
            }
        }
    }
}

// ---------------- generic tiled f32 GEMM (emb MLPs; pack/unpack variants) ----------------

template<int KT, bool PACKIN, bool PACKOUT>
__global__ __launch_bounds__(128) void k_gemm(
    const float* __restrict__ A0,
    const float* __restrict__ W, const float* __restrict__ bias,
    float* __restrict__ C, int M)
{
    __shared__ float At[KT][32];
    __shared__ float Bs[32][128];
    const int tid = threadIdx.x;
    const int tile0 = blockIdx.x * 32;
    const int r = tid >> 2, part = tid & 3;
    const int gr = tile0 + r;

    if (gr < M) {
        #pragma unroll
        for (int j = 0; j < 8; j++) {
            int c = part * 32 + j * 4;
            float f0, f1, f2, f3;
            if (PACKIN) {
                const unsigned int* ap = (const unsigned int*)A0 + (size_t)gr * 128 + c;
                uint4 v = *(const uint4*)ap;
                f0 = unpackf(v.x); f1 = unpackf(v.y); f2 = unpackf(v.z); f3 = unpackf(v.w);
            } else {
                float4 v = *(const float4*)(A0 + (size_t)gr * 128 + c);
                f0 = v.x; f1 = v.y; f2 = v.z; f3 = v.w;
            }
            At[c][r] = f0; At[c+1][r] = f1; At[c+2][r] = f2; At[c+3][r] = f3;
        }
    } else {
        #pragma unroll
        for (int j = 0; j < 8; j++) {
            int c = part * 32 + j * 4;
            At[c][r] = 0.f; At[c+1][r] = 0.f; At[c+2][r] = 0.f; At[c+3][r] = 0.f;
        }
    }

    float acc[4][8];
    #pragma unroll
    for (int i = 0; i < 4; i++)
        #pragma unroll
        for (int j = 0; j < 8; j++) acc[i][j] = 0.f;

    const int tx = tid & 15, ty = tid >> 4;

    for (int kb = 0; kb < KT / 32; kb++) {
        __syncthreads();
        #pragma unroll
        for (int j = 0; j < 8; j++) {
            int li = j * 512 + tid * 4;
            int kk = li >> 7, c = li & 127;
            float4 v = *(const float4*)(W + (size_t)(kb * 32 + kk) * 128 + c);
            *(float4*)&Bs[kk][c] = v;
        }
        __syncthreads();
        #pragma unroll 8
        for (int kk = 0; kk < 32; kk++) {
            float4 a  = *(const float4*)&At[kb * 32 + kk][ty * 4];
            float4 b0 = *(const float4*)&Bs[kk][tx * 8];
            float4 b1 = *(const float4*)&Bs[kk][tx * 8 + 4];
            float av[4] = {a.x, a.y, a.z, a.w};
            float bv[8] = {b0.x, b0.y, b0.z, b0.w, b1.x, b1.y, b1.z, b1.w};
            #pragma unroll
            for (int i = 0; i < 4; i++)
                #pragma unroll
                for (int j = 0; j < 8; j++)
                    acc[i][j] = fmaf(av[i], bv[j], acc[i][j]);
        }
    }

    #pragma unroll
    for (int i = 0; i < 4; i++) {
        int grr = tile0 + ty * 4 + i;
        if (grr >= M) continue;
        #pragma unroll
        for (int j = 0; j < 8; j++) {
            int c = tx * 8 + j;
            float v = acc[i][j] + bias[c];
            if (PACKOUT) ((unsigned int*)C)[(size_t)grr * 128 + c] = packhl(v);
            else         C[(size_t)grr * 128 + c] = v;
        }
    }
}

// ---------------- launch ----------------

extern "C" void kernel_launch(void* const* d_in, const int* in_sizes, int n_in,
                              void* d_out, int out_size, void* d_ws, size_t ws_size,
                              hipStream_t stream) {
    const float* H        = (const float*)d_in[0];
    const float* Z        = (const float*)d_in[1];
    const int*   edges    = (const int*)  d_in[4];
    const float* eattr    = (const float*)d_in[5];
    const float* emb_in_w = (const float*)d_in[6];
    const float* emb_in_b = (const float*)d_in[7];
    const float* emb_out_w= (const float*)d_in[8];
    const float* emb_out_b= (const float*)d_in[9];
    const float* edge_w1  = (const float*)d_in[10];
    const float* edge_b1  = (const float*)d_in[11];
    const float* edge_w2  = (const float*)d_in[12];
    const float* edge_b2  = (const float*)d_in[13];
    const float* node_w1  = (const float*)d_in[14];
    const float* node_b1  = (const float*)d_in[15];
    const float* node_w2  = (const float*)d_in[16];
    const float* node_b2  = (const float*)d_in[17];
    const float* coord_w1 = (const float*)d_in[18];
    const float* coord_b1 = (const float*)d_in[19];
    const float* coord_w2 = (const float*)d_in[20];

    float* out  = (float*)d_out;
    float* hbuf = out;                              // [N][128]  (packed u32 during layers)
    unsigned int* hp = (unsigned int*)hbuf;
    float* xout = out + (size_t)NATOM * 128;        // [N][3]

    // workspace (~37 MB), 16B-aligned sections
    char* w = (char*)d_ws;
    unsigned short* msum = (unsigned short*)w;  w += (size_t)NGRP * 128 * 2;  // 30.72 MB
    float* xsum = (float*)w;           w += (size_t)NGRP * 3 * 4;            // 1.44 MB
    float* xA  = (float*)w;            w += (size_t)NATOM * 3 * 4;
    float* xB  = (float*)w;            w += (size_t)NATOM * 3 * 4;
    unsigned short* w1f_hi = (unsigned short*)w;  w += (size_t)3 * W1F_L * 2;
    unsigned short* w1f_lo = (unsigned short*)w;  w += (size_t)3 * W1F_L * 2;
    unsigned short* w2f_hi = (unsigned short*)w;  w += (size_t)3 * W2F_L * 2;
    unsigned short* w2f_lo = (unsigned short*)w;  w += (size_t)3 * W2F_L * 2;
    unsigned short* c1f_hi = (unsigned short*)w;  w += (size_t)3 * W2F_L * 2;
    unsigned short* c1f_lo = (unsigned short*)w;  w += (size_t)3 * W2F_L * 2;
    unsigned short* n1f_hi = (unsigned short*)w;  w += (size_t)3 * NW1F_L * 2;
    unsigned short* n1f_lo = (unsigned short*)w;  w += (size_t)3 * NW1F_L * 2;
    unsigned short* n2f_hi = (unsigned short*)w;  w += (size_t)3 * W2F_L * 2;
    unsigned short* n2f_lo = (unsigned short*)w;  w += (size_t)3 * W2F_L * 2;
    int* colIdx = (int*)w;             w += (size_t)EALL * 4;
    int* degB   = (int*)w;             w += (size_t)NBLK * 4;
    int* cursor = (int*)w;             w += (size_t)NBLK * 4;
    int* listE  = (int*)w;             w += (size_t)EBK * 4;
    int* offB   = (int*)w;             w += (size_t)(NBLK + 1) * 4;

    hipMemsetAsync(degB,   0, NBLK * sizeof(int), stream);
    hipMemsetAsync(cursor, 0, NBLK * sizeof(int), stream);

    k_count<<<(EBK + 255) / 256, 256, 0, stream>>>(edges, degB);
    k_scan <<<1, 1024, 0, stream>>>(degB, offB);
    k_fill <<<(EBK + 255) / 256, 256, 0, stream>>>(edges, offB, cursor, listE);
    k_topk <<<(EBK * UU + 255) / 256, 256, 0, stream>>>(edges, Z, colIdx);

    {
        int total = 3 * W1F_L + 3 * W2F_L + 3 * W2F_L + 3 * NW1F_L + 3 * W2F_L;
        k_wfrag<<<(total + 255) / 256, 256, 0, stream>>>(
            edge_w1, edge_w2, coord_w1, node_w1, node_w2,
            w1f_hi, w1f_lo, w2f_hi, w2f_lo, c1f_hi, c1f_lo,
            n1f_hi, n1f_lo, n2f_hi, n2f_lo);
    }

    // h = H @ emb_in_w + b  (write packed hi/lo)
    k_gemm<128, false, true><<<NATOM / 32, 128, 0, stream>>>(
        H, emb_in_w, emb_in_b, (float*)hp, NATOM);

    const float* xcur = Z;
    for (int l = 0; l < LAY; l++) {
        float* xnext = (l == 0) ? xA : (l == 1) ? xB : xout;

        k_edge_shared<<<EBK / 4, 256, 0, stream>>>(
            hp, xcur, eattr, edges, colIdx,
            w1f_hi + (size_t)l * W1F_L, w1f_lo + (size_t)l * W1F_L,
            w2f_hi + (size_t)l * W2F_L, w2f_lo + (size_t)l * W2F_L,
            c1f_hi + (size_t)l * W2F_L, c1f_lo + (size_t)l * W2F_L,
            edge_b1 + l * 128, edge_b2 + l * 128, coord_b1 + l * 128, coord_w2 + l * 128,
            msum, xsum);

        k_xupd<<<(NATOM * 3 + 255) / 256, 256, 0, stream>>>(xcur, xsum, offB, listE, xnext);

        k_node<<<NATOM / 64, 256, 0, stream>>>(
            hp, msum, offB, listE,
            n1f_hi + (size_t)l * NW1F_L, n1f_lo + (size_t)l * NW1F_L,
            n2f_hi + (size_t)l * W2F_L, n2f_lo + (size_t)l * W2F_L,
            node_b1 + l * 128, node_b2 + l * 128);

        xcur = xnext;
    }

    // h_out = h @ emb_out_w + b  (read packed, write f32 in-place)
    k_gemm<128, true, false><<<NATOM / 32, 128, 0, stream>>>(
        hbuf, emb_out_w, emb_out_b, hbuf, NATOM);
}

// Round 11
// 895.656 us; speedup vs baseline: 5.9124x; 1.1165x over previous
//
#include <hip/hip_runtime.h>
#include <math.h>

#define HIDC 128
#define EDGEF 16
#define LAY 3
#define KNN 3
#define UU 4
#define NBLK 20000
#define NATOM (NBLK*UU)      // 80000
#define EBK 30000
#define EALL (EBK*UU*KNN)    // 360000
#define NGRP (EBK*UU)        // 120000 (edge,u) groups

#define W1F_L 36864          // 9 kb * 8 j * 64 lanes * 8
#define W2F_L 16384          // 4 kb * 8 j * 64 lanes * 8
#define NW1F_L 32768         // 8 kb * 8 j * 64 lanes * 8

#define E_WG 16              // block-edges per edge-kernel workgroup
#define ROWS_WG (E_WG*12)    // 192 rows
#define WAVES_WG 12

typedef __attribute__((ext_vector_type(8))) short bf16x8;
typedef __attribute__((ext_vector_type(4))) float f32x4;

__device__ __forceinline__ float silu_f(float v) {
    return __fdividef(v, 1.0f + __expf(-v));
}

__device__ __forceinline__ unsigned short f2bf(float f) {
    union { float f; unsigned int u; } v; v.f = f;
    unsigned int r = v.u + 0x7FFFu + ((v.u >> 16) & 1u);
    return (unsigned short)(r >> 16);
}

__device__ __forceinline__ float bf2f(unsigned short h) {
    union { unsigned int u; float f; } t; t.u = ((unsigned int)h) << 16;
    return t.f;
}

// full-precision split (RNE hi) — one-time weight prep only
__device__ __forceinline__ void split2(float v, short& hi, short& lo) {
    unsigned short h = f2bf(v);
    hi = (short)h;
    lo = (short)f2bf(v - bf2f(h));
}

// cheap split: truncated hi + RNE lo (lo captures truncation exactly; ~2^-17 rel)
__device__ __forceinline__ void csplit(float v, unsigned short& hi, unsigned short& lo) {
    unsigned int hu = __float_as_uint(v) & 0xffff0000u;
    hi = (unsigned short)(hu >> 16);
    lo = f2bf(v - __uint_as_float(hu));
}

__device__ __forceinline__ unsigned int packhl(float v) {
    unsigned int hu = __float_as_uint(v) & 0xffff0000u;
    return hu | (unsigned int)f2bf(v - __uint_as_float(hu));
}

__device__ __forceinline__ float unpackf(unsigned int u) {
    return bf2f((unsigned short)(u >> 16)) + bf2f((unsigned short)(u & 0xffffu));
}

__device__ __forceinline__ void unpack8(uint4 v0, uint4 v1, bf16x8& ah, bf16x8& al) {
    unsigned int uu[8] = {v0.x, v0.y, v0.z, v0.w, v1.x, v1.y, v1.z, v1.w};
    #pragma unroll
    for (int q = 0; q < 8; q++) {
        ah[q] = (short)(unsigned short)(uu[q] >> 16);
        al[q] = (short)(unsigned short)(uu[q] & 0xffffu);
    }
}

// async global->LDS DMA: 16B per lane, LDS dest = wave-uniform base + lane*16
__device__ __forceinline__ void stage16(const unsigned short* gsrc, unsigned short* ldst) {
    __builtin_amdgcn_global_load_lds(
        (const __attribute__((address_space(1))) unsigned int*)(const void*)gsrc,
        (__attribute__((address_space(3))) unsigned int*)(void*)ldst,
        16, 0, 0);
}

// ---------------- CSR build ----------------

__global__ void k_count(const int* __restrict__ edges, int* __restrict__ degB) {
    int e = blockIdx.x * 256 + threadIdx.x;
    if (e < EBK) atomicAdd(&degB[edges[e]], 1);
}

__global__ void k_scan(const int* __restrict__ degB, int* __restrict__ offB) {
    __shared__ int s[1024];
    __shared__ int carry;
    if (threadIdx.x == 0) carry = 0;
    __syncthreads();
    for (int base = 0; base < NBLK; base += 1024) {
        int i = base + threadIdx.x;
        int v = (i < NBLK) ? degB[i] : 0;
        s[threadIdx.x] = v;
        __syncthreads();
        for (int d = 1; d < 1024; d <<= 1) {
            int t = (threadIdx.x >= d) ? s[threadIdx.x - d] : 0;
            __syncthreads();
            s[threadIdx.x] += t;
            __syncthreads();
        }
        if (i < NBLK) offB[i] = carry + s[threadIdx.x] - v;
        int tot = s[1023];
        __syncthreads();
        if (threadIdx.x == 0) carry += tot;
        __syncthreads();
    }
    if (threadIdx.x == 0) offB[NBLK] = carry;
}

__global__ void k_fill(const int* __restrict__ edges, const int* __restrict__ offB,
                       int* __restrict__ cursor, int* __restrict__ listE) {
    int e = blockIdx.x * 256 + threadIdx.x;
    if (e < EBK) {
        int b = edges[e];
        int p = atomicAdd(&cursor[b], 1);
        listE[offB[b] + p] = e;
    }
}

// top-3 nearest dst atoms per src atom; exact f32, tie -> lower index (matches top_k)
__global__ void k_topk(const int* __restrict__ edges, const float* __restrict__ Z,
                       int* __restrict__ colIdx) {
    int t = blockIdx.x * 256 + threadIdx.x;
    if (t >= EBK * UU) return;
    int e = t >> 2, u = t & 3;
    int b0 = edges[e], b1 = edges[EBK + e];
    int s = b0 * UU + u;
    float zs0 = Z[s*3+0], zs1 = Z[s*3+1], zs2 = Z[s*3+2];
    float d2[UU];
    #pragma unroll
    for (int v = 0; v < UU; v++) {
        int d = b1 * UU + v;
        float a0 = __fsub_rn(zs0, Z[d*3+0]);
        float a1 = __fsub_rn(zs1, Z[d*3+1]);
        float a2 = __fsub_rn(zs2, Z[d*3+2]);
        float p0 = __fmul_rn(a0, a0);
        float p1 = __fmul_rn(a1, a1);
        float p2 = __fmul_rn(a2, a2);
        d2[v] = __fadd_rn(__fadd_rn(p0, p1), p2);
    }
    bool used[UU] = {false, false, false, false};
    #pragma unroll
    for (int k = 0; k < KNN; k++) {
        int best = -1;
        float bd = INFINITY;
        #pragma unroll
        for (int v = 0; v < UU; v++) {
            if (!used[v] && d2[v] < bd) { bd = d2[v]; best = v; }
        }
        used[best] = true;
        colIdx[t * KNN + k] = b1 * UU + best;
    }
}

// ---------------- weight fragment precompute (hi/lo bf16, MFMA B-layout) ----------------

__global__ void k_wfrag(const float* __restrict__ ew1, const float* __restrict__ ew2,
                        const float* __restrict__ cw1,
                        const float* __restrict__ nw1, const float* __restrict__ nw2,
                        unsigned short* __restrict__ w1f_hi, unsigned short* __restrict__ w1f_lo,
                        unsigned short* __restrict__ w2f_hi, unsigned short* __restrict__ w2f_lo,
                        unsigned short* __restrict__ c1f_hi, unsigned short* __restrict__ c1f_lo,
                        unsigned short* __restrict__ n1f_hi, unsigned short* __restrict__ n1f_lo,
                        unsigned short* __restrict__ n2f_hi, unsigned short* __restrict__ n2f_lo) {
    int i = blockIdx.x * 256 + threadIdx.x;
    float v = 0.f;
    unsigned short* dh = nullptr;
    unsigned short* dl = nullptr;
    int di = 0;
    if (i < 3 * W1F_L) {
        int l = i / W1F_L, rem = i % W1F_L;
        int chunk = rem >> 9, lane = (rem >> 3) & 63, t = rem & 7;
        int kb = chunk >> 3, j = chunk & 7;
        int k = kb*32 + (lane >> 4)*8 + t, n = j*16 + (lane & 15);
        v = (k < 273) ? ew1[(size_t)l*273*128 + (size_t)k*128 + n] : 0.f;
        dh = w1f_hi; dl = w1f_lo; di = i;
    } else {
        int i2 = i - 3 * W1F_L;
        if (i2 < 3 * W2F_L) {
            int l = i2 / W2F_L, rem = i2 % W2F_L;
            int chunk = rem >> 9, lane = (rem >> 3) & 63, t = rem & 7;
            int kb = chunk >> 3, j = chunk & 7;
            int k = kb*32 + (lane >> 4)*8 + t, n = j*16 + (lane & 15);
            v = ew2[(size_t)l*128*128 + (size_t)k*128 + n];
            dh = w2f_hi; dl = w2f_lo; di = i2;
        } else {
            int i3 = i2 - 3 * W2F_L;
            if (i3 < 3 * W2F_L) {
                int l = i3 / W2F_L, rem = i3 % W2F_L;
                int chunk = rem >> 9, lane = (rem >> 3) & 63, t = rem & 7;
                int kb = chunk >> 3, j = chunk & 7;
                int k = kb*32 + (lane >> 4)*8 + t, n = j*16 + (lane & 15);
                v = cw1[(size_t)l*128*128 + (size_t)k*128 + n];
                dh = c1f_hi; dl = c1f_lo; di = i3;
            } else {
                int i4 = i3 - 3 * W2F_L;
                if (i4 < 3 * NW1F_L) {
                    int l = i4 / NW1F_L, rem = i4 % NW1F_L;
                    int chunk = rem >> 9, lane = (rem >> 3) & 63, t = rem & 7;
                    int kb = chunk >> 3, j = chunk & 7;
                    int k = kb*32 + (lane >> 4)*8 + t, n = j*16 + (lane & 15);
                    v = nw1[(size_t)l*256*128 + (size_t)k*128 + n];
                    dh = n1f_hi; dl = n1f_lo; di = i4;
                } else {
                    int i5 = i4 - 3 * NW1F_L;
                    if (i5 >= 3 * W2F_L) return;
                    int l = i5 / W2F_L, rem = i5 % W2F_L;
                    int chunk = rem >> 9, lane = (rem >> 3) & 63, t = rem & 7;
                    int kb = chunk >> 3, j = chunk & 7;
                    int k = kb*32 + (lane >> 4)*8 + t, n = j*16 + (lane & 15);
                    v = nw2[(size_t)l*128*128 + (size_t)k*128 + n];
                    dh = n2f_hi; dl = n2f_lo; di = i5;
                }
            }
        }
    }
    short hi, lo;
    split2(v, hi, lo);
    dh[di] = (unsigned short)hi;
    dl[di] = (unsigned short)lo;
}

// ---------------- flat-12 fused edge pipeline (hybrid-precision MFMA) ----------------
// WG = 768 threads = 12 waves = 16 block-edges = 192 REAL rows (no kk padding).
// Global row R = e*12 + u*3 + kk. Each wave owns 16 consecutive rows.
// Weights DMA-staged global->LDS once per WG (12-wave reuse). Intermediates in a
// WG-shared Mlds[192][128] bf16 (rows wave-exclusive). msum/xsum via small
// barriered LDS passes after phases 2/3.

__global__ __launch_bounds__(768, 6) void k_edge_flat(
    const unsigned int* __restrict__ hp,
    const float* __restrict__ x,
    const float* __restrict__ eattr,
    const int* __restrict__ edges0,
    const int* __restrict__ colIdx,
    const unsigned short* __restrict__ w1f_hi, const unsigned short* __restrict__ w1f_lo,
    const unsigned short* __restrict__ w2f_hi, const unsigned short* __restrict__ w2f_lo,
    const unsigned short* __restrict__ c1f_hi, const unsigned short* __restrict__ c1f_lo,
    const float* __restrict__ eb1,
    const float* __restrict__ eb2,
    const float* __restrict__ cb1,
    const float* __restrict__ cw2v,
    unsigned short* __restrict__ msum,
    float* __restrict__ xsum)
{
    __shared__ unsigned short wbufH[4096], wbufL[4096];        // 16 KB
    __shared__ unsigned short Mlds[ROWS_WG * 128];             // 48 KB (C1, then M)
    __shared__ float diffLDS[ROWS_WG][3];                      // 2.25 KB
    __shared__ float pLDS[ROWS_WG];                            // 0.75 KB

    const int tid = threadIdx.x;
    const int wid = tid >> 6, l = tid & 63;
    const int g = l >> 4, er = l & 15;
    const int e_base = blockIdx.x * E_WG;
    const int r0 = wid * 16;

    // per-lane gather row (row = r0 + er)
    const int row_g = r0 + er;
    const int e_loc = row_g / 12;
    const int rr = row_g - e_loc * 12;
    const int u = rr / 3;
    const int kk = rr - u * 3;
    const int e = e_base + e_loc;
    const int bs = edges0[e];
    const int srcA = bs * 4 + u;
    const int colA = colIdx[(e * 4 + u) * 3 + kk];
    float rad = 0.f;
    if (g == 0) {
        float dx = x[srcA*3+0] - x[colA*3+0];
        float dy = x[srcA*3+1] - x[colA*3+1];
        float dz = x[srcA*3+2] - x[colA*3+2];
        rad = dx*dx + dy*dy + dz*dz;
        diffLDS[row_g][0] = dx; diffLDS[row_g][1] = dy; diffLDS[row_g][2] = dz;
    }

    // staging: waves 0..3 cover 16 KB/kb exactly as the 4-wave version did
    const int goff = wid * 512 + l * 8;               // shorts (valid for wid<4)
    unsigned short* lb0H = wbufH + wid * 512;
    unsigned short* lb1H = wbufH + 2048 + wid * 512;
    unsigned short* lb0L = wbufL + wid * 512;
    unsigned short* lb1L = wbufL + 2048 + wid * 512;

    // ---- phase 1: C1 = silu([h_r|h_c|rad|ea] @ W1 + b1), K=288, 3-MFMA split ----
    {
        f32x4 acc[8];
        #pragma unroll
        for (int jj = 0; jj < 8; jj++) acc[jj] = (f32x4){0.f, 0.f, 0.f, 0.f};

        #pragma unroll 1
        for (int kb = 0; kb < 9; kb++) {
            __syncthreads();
            if (wid < 4) {
                stage16(w1f_hi + (kb << 12) + goff,        lb0H);
                stage16(w1f_hi + (kb << 12) + 2048 + goff, lb1H);
                stage16(w1f_lo + (kb << 12) + goff,        lb0L);
                stage16(w1f_lo + (kb << 12) + 2048 + goff, lb1L);
            }
            bf16x8 ah, al;
            if (kb < 8) {
                const unsigned int* src = (kb < 4) ? (hp + (size_t)srcA * 128 + kb * 32 + g * 8)
                                                   : (hp + (size_t)colA * 128 + (kb - 4) * 32 + g * 8);
                uint4 v0 = *(const uint4*)src;
                uint4 v1 = *((const uint4*)src + 1);
                unpack8(v0, v1, ah, al);
            } else {
                float tv[8];
                #pragma unroll
                for (int q = 0; q < 8; q++) tv[q] = 0.f;
                if (g == 0) {
                    tv[0] = rad;
                    #pragma unroll
                    for (int q = 1; q < 8; q++) tv[q] = eattr[(size_t)e*16 + (q-1)];
                } else if (g == 1) {
                    #pragma unroll
                    for (int q = 0; q < 8; q++) tv[q] = eattr[(size_t)e*16 + 7 + q];
                } else if (g == 2) {
                    tv[0] = eattr[(size_t)e*16 + 15];
                }
                #pragma unroll
                for (int q = 0; q < 8; q++) { unsigned short hh, ll; csplit(tv[q], hh, ll); ah[q] = (short)hh; al[q] = (short)ll; }
            }
            __syncthreads();
            __builtin_amdgcn_s_setprio(1);
            #pragma unroll
            for (int jj = 0; jj < 8; jj++) {
                const int off = (jj << 9) + (l << 3);
                bf16x8 wh = *(const bf16x8*)&wbufH[off];
                bf16x8 wl = *(const bf16x8*)&wbufL[off];
                acc[jj] = __builtin_amdgcn_mfma_f32_16x16x32_bf16(ah, wh, acc[jj], 0, 0, 0);
                acc[jj] = __builtin_amdgcn_mfma_f32_16x16x32_bf16(al, wh, acc[jj], 0, 0, 0);
                acc[jj] = __builtin_amdgcn_mfma_f32_16x16x32_bf16(ah, wl, acc[jj], 0, 0, 0);
            }
            __builtin_amdgcn_s_setprio(0);
        }
        #pragma unroll
        for (int jj = 0; jj < 8; jj++) {
            const int n = jj * 16 + er;
            const float bv = eb1[n];
            #pragma unroll
            for (int reg = 0; reg < 4; reg++) {
                const int row = r0 + g * 4 + reg;
                float v = silu_f(acc[jj][reg] + bv);
                Mlds[row * 128 + (n ^ ((row & 7) << 3))] = f2bf(v);
            }
        }
    }

    // ---- phase 2: m = silu(C1 @ W2 + b2) -> Mlds (own rows) ----
    {
        f32x4 acc[8];
        #pragma unroll
        for (int jj = 0; jj < 8; jj++) acc[jj] = (f32x4){0.f, 0.f, 0.f, 0.f};

        #pragma unroll 1
        for (int kb = 0; kb < 4; kb++) {
            __syncthreads();
            if (wid < 4) {
                stage16(w2f_hi + (kb << 12) + goff,        lb0H);
                stage16(w2f_hi + (kb << 12) + 2048 + goff, lb1H);
                stage16(w2f_lo + (kb << 12) + goff,        lb0L);
                stage16(w2f_lo + (kb << 12) + 2048 + goff, lb1L);
            }
            const int aoff = row_g * 128 + ((kb * 32 + g * 8) ^ ((row_g & 7) << 3));
            bf16x8 a2 = *(const bf16x8*)&Mlds[aoff];
            __syncthreads();
            __builtin_amdgcn_s_setprio(1);
            #pragma unroll
            for (int jj = 0; jj < 8; jj++) {
                const int off = (jj << 9) + (l << 3);
                bf16x8 wh = *(const bf16x8*)&wbufH[off];
                bf16x8 wl = *(const bf16x8*)&wbufL[off];
                acc[jj] = __builtin_amdgcn_mfma_f32_16x16x32_bf16(a2, wh, acc[jj], 0, 0, 0);
                acc[jj] = __builtin_amdgcn_mfma_f32_16x16x32_bf16(a2, wl, acc[jj], 0, 0, 0);
            }
            __builtin_amdgcn_s_setprio(0);
        }
        #pragma unroll
        for (int jj = 0; jj < 8; jj++) {
            const int n = jj * 16 + er;
            const float bv = eb2[n];
            #pragma unroll
            for (int reg = 0; reg < 4; reg++) {
                const int row = r0 + g * 4 + reg;
                float v = silu_f(acc[jj][reg] + bv);
                Mlds[row * 128 + (n ^ ((row & 7) << 3))] = f2bf(v);
            }
        }
    }
    __syncthreads();

    // ---- msum pass: msum[(e,u)][col] = sum_kk M[e*12+u*3+kk][col] ----
    {
        const int col = tid & 127;
        const int gslot = tid >> 7;                 // 0..5
        for (int gi = gslot; gi < E_WG * 4; gi += 6) {
            const int el = gi >> 2, uu2 = gi & 3;
            const int base = el * 12 + uu2 * 3;
            float ms = 0.f;
            #pragma unroll
            for (int k3 = 0; k3 < 3; k3++) {
                const int row = base + k3;
                ms += bf2f(Mlds[row * 128 + (col ^ ((row & 7) << 3))]);
            }
            msum[(size_t)((e_base + el) * 4 + uu2) * 128 + col] = f2bf(ms);
        }
    }

    // ---- phase 3: w = silu(m @ CW1 + cb1) @ cw2; p per row -> pLDS ----
    {
        f32x4 acc[8];
        #pragma unroll
        for (int jj = 0; jj < 8; jj++) acc[jj] = (f32x4){0.f, 0.f, 0.f, 0.f};

        #pragma unroll 1
        for (int kb = 0; kb < 4; kb++) {
            __syncthreads();
            if (wid < 4) {
                stage16(c1f_hi + (kb << 12) + goff,        lb0H);
                stage16(c1f_hi + (kb << 12) + 2048 + goff, lb1H);
                stage16(c1f_lo + (kb << 12) + goff,        lb0L);
                stage16(c1f_lo + (kb << 12) + 2048 + goff, lb1L);
            }
            const int aoff = row_g * 128 + ((kb * 32 + g * 8) ^ ((row_g & 7) << 3));
            bf16x8 a3 = *(const bf16x8*)&Mlds[aoff];
            __syncthreads();
            __builtin_amdgcn_s_setprio(1);
            #pragma unroll
            for (int jj = 0; jj < 8; jj++) {
                const int off = (jj << 9) + (l << 3);
                bf16x8 wh = *(const bf16x8*)&wbufH[off];
                bf16x8 wl = *(const bf16x8*)&wbufL[off];
                acc[jj] = __builtin_amdgcn_mfma_f32_16x16x32_bf16(a3, wh, acc[jj], 0, 0, 0);
                acc[jj] = __builtin_amdgcn_mfma_f32_16x16x32_bf16(a3, wl, acc[jj], 0, 0, 0);
            }
            __builtin_amdgcn_s_setprio(0);
        }
        float p[4] = {0.f, 0.f, 0.f, 0.f};
        #pragma unroll
        for (int jj = 0; jj < 8; jj++) {
            const int n = jj * 16 + er;
            const float cb = cb1[n], cw = cw2v[n];
            #pragma unroll
            for (int reg = 0; reg < 4; reg++)
                p[reg] += silu_f(acc[jj][reg] + cb) * cw;
        }
        #pragma unroll
        for (int d = 1; d < 16; d <<= 1) {
            #pragma unroll
            for (int reg = 0; reg < 4; reg++)
                p[reg] += __shfl_xor(p[reg], d);
        }
        if (er == 0) {
            #pragma unroll
            for (int reg = 0; reg < 4; reg++)
                pLDS[r0 + g * 4 + reg] = p[reg];
        }
    }
    __syncthreads();

    // ---- xsum pass: xsum[(e,u)][c] = sum_kk diff[row][c] * p[row] ----
    if (tid < E_WG * 4 * 3) {
        const int gi = tid / 3, c = tid - gi * 3;
        const int el = gi >> 2, uu2 = gi & 3;
        const int base = el * 12 + uu2 * 3;
        float xs = 0.f;
        #pragma unroll
        for (int k3 = 0; k3 < 3; k3++)
            xs += diffLDS[base + k3][c] * pLDS[base + k3];
        xsum[(size_t)((e_base + el) * 4 + uu2) * 3 + c] = xs;
    }
}

// ---------------- coordinate update (CSR gather of xsum) ----------------

__global__ void k_xupd(const float* __restrict__ xcur, const float* __restrict__ xsum,
                       const int* __restrict__ offB, const int* __restrict__ listE,
                       float* __restrict__ xnext)
{
    int i = blockIdx.x * 256 + threadIdx.x;
    if (i >= NATOM * 3) return;
    int a = i / 3, d = i - a * 3;
    int b = a >> 2, u = a & 3;
    int o0 = offB[b], o1 = offB[b + 1];
    float xs = 0.f;
    for (int pos = o0; pos < o1; pos++) {
        int e = listE[pos];
        xs += xsum[(size_t)(e * 4 + u) * 3 + d];
    }
    int deg = o1 - o0;
    xnext[i] = xcur[i] + ((deg > 0) ? xs / (3.0f * (float)deg) : 0.f);
}

// ---------------- fused node MLP (gathers msum directly; hybrid-precision MFMA) ----------------

__global__ __launch_bounds__(256, 4) void k_node(
    unsigned int* __restrict__ hp,
    const unsigned short* __restrict__ msum,
    const int* __restrict__ offB,
    const int* __restrict__ listE,
    const unsigned short* __restrict__ n1f_hi, const unsigned short* __restrict__ n1f_lo,
    const unsigned short* __restrict__ n2f_hi, const unsigned short* __restrict__ n2f_lo,
    const float* __restrict__ nb1,
    const float* __restrict__ nb2)
{
    __shared__ unsigned short wbufH[4096], wbufL[4096];
    __shared__ unsigned short hid[4][16 * 128];

    const int tid = threadIdx.x;
    const int wid = tid >> 6, l = tid & 63;
    const int g = l >> 4, er = l & 15;
    const int a0 = blockIdx.x * 64 + wid * 16;
    const int a = a0 + er;
    const int b = a >> 2, u = a & 3;
    const int o0 = offB[b], o1 = offB[b + 1];

    const int goff = wid * 512 + l * 8;
    unsigned short* lb0H = wbufH + wid * 512;
    unsigned short* lb1H = wbufH + 2048 + wid * 512;
    unsigned short* lb0L = wbufL + wid * 512;
    unsigned short* lb1L = wbufL + 2048 + wid * 512;

    // ---- phase A: hid = silu([h|agg] @ W1 + b1), K=256, 3-MFMA split ----
    {
        f32x4 acc[8];
        #pragma unroll
        for (int jj = 0; jj < 8; jj++) acc[jj] = (f32x4){0.f, 0.f, 0.f, 0.f};

        #pragma unroll 1
        for (int kb = 0; kb < 8; kb++) {
            __syncthreads();
            stage16(n1f_hi + (kb << 12) + goff,        lb0H);
            stage16(n1f_hi + (kb << 12) + 2048 + goff, lb1H);
            stage16(n1f_lo + (kb << 12) + goff,        lb0L);
            stage16(n1f_lo + (kb << 12) + 2048 + goff, lb1L);
            bf16x8 ah, al;
            if (kb < 4) {
                const unsigned int* src = hp + (size_t)a * 128 + kb * 32 + g * 8;
                uint4 v0 = *(const uint4*)src;
                uint4 v1 = *((const uint4*)src + 1);
                unpack8(v0, v1, ah, al);
            } else {
                float s[8];
                #pragma unroll
                for (int q = 0; q < 8; q++) s[q] = 0.f;
                for (int pos = o0; pos < o1; pos++) {
                    const int e = listE[pos];
                    bf16x8 mv = *(const bf16x8*)(msum + (size_t)(e * 4 + u) * 128 + (kb - 4) * 32 + g * 8);
                    #pragma unroll
                    for (int q = 0; q < 8; q++) s[q] += bf2f((unsigned short)mv[q]);
                }
                #pragma unroll
                for (int q = 0; q < 8; q++) { unsigned short hh, ll; csplit(s[q], hh, ll); ah[q] = (short)hh; al[q] = (short)ll; }
            }
            __syncthreads();
            __builtin_amdgcn_s_setprio(1);
            #pragma unroll
            for (int jj = 0; jj < 8; jj++) {
                const int off = (jj << 9) + (l << 3);
                bf16x8 wh = *(const bf16x8*)&wbufH[off];
                bf16x8 wl = *(const bf16x8*)&wbufL[off];
                acc[jj] = __builtin_amdgcn_mfma_f32_16x16x32_bf16(ah, wh, acc[jj], 0, 0, 0);
                acc[jj] = __builtin_amdgcn_mfma_f32_16x16x32_bf16(al, wh, acc[jj], 0, 0, 0);
                acc[jj] = __builtin_amdgcn_mfma_f32_16x16x32_bf16(ah, wl, acc[jj], 0, 0, 0);
            }
            __builtin_amdgcn_s_setprio(0);
        }
        #pragma unroll
        for (int jj = 0; jj < 8; jj++) {
            const int n = jj * 16 + er;
            const float bv = nb1[n];
            #pragma unroll
            for (int reg = 0; reg < 4; reg++) {
                const int row = g * 4 + reg;
                float v = silu_f(acc[jj][reg] + bv);
                hid[wid][row * 128 + (n ^ ((row & 7) << 3))] = f2bf(v);
            }
        }
    }

    // ---- phase B: h += hid @ W2 + b2, K=128, 2-MFMA ----
    {
        f32x4 acc[8];
        #pragma unroll
        for (int jj = 0; jj < 8; jj++) acc[jj] = (f32x4){0.f, 0.f, 0.f, 0.f};

        #pragma unroll 1
        for (int kb = 0; kb < 4; kb++) {
            __syncthreads();
            stage16(n2f_hi + (kb << 12) + goff,        lb0H);
            stage16(n2f_hi + (kb << 12) + 2048 + goff, lb1H);
            stage16(n2f_lo + (kb << 12) + goff,        lb0L);
            stage16(n2f_lo + (kb << 12) + 2048 + goff, lb1L);
            const int aoff = er * 128 + ((kb * 32 + g * 8) ^ ((er & 7) << 3));
            bf16x8 ab = *(const bf16x8*)&hid[wid][aoff];
            __syncthreads();
            __builtin_amdgcn_s_setprio(1);
            #pragma unroll
            for (int jj = 0; jj < 8; jj++) {
                const int off = (jj << 9) + (l << 3);
                bf16x8 wh = *(const bf16x8*)&wbufH[off];
                bf16x8 wl = *(const bf16x8*)&wbufL[off];
                acc[jj] = __builtin_amdgcn_mfma_f32_16x16x32_bf16(ab, wh, acc[jj], 0, 0, 0);
                acc[jj] = __builtin_amdgcn_mfma_f32_16x16x32_bf16(ab, wl, acc[jj], 0, 0, 0);
            }
            __builtin_amdgcn_s_setprio(0);
        }
        #pragma unroll
        for (int jj = 0; jj < 8; jj++) {
            const int n = jj * 16 + er;
            const float bv = nb2[n];
            #pragma unroll
            for (int reg = 0; reg < 4; reg++) {
                const int row = g * 4 + reg;
                const size_t idx = (size_t)(a0 + row) * 128 + n;
                float v = acc[jj][reg] + bv + unpackf(hp[idx]);
                hp[idx] = packhl(v);
            }
        }
    }
}

// ---------------- generic tiled f32 GEMM (emb MLPs; pack/unpack variants) ----------------

template<int KT, bool PACKIN, bool PACKOUT>
__global__ __launch_bounds__(128) void k_gemm(
    const float* __restrict__ A0,
    const float* __restrict__ W, const float* __restrict__ bias,
    float* __restrict__ C, int M)
{
    __shared__ float At[KT][32];
    __shared__ float Bs[32][128];
    const int tid = threadIdx.x;
    const int tile0 = blockIdx.x * 32;
    const int r = tid >> 2, part = tid & 3;
    const int gr = tile0 + r;

    if (gr < M) {
        #pragma unroll
        for (int j = 0; j < 8; j++) {
            int c = part * 32 + j * 4;
            float f0, f1, f2, f3;
            if (PACKIN) {
                const unsigned int* ap = (const unsigned int*)A0 + (size_t)gr * 128 + c;
                uint4 v = *(const uint4*)ap;
                f0 = unpackf(v.x); f1 = unpackf(v.y); f2 = unpackf(v.z); f3 = unpackf(v.w);
            } else {
                float4 v = *(const float4*)(A0 + (size_t)gr * 128 + c);
                f0 = v.x; f1 = v.y; f2 = v.z; f3 = v.w;
            }
            At[c][r] = f0; At[c+1][r] = f1; At[c+2][r] = f2; At[c+3][r] = f3;
        }
    } else {
        #pragma unroll
        for (int j = 0; j < 8; j++) {
            int c = part * 32 + j * 4;
            At[c][r] = 0.f; At[c+1][r] = 0.f; At[c+2][r] = 0.f; At[c+3][r] = 0.f;
        }
    }

    float acc[4][8];
    #pragma unroll
    for (int i = 0; i < 4; i++)
        #pragma unroll
        for (int j = 0; j < 8; j++) acc[i][j] = 0.f;

    const int tx = tid & 15, ty = tid >> 4;

    for (int kb = 0; kb < KT / 32; kb++) {
        __syncthreads();
        #pragma unroll
        for (int j = 0; j < 8; j++) {
            int li = j * 512 + tid * 4;
            int kk = li >> 7, c = li & 127;
            float4 v = *(const float4*)(W + (size_t)(kb * 32 + kk) * 128 + c);
            *(float4*)&Bs[kk][c] = v;
        }
        __syncthreads();
        #pragma unroll 8
        for (int kk = 0; kk < 32; kk++) {
            float4 a  = *(const float4*)&At[kb * 32 + kk][ty * 4];
            float4 b0 = *(const float4*)&Bs[kk][tx * 8];
            float4 b1 = *(const float4*)&Bs[kk][tx * 8 + 4];
            float av[4] = {a.x, a.y, a.z, a.w};
            float bv[8] = {b0.x, b0.y, b0.z, b0.w, b1.x, b1.y, b1.z, b1.w};
            #pragma unroll
            for (int i = 0; i < 4; i++)
                #pragma unroll
                for (int j = 0; j < 8; j++)
                    acc[i][j] = fmaf(av[i], bv[j], acc[i][j]);
        }
    }

    #pragma unroll
    for (int i = 0; i < 4; i++) {
        int grr = tile0 + ty * 4 + i;
        if (grr >= M) continue;
        #pragma unroll
        for (int j = 0; j < 8; j++) {
            int c = tx * 8 + j;
            float v = acc[i][j] + bias[c];
            if (PACKOUT) ((unsigned int*)C)[(size_t)grr * 128 + c] = packhl(v);
            else         C[(size_t)grr * 128 + c] = v;
        }
    }
}

// ---------------- launch ----------------

extern "C" void kernel_launch(void* const* d_in, const int* in_sizes, int n_in,
                              void* d_out, int out_size, void* d_ws, size_t ws_size,
                              hipStream_t stream) {
    const float* H        = (const float*)d_in[0];
    const float* Z        = (const float*)d_in[1];
    const int*   edges    = (const int*)  d_in[4];
    const float* eattr    = (const float*)d_in[5];
    const float* emb_in_w = (const float*)d_in[6];
    const float* emb_in_b = (const float*)d_in[7];
    const float* emb_out_w= (const float*)d_in[8];
    const float* emb_out_b= (const float*)d_in[9];
    const float* edge_w1  = (const float*)d_in[10];
    const float* edge_b1  = (const float*)d_in[11];
    const float* edge_w2  = (const float*)d_in[12];
    const float* edge_b2  = (const float*)d_in[13];
    const float* node_w1  = (const float*)d_in[14];
    const float* node_b1  = (const float*)d_in[15];
    const float* node_w2  = (const float*)d_in[16];
    const float* node_b2  = (const float*)d_in[17];
    const float* coord_w1 = (const float*)d_in[18];
    const float* coord_b1 = (const float*)d_in[19];
    const float* coord_w2 = (const float*)d_in[20];

    float* out  = (float*)d_out;
    float* hbuf = out;                              // [N][128]  (packed u32 during layers)
    unsigned int* hp = (unsigned int*)hbuf;
    float* xout = out + (size_t)NATOM * 128;        // [N][3]

    // workspace (~37 MB), 16B-aligned sections
    char* w = (char*)d_ws;
    unsigned short* msum = (unsigned short*)w;  w += (size_t)NGRP * 128 * 2;  // 30.72 MB
    float* xsum = (float*)w;           w += (size_t)NGRP * 3 * 4;            // 1.44 MB
    float* xA  = (float*)w;            w += (size_t)NATOM * 3 * 4;
    float* xB  = (float*)w;            w += (size_t)NATOM * 3 * 4;
    unsigned short* w1f_hi = (unsigned short*)w;  w += (size_t)3 * W1F_L * 2;
    unsigned short* w1f_lo = (unsigned short*)w;  w += (size_t)3 * W1F_L * 2;
    unsigned short* w2f_hi = (unsigned short*)w;  w += (size_t)3 * W2F_L * 2;
    unsigned short* w2f_lo = (unsigned short*)w;  w += (size_t)3 * W2F_L * 2;
    unsigned short* c1f_hi = (unsigned short*)w;  w += (size_t)3 * W2F_L * 2;
    unsigned short* c1f_lo = (unsigned short*)w;  w += (size_t)3 * W2F_L * 2;
    unsigned short* n1f_hi = (unsigned short*)w;  w += (size_t)3 * NW1F_L * 2;
    unsigned short* n1f_lo = (unsigned short*)w;  w += (size_t)3 * NW1F_L * 2;
    unsigned short* n2f_hi = (unsigned short*)w;  w += (size_t)3 * W2F_L * 2;
    unsigned short* n2f_lo = (unsigned short*)w;  w += (size_t)3 * W2F_L * 2;
    int* colIdx = (int*)w;             w += (size_t)EALL * 4;
    int* degB   = (int*)w;             w += (size_t)NBLK * 4;
    int* cursor = (int*)w;             w += (size_t)NBLK * 4;
    int* listE  = (int*)w;             w += (size_t)EBK * 4;
    int* offB   = (int*)w;             w += (size_t)(NBLK + 1) * 4;

    hipMemsetAsync(degB,   0, NBLK * sizeof(int), stream);
    hipMemsetAsync(cursor, 0, NBLK * sizeof(int), stream);

    k_count<<<(EBK + 255) / 256, 256, 0, stream>>>(edges, degB);
    k_scan <<<1, 1024, 0, stream>>>(degB, offB);
    k_fill <<<(EBK + 255) / 256, 256, 0, stream>>>(edges, offB, cursor, listE);
    k_topk <<<(EBK * UU + 255) / 256, 256, 0, stream>>>(edges, Z, colIdx);

    {
        int total = 3 * W1F_L + 3 * W2F_L + 3 * W2F_L + 3 * NW1F_L + 3 * W2F_L;
        k_wfrag<<<(total + 255) / 256, 256, 0, stream>>>(
            edge_w1, edge_w2, coord_w1, node_w1, node_w2,
            w1f_hi, w1f_lo, w2f_hi, w2f_lo, c1f_hi, c1f_lo,
            n1f_hi, n1f_lo, n2f_hi, n2f_lo);
    }

    // h = H @ emb_in_w + b  (write packed hi/lo)
    k_gemm<128, false, true><<<NATOM / 32, 128, 0, stream>>>(
        H, emb_in_w, emb_in_b, (float*)hp, NATOM);

    const float* xcur = Z;
    for (int l = 0; l < LAY; l++) {
        float* xnext = (l == 0) ? xA : (l == 1) ? xB : xout;

        k_edge_flat<<<EBK / E_WG, 768, 0, stream>>>(
            hp, xcur, eattr, edges, colIdx,
            w1f_hi + (size_t)l * W1F_L, w1f_lo + (size_t)l * W1F_L,
            w2f_hi + (size_t)l * W2F_L, w2f_lo + (size_t)l * W2F_L,
            c1f_hi + (size_t)l * W2F_L, c1f_lo + (size_t)l * W2F_L,
            edge_b1 + l * 128, edge_b2 + l * 128, coord_b1 + l * 128, coord_w2 + l * 128,
            msum, xsum);

        k_xupd<<<(NATOM * 3 + 255) / 256, 256, 0, stream>>>(xcur, xsum, offB, listE, xnext);

        k_node<<<NATOM / 64, 256, 0, stream>>>(
            hp, msum, offB, listE,
            n1f_hi + (size_t)l * NW1F_L, n1f_lo + (size_t)l * NW1F_L,
            n2f_hi + (size_t)l * W2F_L, n2f_lo + (size_t)l * W2F_L,
            node_b1 + l * 128, node_b2 + l * 128);

        xcur = xnext;
    }

    // h_out = h @ emb_out_w + b  (read packed, write f32 in-place)
    k_gemm<128, true, false><<<NATOM / 32, 128, 0, stream>>>(
        hbuf, emb_out_w, emb_out_b, hbuf, NATOM);
}